// Round 9
// baseline (346.652 us; speedup 1.0000x reference)
//
#include <hip/hip_runtime.h>
#include <hip/hip_bf16.h>
#include <math.h>

#define DMODEL 512
#define DINNER 1024
#define DSTATE 16
#define SEQLEN 2048
#define NTOK   4096
#define CHUNK  64
#define NCHUNK (SEQLEN / CHUNK)  // 32

#define BM 128
#define BN 128
#define BK 64

typedef __bf16 bf16x8 __attribute__((ext_vector_type(8)));
typedef float  f32x4  __attribute__((ext_vector_type(4)));

__device__ __forceinline__ float silu_f(float x) {
    return x / (1.0f + __expf(-x));
}

// swizzled LDS index (bf16 elems) for row r, 16B slot s (8 slots per 64-elem row)
__device__ __forceinline__ int swz(int r, int s) {
    return r * BK + ((s ^ (r & 7)) << 3);
}

// ---------------------------------------------------------------------------
// bf16 MFMA GEMM, tile 128x128, BK=64, 4 waves (each 64x64 = 4x4 frags).
// Single-buffer LDS (32 KB), R4-proven loop: stage -> bar -> prefetch -> MFMA -> bar.
// MODE 0: fused conv+z dual path.
//         bn <  1024: conv — A rows tap-shifted by (k0>>9)-1 (batch-aware pad),
//                     B = WT (FT, ldw), K = 2048; silu(acc+bias) -> C0 f32 + Cb bf16
//         bn >= 1024: z    — plain A, B = WT2 (w2T, ldw2), K = 512; Cz = acc
// MODE 2: delta — epilogue softplus(acc+bias[n]) * xc[m,n] * 0.95^(l+1) -> C0
// MODE 3: plain — C0 = acc (f32)
// MODE 4: fused-weight GEMM — per-tap (blockIdx.z), bf16 store at ldc stride
// ---------------------------------------------------------------------------
template<int MODE>
__global__ __launch_bounds__(256)
void mgemm(const __hip_bfloat16* __restrict__ A, int lda,
           const __hip_bfloat16* __restrict__ WT, int ldw,
           float* __restrict__ C0, __hip_bfloat16* __restrict__ Cb,
           float* __restrict__ Cz, int ldc,
           int K, const float* __restrict__ bias,
           const float* __restrict__ xc,
           const __hip_bfloat16* __restrict__ WT2, int ldw2)
{
    __shared__ __align__(16) __hip_bfloat16 As[BM * BK];  // 16 KB
    __shared__ __align__(16) __hip_bfloat16 Bs[BN * BK];  // 16 KB

    // bijective XCD swizzle (all launches have nb % 8 == 0)
    const int nb  = gridDim.x * gridDim.y;
    const int lin = blockIdx.y * gridDim.x + blockIdx.x;
    const int cpx = nb >> 3;
    const int sl  = (lin & 7) * cpx + (lin >> 3);
    const int bm  = (sl / gridDim.x) * BM;
    const int bn  = (sl % gridDim.x) * BN;

    if (MODE == 4) { A += blockIdx.z * 1024; Cb += blockIdx.z * 512; }

    const bool zblk = (MODE == 0) && (bn >= DINNER);
    const int  bnb  = zblk ? (bn - DINNER) : bn;
    const __hip_bfloat16* Wp = zblk ? WT2 : WT;
    const int  ldwp = zblk ? ldw2 : ldw;
    const int  Keff = zblk ? DMODEL : K;

    const int tid  = threadIdx.x;
    const int srow = tid >> 3, sslot = tid & 7;
    const int wid  = tid >> 6, lane = tid & 63;
    const int wr   = (wid >> 1) * 64, wc = (wid & 1) * 64;
    const int llo  = lane & 15, lhi = lane >> 4;

    f32x4 acc[4][4] = {};
    int4 ra[4], rb[4];

    auto load_tile = [&](int k0) {
#pragma unroll
        for (int p = 0; p < 4; ++p) {
            int r = srow + p * 32;
            if (MODE == 0 && !zblk) {
                int kid = k0 >> 9;                 // tap index (512 K per tap)
                int gr  = bm + r;
                int l2  = (gr & (SEQLEN - 1)) + kid - 1;
                if ((unsigned)l2 < (unsigned)SEQLEN)
                    ra[p] = *reinterpret_cast<const int4*>(
                        A + (size_t)(gr + kid - 1) * lda + (k0 & 511) + sslot * 8);
                else
                    ra[p] = make_int4(0, 0, 0, 0);
            } else {
                ra[p] = *reinterpret_cast<const int4*>(
                    A + (size_t)(bm + r) * lda + k0 + sslot * 8);
            }
        }
#pragma unroll
        for (int p = 0; p < 4; ++p)
            rb[p] = *reinterpret_cast<const int4*>(
                Wp + (size_t)(bnb + srow + p * 32) * ldwp + k0 + sslot * 8);
    };

    const int NT = Keff / BK;
    load_tile(0);
    for (int t = 0; t < NT; ++t) {
        // stage tile t (swizzled)
#pragma unroll
        for (int p = 0; p < 4; ++p)
            *reinterpret_cast<int4*>(&As[swz(srow + p * 32, sslot)]) = ra[p];
#pragma unroll
        for (int p = 0; p < 4; ++p)
            *reinterpret_cast<int4*>(&Bs[swz(srow + p * 32, sslot)]) = rb[p];
        __syncthreads();
        if (t + 1 < NT) load_tile((t + 1) * BK);   // in flight under MFMA phase
#pragma unroll
        for (int kk = 0; kk < 2; ++kk) {
            bf16x8 af[4], bv[4];
#pragma unroll
            for (int i = 0; i < 4; ++i)
                af[i] = *reinterpret_cast<const bf16x8*>(&As[swz(wr + i * 16 + llo, kk * 4 + lhi)]);
#pragma unroll
            for (int j = 0; j < 4; ++j)
                bv[j] = *reinterpret_cast<const bf16x8*>(&Bs[swz(wc + j * 16 + llo, kk * 4 + lhi)]);
#pragma unroll
            for (int i = 0; i < 4; ++i)
#pragma unroll
                for (int j = 0; j < 4; ++j)
                    acc[i][j] = __builtin_amdgcn_mfma_f32_16x16x32_bf16(af[i], bv[j], acc[i][j], 0, 0, 0);
        }
        __syncthreads();
    }

#pragma unroll
    for (int i = 0; i < 4; ++i) {
#pragma unroll
        for (int q = 0; q < 4; ++q) {
            int m = bm + wr + i * 16 + lhi * 4 + q;
            float dec = 1.0f;
            if (MODE == 2)
                dec = __expf((float)((m & (SEQLEN - 1)) + 1) * -0.051293294f); // ln 0.95
#pragma unroll
            for (int j = 0; j < 4; ++j) {
                int nrel = wc + j * 16 + llo;
                int n = bn + nrel;
                float v = acc[i][j][q];
                if (MODE == 0) {
                    if (!zblk) {
                        v = silu_f(v + bias[n]);
                        C0[(size_t)m * DINNER + n] = v;
                        Cb[(size_t)m * DINNER + n] = __float2bfloat16(v);
                    } else {
                        Cz[(size_t)m * DINNER + bnb + nrel] = v;
                    }
                } else if (MODE == 2) {
                    float d  = v + bias[n];
                    float sp = fmaxf(d, 0.f) + log1pf(__expf(-fabsf(d)));
                    C0[(size_t)m * ldc + n] = sp * xc[(size_t)m * DINNER + n] * dec;
                } else if (MODE == 4) {
                    Cb[(size_t)m * ldc + n] = __float2bfloat16(v);
                } else {
                    C0[(size_t)m * ldc + n] = v;
                }
            }
        }
    }
}

// transpose + f32->bf16: out[c][r] = in[r*ldin + c], out row stride R
__global__ __launch_bounds__(256)
void transpose_bf16_k(const float* __restrict__ in, __hip_bfloat16* __restrict__ out,
                      int R, int C, int ldin)
{
    __shared__ float t[32][33];
    int bx = blockIdx.x * 32, by = blockIdx.y * 32;
    int tx = threadIdx.x & 31, ty = threadIdx.x >> 5;
#pragma unroll
    for (int q = 0; q < 4; ++q)
        t[ty + q * 8][tx] = in[(size_t)(by + ty + q * 8) * ldin + bx + tx];
    __syncthreads();
#pragma unroll
    for (int q = 0; q < 4; ++q)
        out[(size_t)(bx + ty + q * 8) * R + by + tx] = __float2bfloat16(t[tx][ty + q * 8]);
}

// f32 -> bf16, first C cols of each row (ldin-strided source)
__global__ __launch_bounds__(256)
void cvt_slice_k(const float* __restrict__ in, __hip_bfloat16* __restrict__ out,
                 int ldin, int c4cnt)
{
    int idx = blockIdx.x * 256 + threadIdx.x;
    int r = idx / c4cnt, c = (idx - r * c4cnt) * 4;
    float4 v = *reinterpret_cast<const float4*>(in + (size_t)r * ldin + c);
    __hip_bfloat16 tmp[4] = {__float2bfloat16(v.x), __float2bfloat16(v.y),
                             __float2bfloat16(v.z), __float2bfloat16(v.w)};
    *reinterpret_cast<ushort4*>(&out[(size_t)r * (c4cnt * 4) + c]) =
        *reinterpret_cast<const ushort4*>(tmp);
}

// Bm = xc@wB + bB ; Cm = xc@wC + bC   (one token per block)
__global__ __launch_bounds__(256)
void bc_k(const float* __restrict__ xc,
          const float* __restrict__ wB, const float* __restrict__ bB,
          const float* __restrict__ wC, const float* __restrict__ bC,
          float* __restrict__ Bm, float* __restrict__ Cm)
{
    __shared__ float xr[DINNER];
    __shared__ float part[8][32];
    int t = blockIdx.x;
    int tid = threadIdx.x;
#pragma unroll
    for (int q = 0; q < 4; ++q) {
        int i = tid + q * 256;
        xr[i] = xc[(size_t)t * DINNER + i];
    }
    __syncthreads();
    int s = tid & 31;
    int p = tid >> 5;
    const float* W = (s < 16) ? wB : wC;
    int col = s & 15;
    float acc = 0.f;
    for (int k = p * 128; k < p * 128 + 128; ++k)
        acc += xr[k] * W[k * DSTATE + col];
    part[p][s] = acc;
    __syncthreads();
    if (tid < 32) {
        float sum = 0.f;
#pragma unroll
        for (int pp = 0; pp < 8; ++pp) sum += part[pp][tid];
        if (tid < 16) Bm[(size_t)t * DSTATE + tid] = sum + bB[tid];
        else          Cm[(size_t)t * DSTATE + (tid - 16)] = sum + bC[tid - 16];
    }
}

// per-chunk state S[bc][n][s] = sum_{t in chunk} w[t,n]*Bm[t,s]
__global__ __launch_bounds__(256)
void chunkS_k(const float* __restrict__ w, const float* __restrict__ Bm,
              float* __restrict__ S)
{
    int bc = blockIdx.x;
    int n0 = blockIdx.y * 16;
    int t0 = bc * CHUNK;
    __shared__ float wsh[CHUNK][16];
    __shared__ float bsh[CHUNK][17];
    int tid = threadIdx.x;
#pragma unroll
    for (int q = 0; q < 4; ++q) {
        int lin = tid + q * 256;
        int j = lin >> 4, col = lin & 15;
        wsh[j][col] = w[(size_t)(t0 + j) * DINNER + n0 + col];
        bsh[j][col] = Bm[(size_t)(t0 + j) * DSTATE + col];
    }
    __syncthreads();
    int ni = tid & 15, s = tid >> 4;
    float acc = 0.f;
#pragma unroll
    for (int j = 0; j < CHUNK; ++j)
        acc += wsh[j][ni] * bsh[j][s];
    S[((size_t)bc * DINNER + n0 + ni) * DSTATE + s] = acc;
}

// exclusive prefix over chunks
__global__ __launch_bounds__(256)
void hpre_k(const float* __restrict__ S, float* __restrict__ H)
{
    int idx = blockIdx.x * 256 + threadIdx.x;
    int b  = idx >> 14;
    int ns = idx & 16383;
    float acc = 0.f;
    for (int c = 0; c < NCHUNK; ++c) {
        size_t off = ((size_t)(b * NCHUNK + c)) * (DINNER * DSTATE) + ns;
        H[off] = acc;
        acc += S[off];
    }
}

// intra-chunk + inter combine + gate -> gb (bf16)
__global__ __launch_bounds__(256)
void intra_k(const float* __restrict__ wbuf,
             const float* __restrict__ Bm, const float* __restrict__ Cm,
             const float* __restrict__ H,
             const float* __restrict__ zbuf,
             __hip_bfloat16* __restrict__ gb)
{
    int bc = blockIdx.x;
    int t0 = bc * CHUNK;
    int n0 = blockIdx.y * 64;
    __shared__ float wsh[CHUNK][65];
    __shared__ float Psh[CHUNK][CHUNK + 1];
    __shared__ float bsh[CHUNK][17];
    __shared__ float csh[CHUNK][17];
    int tid = threadIdx.x;
#pragma unroll
    for (int q = 0; q < 16; ++q) {
        int lin = tid + q * 256;
        int j = lin >> 6, col = lin & 63;
        wsh[j][col] = wbuf[(size_t)(t0 + j) * DINNER + n0 + col];
    }
#pragma unroll
    for (int q = 0; q < 4; ++q) {
        int lin = tid + q * 256;
        int j = lin >> 4, sc = lin & 15;
        bsh[j][sc] = Bm[(size_t)(t0 + j) * DSTATE + sc];
        csh[j][sc] = Cm[(size_t)(t0 + j) * DSTATE + sc];
    }
    __syncthreads();
#pragma unroll
    for (int q = 0; q < 16; ++q) {
        int lin = tid + q * 256;
        int l = lin >> 6, t = lin & 63;
        float p = 0.f;
#pragma unroll
        for (int s = 0; s < DSTATE; ++s) p += csh[l][s] * bsh[t][s];
        Psh[l][t] = p;
    }
    __syncthreads();
    int n  = tid & 63;
    int lg = tid >> 6;
    float hv[DSTATE];
#pragma unroll
    for (int s = 0; s < DSTATE; ++s)
        hv[s] = H[(size_t)bc * (DINNER * DSTATE) + (size_t)(n0 + n) * DSTATE + s];
#pragma unroll
    for (int q = 0; q < 16; ++q) {
        int l = lg * 16 + q;
        float y = 0.f;
#pragma unroll
        for (int s = 0; s < DSTATE; ++s) y += hv[s] * csh[l][s];
        for (int t = 0; t <= l; ++t) y += Psh[l][t] * wsh[t][n];
        int token = t0 + l;
        float z = zbuf[(size_t)token * DINNER + n0 + n];
        gb[(size_t)token * DINNER + n0 + n] = __float2bfloat16(y * silu_f(z));
    }
}

extern "C" void kernel_launch(void* const* d_in, const int* in_sizes, int n_in,
                              void* d_out, int out_size, void* d_ws, size_t ws_size,
                              hipStream_t stream) {
    const float* x      = (const float*)d_in[0];
    const float* w_in   = (const float*)d_in[1];
    const float* conv_k = (const float*)d_in[2];
    const float* conv_b = (const float*)d_in[3];
    const float* w_del  = (const float*)d_in[4];
    const float* b_del  = (const float*)d_in[5];
    const float* w_B    = (const float*)d_in[6];
    const float* b_B    = (const float*)d_in[7];
    const float* w_C    = (const float*)d_in[8];
    const float* b_C    = (const float*)d_in[9];
    const float* w_out  = (const float*)d_in[11];
    float* out = (float*)d_out;

    // R4-exact workspace layout (93.5 MB proven)
    float* zbuf  = (float*)d_ws;                          // 4M f32
    float* xconv = zbuf  + (size_t)NTOK * DINNER;         // 4M
    float* wbuf  = xconv + (size_t)NTOK * DINNER;         // 4M
    float* Bm    = wbuf  + (size_t)NTOK * DINNER;
    float* Cm    = Bm    + (size_t)NTOK * DSTATE;
    float* S     = Cm    + (size_t)NTOK * DSTATE;         // 1M
    float* H     = S     + (size_t)2 * NCHUNK * DINNER * DSTATE;  // 1M
    __hip_bfloat16* xb    = (__hip_bfloat16*)(H + (size_t)2 * NCHUNK * DINNER * DSTATE);
    __hip_bfloat16* xcb   = xb    + (size_t)NTOK * DMODEL;        // 4M elems
    __hip_bfloat16* gb    = xcb   + (size_t)NTOK * DINNER;        // 4M
    __hip_bfloat16* W1b   = gb    + (size_t)NTOK * DINNER;        // 0.5M
    __hip_bfloat16* w2T   = W1b   + (size_t)DMODEL * DINNER;      // 0.5M
    __hip_bfloat16* convT = w2T   + (size_t)DINNER * DMODEL;      // 4M
    __hip_bfloat16* wdelT = convT + (size_t)4 * DINNER * DINNER;  // 1M
    __hip_bfloat16* woutT = wdelT + (size_t)DINNER * DINNER;      // 0.5M
    __hip_bfloat16* FT    = woutT + (size_t)DINNER * DMODEL;      // 2M (1024 x 2048)

    // input/weight prep
    cvt_slice_k<<<NTOK * DMODEL / 1024, 256, 0, stream>>>(x, xb, DMODEL, DMODEL / 4);
    cvt_slice_k<<<DMODEL * DINNER / 1024, 256, 0, stream>>>(w_in, W1b, 2 * DINNER, DINNER / 4);
    transpose_bf16_k<<<dim3(DINNER / 32, DMODEL / 32), 256, 0, stream>>>(
        w_in + DINNER, w2T, DMODEL, DINNER, 2 * DINNER);
    transpose_bf16_k<<<dim3(DINNER / 32, 4 * DINNER / 32), 256, 0, stream>>>(
        conv_k, convT, 4 * DINNER, DINNER, DINNER);
    transpose_bf16_k<<<dim3(DINNER / 32, DINNER / 32), 256, 0, stream>>>(
        w_del, wdelT, DINNER, DINNER, DINNER);
    transpose_bf16_k<<<dim3(DMODEL / 32, DINNER / 32), 256, 0, stream>>>(
        w_out, woutT, DINNER, DMODEL, DMODEL);

    // fused conv weights: FT[o][tap*512 + dm] = (W1 @ K_tap)[dm][o], row stride 2048
    mgemm<4><<<dim3(DMODEL / BN, DINNER / BM, 4), 256, 0, stream>>>(
        convT, 4 * DINNER, W1b, DINNER, nullptr, FT, nullptr, 4 * DMODEL, DINNER,
        nullptr, nullptr, nullptr, 0);
    // fused conv+z (dual path): bn<1024 conv (FT, K=2048) -> xconv/xcb;
    //                           bn>=1024 z (w2T, K=512)   -> zbuf
    mgemm<0><<<dim3(2 * DINNER / BN, NTOK / BM), 256, 0, stream>>>(
        xb, DMODEL, FT, 4 * DMODEL, xconv, xcb, zbuf, DINNER, 4 * DMODEL,
        conv_b, nullptr, w2T, DMODEL);
    // Bm, Cm
    bc_k<<<NTOK, 256, 0, stream>>>(xconv, w_B, b_B, w_C, b_C, Bm, Cm);
    // w = softplus(xc@w_delta+b) * xc * decay
    mgemm<2><<<dim3(DINNER / BN, NTOK / BM), 256, 0, stream>>>(
        xcb, DINNER, wdelT, DINNER, wbuf, nullptr, nullptr, DINNER, DINNER,
        b_del, xconv, nullptr, 0);
    // scan
    chunkS_k<<<dim3(2 * NCHUNK, DINNER / 16), 256, 0, stream>>>(wbuf, Bm, S);
    hpre_k<<<dim3(2 * DINNER * DSTATE / 256), 256, 0, stream>>>(S, H);
    intra_k<<<dim3(2 * NCHUNK, DINNER / 64), 256, 0, stream>>>(wbuf, Bm, Cm, H, zbuf, gb);
    // out = g @ w_out
    mgemm<3><<<dim3(DMODEL / BN, NTOK / BM), 256, 0, stream>>>(
        gb, DINNER, woutT, DINNER, out, nullptr, nullptr, DMODEL, DINNER,
        nullptr, nullptr, nullptr, 0);
}

// Round 10
// 237.751 us; speedup vs baseline: 1.4580x; 1.4580x over previous
//
#include <hip/hip_runtime.h>
#include <hip/hip_bf16.h>
#include <math.h>

#define DMODEL 512
#define DINNER 1024
#define DSTATE 16
#define SEQLEN 2048
#define NTOK   4096
#define CHUNK  64
#define NCHUNK (SEQLEN / CHUNK)  // 32

#define BM 128
#define BN 128
#define BK 64

typedef __bf16 bf16x8 __attribute__((ext_vector_type(8)));
typedef float  f32x4  __attribute__((ext_vector_type(4)));

__device__ __forceinline__ float silu_f(float x) {
    return x / (1.0f + __expf(-x));
}

// swizzled LDS index (bf16 elems) for row r, 16B slot s (8 slots per 64-elem row)
__device__ __forceinline__ int swz(int r, int s) {
    return r * BK + ((s ^ (r & 7)) << 3);
}

// async global->LDS 16B; LDS dest is wave-uniform base + lane*16
__device__ __forceinline__ void gload16(const void* g, void* l) {
    __builtin_amdgcn_global_load_lds(
        (const __attribute__((address_space(1))) void*)g,
        (__attribute__((address_space(3))) void*)l, 16, 0, 0);
}

// ---------------------------------------------------------------------------
// bf16 MFMA GEMM, tile 128x128, BK=64, 4 waves (each 64x64 = 4x4 frags).
// global_load_lds staging (m97 structure): linear LDS [128][64], XOR-swizzle
// applied on the SOURCE address (involution) + same swizzle on ds_read.
// MODE 0: fused conv+z dual path (conv: tap-shifted rows, OOB -> zpage).
// MODE 2: delta — epilogue softplus(acc+bias[n]) * xc[m,n] * 0.95^(l+1) -> C0
// MODE 3: plain — C0 = acc (f32)
// MODE 4: fused-weight GEMM — per-tap (blockIdx.z), bf16 store at ldc stride
// ---------------------------------------------------------------------------
template<int MODE>
__global__ __launch_bounds__(256)
void mgemm(const __hip_bfloat16* __restrict__ A, int lda,
           const __hip_bfloat16* __restrict__ WT, int ldw,
           float* __restrict__ C0, __hip_bfloat16* __restrict__ Cb,
           float* __restrict__ Cz, int ldc,
           int K, const float* __restrict__ bias,
           const float* __restrict__ xc,
           const __hip_bfloat16* __restrict__ WT2, int ldw2,
           const __hip_bfloat16* __restrict__ zpage)
{
    __shared__ __align__(16) __hip_bfloat16 As[BM * BK];  // 16 KB, linear [128][64]
    __shared__ __align__(16) __hip_bfloat16 Bs[BN * BK];  // 16 KB

    // bijective XCD swizzle (all launches have nb % 8 == 0)
    const int nb  = gridDim.x * gridDim.y;
    const int lin = blockIdx.y * gridDim.x + blockIdx.x;
    const int cpx = nb >> 3;
    const int sl  = (lin & 7) * cpx + (lin >> 3);
    const int bm  = (sl / gridDim.x) * BM;
    const int bn  = (sl % gridDim.x) * BN;

    if (MODE == 4) { A += blockIdx.z * 1024; Cb += blockIdx.z * 512; }

    const bool zblk = (MODE == 0) && (bn >= DINNER);
    const int  bnb  = zblk ? (bn - DINNER) : bn;
    const __hip_bfloat16* Wp = zblk ? WT2 : WT;
    const int  ldwp = zblk ? ldw2 : ldw;
    const int  Keff = zblk ? DMODEL : K;

    const int tid  = threadIdx.x;
    const int wid  = tid >> 6, lane = tid & 63;
    const int wr   = (wid >> 1) * 64, wc = (wid & 1) * 64;
    const int llo  = lane & 15, lhi = lane >> 4;

    f32x4 acc[4][4] = {};

    // per-lane staging geometry: each issue q covers rows q*32 + wid*8 + (lane>>3)
    const int srow0 = wid * 8 + (lane >> 3);
    const int sphys = lane & 7;

    auto stage_tile = [&](int k0) {
#pragma unroll
        for (int q = 0; q < 4; ++q) {
            int row  = q * 32 + srow0;
            int sdat = sphys ^ (row & 7);          // source pre-swizzle (involution)
            const __hip_bfloat16* srcA;
            if (MODE == 0 && !zblk) {
                int kid = k0 >> 9;                 // tap index (512 K per tap)
                int gr  = bm + row;
                int l2  = (gr & (SEQLEN - 1)) + kid - 1;
                srcA = ((unsigned)l2 < (unsigned)SEQLEN)
                     ? A + (size_t)(gr + kid - 1) * lda + (k0 & 511) + sdat * 8
                     : zpage;
            } else {
                srcA = A + (size_t)(bm + row) * lda + k0 + sdat * 8;
            }
            gload16(srcA, &As[q * 2048 + wid * 512]);
            const __hip_bfloat16* srcB =
                Wp + (size_t)(bnb + row) * ldwp + k0 + sdat * 8;
            gload16(srcB, &Bs[q * 2048 + wid * 512]);
        }
    };

    const int NT = Keff / BK;
    for (int t = 0; t < NT; ++t) {
        stage_tile(t * BK);
        __syncthreads();                  // drains vmcnt (gload_lds) per barrier semantics
#pragma unroll
        for (int kk = 0; kk < 2; ++kk) {
            bf16x8 af[4], bv[4];
#pragma unroll
            for (int i = 0; i < 4; ++i)
                af[i] = *reinterpret_cast<const bf16x8*>(&As[swz(wr + i * 16 + llo, kk * 4 + lhi)]);
#pragma unroll
            for (int j = 0; j < 4; ++j)
                bv[j] = *reinterpret_cast<const bf16x8*>(&Bs[swz(wc + j * 16 + llo, kk * 4 + lhi)]);
#pragma unroll
            for (int i = 0; i < 4; ++i)
#pragma unroll
                for (int j = 0; j < 4; ++j)
                    acc[i][j] = __builtin_amdgcn_mfma_f32_16x16x32_bf16(af[i], bv[j], acc[i][j], 0, 0, 0);
        }
        __syncthreads();
    }

#pragma unroll
    for (int i = 0; i < 4; ++i) {
#pragma unroll
        for (int q = 0; q < 4; ++q) {
            int m = bm + wr + i * 16 + lhi * 4 + q;
            float dec = 1.0f;
            if (MODE == 2)
                dec = __expf((float)((m & (SEQLEN - 1)) + 1) * -0.051293294f); // ln 0.95
#pragma unroll
            for (int j = 0; j < 4; ++j) {
                int nrel = wc + j * 16 + llo;
                int n = bn + nrel;
                float v = acc[i][j][q];
                if (MODE == 0) {
                    if (!zblk) {
                        v = silu_f(v + bias[n]);
                        C0[(size_t)m * DINNER + n] = v;
                        Cb[(size_t)m * DINNER + n] = __float2bfloat16(v);
                    } else {
                        Cz[(size_t)m * DINNER + bnb + nrel] = v;
                    }
                } else if (MODE == 2) {
                    float d  = v + bias[n];
                    float sp = fmaxf(d, 0.f) + log1pf(__expf(-fabsf(d)));
                    C0[(size_t)m * ldc + n] = sp * xc[(size_t)m * DINNER + n] * dec;
                } else if (MODE == 4) {
                    Cb[(size_t)m * ldc + n] = __float2bfloat16(v);
                } else {
                    C0[(size_t)m * ldc + n] = v;
                }
            }
        }
    }
}

// transpose + f32->bf16: out[c][r] = in[r*ldin + c], out row stride R
__global__ __launch_bounds__(256)
void transpose_bf16_k(const float* __restrict__ in, __hip_bfloat16* __restrict__ out,
                      int R, int C, int ldin)
{
    __shared__ float t[32][33];
    int bx = blockIdx.x * 32, by = blockIdx.y * 32;
    int tx = threadIdx.x & 31, ty = threadIdx.x >> 5;
#pragma unroll
    for (int q = 0; q < 4; ++q)
        t[ty + q * 8][tx] = in[(size_t)(by + ty + q * 8) * ldin + bx + tx];
    __syncthreads();
#pragma unroll
    for (int q = 0; q < 4; ++q)
        out[(size_t)(bx + ty + q * 8) * R + by + tx] = __float2bfloat16(t[tx][ty + q * 8]);
}

// f32 -> bf16, first C cols of each row (ldin-strided source)
__global__ __launch_bounds__(256)
void cvt_slice_k(const float* __restrict__ in, __hip_bfloat16* __restrict__ out,
                 int ldin, int c4cnt)
{
    int idx = blockIdx.x * 256 + threadIdx.x;
    int r = idx / c4cnt, c = (idx - r * c4cnt) * 4;
    float4 v = *reinterpret_cast<const float4*>(in + (size_t)r * ldin + c);
    __hip_bfloat16 tmp[4] = {__float2bfloat16(v.x), __float2bfloat16(v.y),
                             __float2bfloat16(v.z), __float2bfloat16(v.w)};
    *reinterpret_cast<ushort4*>(&out[(size_t)r * (c4cnt * 4) + c]) =
        *reinterpret_cast<const ushort4*>(tmp);
}

// Bm = xc@wB + bB ; Cm = xc@wC + bC   (one token per block)
__global__ __launch_bounds__(256)
void bc_k(const float* __restrict__ xc,
          const float* __restrict__ wB, const float* __restrict__ bB,
          const float* __restrict__ wC, const float* __restrict__ bC,
          float* __restrict__ Bm, float* __restrict__ Cm)
{
    __shared__ float xr[DINNER];
    __shared__ float part[8][32];
    int t = blockIdx.x;
    int tid = threadIdx.x;
#pragma unroll
    for (int q = 0; q < 4; ++q) {
        int i = tid + q * 256;
        xr[i] = xc[(size_t)t * DINNER + i];
    }
    __syncthreads();
    int s = tid & 31;
    int p = tid >> 5;
    const float* W = (s < 16) ? wB : wC;
    int col = s & 15;
    float acc = 0.f;
    for (int k = p * 128; k < p * 128 + 128; ++k)
        acc += xr[k] * W[k * DSTATE + col];
    part[p][s] = acc;
    __syncthreads();
    if (tid < 32) {
        float sum = 0.f;
#pragma unroll
        for (int pp = 0; pp < 8; ++pp) sum += part[pp][tid];
        if (tid < 16) Bm[(size_t)t * DSTATE + tid] = sum + bB[tid];
        else          Cm[(size_t)t * DSTATE + (tid - 16)] = sum + bC[tid - 16];
    }
}

// per-chunk state S[bc][n][s] = sum_{t in chunk} w[t,n]*Bm[t,s]
__global__ __launch_bounds__(256)
void chunkS_k(const float* __restrict__ w, const float* __restrict__ Bm,
              float* __restrict__ S)
{
    int bc = blockIdx.x;
    int n0 = blockIdx.y * 16;
    int t0 = bc * CHUNK;
    __shared__ float wsh[CHUNK][16];
    __shared__ float bsh[CHUNK][17];
    int tid = threadIdx.x;
#pragma unroll
    for (int q = 0; q < 4; ++q) {
        int lin = tid + q * 256;
        int j = lin >> 4, col = lin & 15;
        wsh[j][col] = w[(size_t)(t0 + j) * DINNER + n0 + col];
        bsh[j][col] = Bm[(size_t)(t0 + j) * DSTATE + col];
    }
    __syncthreads();
    int ni = tid & 15, s = tid >> 4;
    float acc = 0.f;
#pragma unroll
    for (int j = 0; j < CHUNK; ++j)
        acc += wsh[j][ni] * bsh[j][s];
    S[((size_t)bc * DINNER + n0 + ni) * DSTATE + s] = acc;
}

// exclusive prefix over chunks
__global__ __launch_bounds__(256)
void hpre_k(const float* __restrict__ S, float* __restrict__ H)
{
    int idx = blockIdx.x * 256 + threadIdx.x;
    int b  = idx >> 14;
    int ns = idx & 16383;
    float acc = 0.f;
    for (int c = 0; c < NCHUNK; ++c) {
        size_t off = ((size_t)(b * NCHUNK + c)) * (DINNER * DSTATE) + ns;
        H[off] = acc;
        acc += S[off];
    }
}

// intra-chunk + inter combine + gate -> gb (bf16)
__global__ __launch_bounds__(256)
void intra_k(const float* __restrict__ wbuf,
             const float* __restrict__ Bm, const float* __restrict__ Cm,
             const float* __restrict__ H,
             const float* __restrict__ zbuf,
             __hip_bfloat16* __restrict__ gb)
{
    int bc = blockIdx.x;
    int t0 = bc * CHUNK;
    int n0 = blockIdx.y * 64;
    __shared__ float wsh[CHUNK][65];
    __shared__ float Psh[CHUNK][CHUNK + 1];
    __shared__ float bsh[CHUNK][17];
    __shared__ float csh[CHUNK][17];
    int tid = threadIdx.x;
#pragma unroll
    for (int q = 0; q < 16; ++q) {
        int lin = tid + q * 256;
        int j = lin >> 6, col = lin & 63;
        wsh[j][col] = wbuf[(size_t)(t0 + j) * DINNER + n0 + col];
    }
#pragma unroll
    for (int q = 0; q < 4; ++q) {
        int lin = tid + q * 256;
        int j = lin >> 4, sc = lin & 15;
        bsh[j][sc] = Bm[(size_t)(t0 + j) * DSTATE + sc];
        csh[j][sc] = Cm[(size_t)(t0 + j) * DSTATE + sc];
    }
    __syncthreads();
#pragma unroll
    for (int q = 0; q < 16; ++q) {
        int lin = tid + q * 256;
        int l = lin >> 6, t = lin & 63;
        float p = 0.f;
#pragma unroll
        for (int s = 0; s < DSTATE; ++s) p += csh[l][s] * bsh[t][s];
        Psh[l][t] = p;
    }
    __syncthreads();
    int n  = tid & 63;
    int lg = tid >> 6;
    float hv[DSTATE];
#pragma unroll
    for (int s = 0; s < DSTATE; ++s)
        hv[s] = H[(size_t)bc * (DINNER * DSTATE) + (size_t)(n0 + n) * DSTATE + s];
#pragma unroll
    for (int q = 0; q < 16; ++q) {
        int l = lg * 16 + q;
        float y = 0.f;
#pragma unroll
        for (int s = 0; s < DSTATE; ++s) y += hv[s] * csh[l][s];
        for (int t = 0; t <= l; ++t) y += Psh[l][t] * wsh[t][n];
        int token = t0 + l;
        float z = zbuf[(size_t)token * DINNER + n0 + n];
        gb[(size_t)token * DINNER + n0 + n] = __float2bfloat16(y * silu_f(z));
    }
}

extern "C" void kernel_launch(void* const* d_in, const int* in_sizes, int n_in,
                              void* d_out, int out_size, void* d_ws, size_t ws_size,
                              hipStream_t stream) {
    const float* x      = (const float*)d_in[0];
    const float* w_in   = (const float*)d_in[1];
    const float* conv_k = (const float*)d_in[2];
    const float* conv_b = (const float*)d_in[3];
    const float* w_del  = (const float*)d_in[4];
    const float* b_del  = (const float*)d_in[5];
    const float* w_B    = (const float*)d_in[6];
    const float* b_B    = (const float*)d_in[7];
    const float* w_C    = (const float*)d_in[8];
    const float* b_C    = (const float*)d_in[9];
    const float* w_out  = (const float*)d_in[11];
    float* out = (float*)d_out;

    // R4-exact workspace layout (93.5 MB proven) + 16 KB zpage at tail
    float* zbuf  = (float*)d_ws;                          // 4M f32
    float* xconv = zbuf  + (size_t)NTOK * DINNER;         // 4M
    float* wbuf  = xconv + (size_t)NTOK * DINNER;         // 4M
    float* Bm    = wbuf  + (size_t)NTOK * DINNER;
    float* Cm    = Bm    + (size_t)NTOK * DSTATE;
    float* S     = Cm    + (size_t)NTOK * DSTATE;         // 1M
    float* H     = S     + (size_t)2 * NCHUNK * DINNER * DSTATE;  // 1M
    __hip_bfloat16* xb    = (__hip_bfloat16*)(H + (size_t)2 * NCHUNK * DINNER * DSTATE);
    __hip_bfloat16* xcb   = xb    + (size_t)NTOK * DMODEL;        // 4M elems
    __hip_bfloat16* gb    = xcb   + (size_t)NTOK * DINNER;        // 4M
    __hip_bfloat16* W1b   = gb    + (size_t)NTOK * DINNER;        // 0.5M
    __hip_bfloat16* w2T   = W1b   + (size_t)DMODEL * DINNER;      // 0.5M
    __hip_bfloat16* convT = w2T   + (size_t)DINNER * DMODEL;      // 4M
    __hip_bfloat16* wdelT = convT + (size_t)4 * DINNER * DINNER;  // 1M
    __hip_bfloat16* woutT = wdelT + (size_t)DINNER * DINNER;      // 0.5M
    __hip_bfloat16* FT    = woutT + (size_t)DINNER * DMODEL;      // 2M (1024 x 2048)
    __hip_bfloat16* zpage = FT    + (size_t)DINNER * 2048;        // 8K elems

    hipMemsetAsync(zpage, 0, 16384, stream);

    // input/weight prep
    cvt_slice_k<<<NTOK * DMODEL / 1024, 256, 0, stream>>>(x, xb, DMODEL, DMODEL / 4);
    cvt_slice_k<<<DMODEL * DINNER / 1024, 256, 0, stream>>>(w_in, W1b, 2 * DINNER, DINNER / 4);
    transpose_bf16_k<<<dim3(DINNER / 32, DMODEL / 32), 256, 0, stream>>>(
        w_in + DINNER, w2T, DMODEL, DINNER, 2 * DINNER);
    transpose_bf16_k<<<dim3(DINNER / 32, 4 * DINNER / 32), 256, 0, stream>>>(
        conv_k, convT, 4 * DINNER, DINNER, DINNER);
    transpose_bf16_k<<<dim3(DINNER / 32, DINNER / 32), 256, 0, stream>>>(
        w_del, wdelT, DINNER, DINNER, DINNER);
    transpose_bf16_k<<<dim3(DMODEL / 32, DINNER / 32), 256, 0, stream>>>(
        w_out, woutT, DINNER, DMODEL, DMODEL);

    // fused conv weights: FT[o][tap*512 + dm] = (W1 @ K_tap)[dm][o], row stride 2048
    mgemm<4><<<dim3(DMODEL / BN, DINNER / BM, 4), 256, 0, stream>>>(
        convT, 4 * DINNER, W1b, DINNER, nullptr, FT, nullptr, 4 * DMODEL, DINNER,
        nullptr, nullptr, nullptr, 0, zpage);
    // fused conv+z (dual path): bn<1024 conv (FT, K=2048) -> xconv/xcb;
    //                           bn>=1024 z (w2T, K=512)   -> zbuf
    mgemm<0><<<dim3(2 * DINNER / BN, NTOK / BM), 256, 0, stream>>>(
        xb, DMODEL, FT, 4 * DMODEL, xconv, xcb, zbuf, DINNER, 4 * DMODEL,
        conv_b, nullptr, w2T, DMODEL, zpage);
    // Bm, Cm
    bc_k<<<NTOK, 256, 0, stream>>>(xconv, w_B, b_B, w_C, b_C, Bm, Cm);
    // w = softplus(xc@w_delta+b) * xc * decay
    mgemm<2><<<dim3(DINNER / BN, NTOK / BM), 256, 0, stream>>>(
        xcb, DINNER, wdelT, DINNER, wbuf, nullptr, nullptr, DINNER, DINNER,
        b_del, xconv, nullptr, 0, zpage);
    // scan
    chunkS_k<<<dim3(2 * NCHUNK, DINNER / 16), 256, 0, stream>>>(wbuf, Bm, S);
    hpre_k<<<dim3(2 * DINNER * DSTATE / 256), 256, 0, stream>>>(S, H);
    intra_k<<<dim3(2 * NCHUNK, DINNER / 64), 256, 0, stream>>>(wbuf, Bm, Cm, H, zbuf, gb);
    // out = g @ w_out
    mgemm<3><<<dim3(DMODEL / BN, NTOK / BM), 256, 0, stream>>>(
        gb, DINNER, woutT, DINNER, out, nullptr, nullptr, DMODEL, DINNER,
        nullptr, nullptr, nullptr, 0, zpage);
}

// Round 11
// 223.673 us; speedup vs baseline: 1.5498x; 1.0629x over previous
//
#include <hip/hip_runtime.h>
#include <hip/hip_bf16.h>
#include <math.h>

#define DMODEL 512
#define DINNER 1024
#define DSTATE 16
#define SEQLEN 2048
#define NTOK   4096
#define CHUNK  64
#define NCHUNK (SEQLEN / CHUNK)  // 32

typedef __bf16 bf16x8 __attribute__((ext_vector_type(8)));
typedef float  f32x4  __attribute__((ext_vector_type(4)));

__device__ __forceinline__ float silu_f(float x) {
    return x / (1.0f + __expf(-x));
}

// swizzled LDS index (bf16 elems) for row r, 16B slot s (8 slots per 64-elem row)
__device__ __forceinline__ int swz(int r, int s) {
    return r * 64 + ((s ^ (r & 7)) << 3);
}

// async global->LDS 16B; LDS dest is wave-uniform base + lane*16
__device__ __forceinline__ void gload16(const void* g, void* l) {
    __builtin_amdgcn_global_load_lds(
        (const __attribute__((address_space(1))) void*)g,
        (__attribute__((address_space(3))) void*)l, 16, 0, 0);
}

// ---------------------------------------------------------------------------
// bf16 MFMA GEMM, tile TBM x TBN, BK=64, 4 waves (2x2), gload_lds staging,
// linear LDS + source-side XOR swizzle (involution) + same swizzle on ds_read.
// MODE 0: fused conv+z dual path (conv: tap-shifted rows, OOB -> zpage);
//         n<1024: silu(acc+bias) -> Cb bf16 ; else Czb bf16
// MODE 2: delta — softplus(acc+bias[n]) * bf16 xc[m,n] * 0.95^(l+1) -> C0 f32
// MODE 3: plain — C0 = acc (f32)
// MODE 4: fused-weight GEMM — per-tap (blockIdx.z), bf16 store at ldc stride
// ---------------------------------------------------------------------------
template<int MODE, int TBM, int TBN>
__global__ __launch_bounds__(256)
void mgemm(const __hip_bfloat16* __restrict__ A, int lda,
           const __hip_bfloat16* __restrict__ WT, int ldw,
           float* __restrict__ C0, __hip_bfloat16* __restrict__ Cb,
           __hip_bfloat16* __restrict__ Czb, int ldc,
           int K, const float* __restrict__ bias,
           const __hip_bfloat16* __restrict__ xc,
           const __hip_bfloat16* __restrict__ WT2, int ldw2,
           const __hip_bfloat16* __restrict__ zpage)
{
    constexpr int MI = TBM / 32;          // A frags per wave
    constexpr int MJ = TBN / 32;          // B frags per wave
    __shared__ __align__(16) __hip_bfloat16 As[TBM * 64];
    __shared__ __align__(16) __hip_bfloat16 Bs[TBN * 64];

    // bijective XCD swizzle (all launches have nb % 8 == 0)
    const int nb  = gridDim.x * gridDim.y;
    const int lin = blockIdx.y * gridDim.x + blockIdx.x;
    const int cpx = nb >> 3;
    const int sl  = (lin & 7) * cpx + (lin >> 3);
    const int bm  = (sl / gridDim.x) * TBM;
    const int bn  = (sl % gridDim.x) * TBN;

    if (MODE == 4) { A += blockIdx.z * 1024; Cb += blockIdx.z * 512; }

    const bool zblk = (MODE == 0) && (bn >= DINNER);
    const int  bnb  = zblk ? (bn - DINNER) : bn;
    const __hip_bfloat16* Wp = zblk ? WT2 : WT;
    const int  ldwp = zblk ? ldw2 : ldw;
    const int  Keff = zblk ? DMODEL : K;

    const int tid  = threadIdx.x;
    const int wid  = tid >> 6, lane = tid & 63;
    const int wr   = (wid >> 1) * (TBM / 2), wc = (wid & 1) * (TBN / 2);
    const int llo  = lane & 15, lhi = lane >> 4;

    f32x4 acc[MI][MJ] = {};

    // per-lane staging geometry: issue q covers rows q*32 + wid*8 + (lane>>3)
    const int srow0 = wid * 8 + (lane >> 3);
    const int sphys = lane & 7;

    auto stage_tile = [&](int k0) {
#pragma unroll
        for (int q = 0; q < MI; ++q) {
            int row  = q * 32 + srow0;
            int sdat = sphys ^ (row & 7);          // source pre-swizzle (involution)
            const __hip_bfloat16* srcA;
            if (MODE == 0 && !zblk) {
                int kid = k0 >> 9;                 // tap index (512 K per tap)
                int gr  = bm + row;
                int l2  = (gr & (SEQLEN - 1)) + kid - 1;
                srcA = ((unsigned)l2 < (unsigned)SEQLEN)
                     ? A + (size_t)(gr + kid - 1) * lda + (k0 & 511) + sdat * 8
                     : zpage;
            } else {
                srcA = A + (size_t)(bm + row) * lda + k0 + sdat * 8;
            }
            gload16(srcA, &As[q * 2048 + wid * 512]);
        }
#pragma unroll
        for (int q = 0; q < MJ; ++q) {
            int row  = q * 32 + srow0;
            int sdat = sphys ^ (row & 7);
            gload16(Wp + (size_t)(bnb + row) * ldwp + k0 + sdat * 8,
                    &Bs[q * 2048 + wid * 512]);
        }
    };

    const int NT = Keff / 64;
    for (int t = 0; t < NT; ++t) {
        stage_tile(t * 64);
        __syncthreads();                  // drains vmcnt per barrier semantics
#pragma unroll
        for (int kk = 0; kk < 2; ++kk) {
            bf16x8 af[MI], bv[MJ];
#pragma unroll
            for (int i = 0; i < MI; ++i)
                af[i] = *reinterpret_cast<const bf16x8*>(&As[swz(wr + i * 16 + llo, kk * 4 + lhi)]);
#pragma unroll
            for (int j = 0; j < MJ; ++j)
                bv[j] = *reinterpret_cast<const bf16x8*>(&Bs[swz(wc + j * 16 + llo, kk * 4 + lhi)]);
#pragma unroll
            for (int i = 0; i < MI; ++i)
#pragma unroll
                for (int j = 0; j < MJ; ++j)
                    acc[i][j] = __builtin_amdgcn_mfma_f32_16x16x32_bf16(af[i], bv[j], acc[i][j], 0, 0, 0);
        }
        __syncthreads();
    }

#pragma unroll
    for (int i = 0; i < MI; ++i) {
#pragma unroll
        for (int q = 0; q < 4; ++q) {
            int m = bm + wr + i * 16 + lhi * 4 + q;
            float dec = 1.0f;
            if (MODE == 2)
                dec = __expf((float)((m & (SEQLEN - 1)) + 1) * -0.051293294f); // ln 0.95
#pragma unroll
            for (int j = 0; j < MJ; ++j) {
                int nrel = wc + j * 16 + llo;
                int n = bn + nrel;
                float v = acc[i][j][q];
                if (MODE == 0) {
                    if (!zblk) {
                        v = silu_f(v + bias[n]);
                        Cb[(size_t)m * DINNER + n] = __float2bfloat16(v);
                    } else {
                        Czb[(size_t)m * DINNER + bnb + nrel] = __float2bfloat16(v);
                    }
                } else if (MODE == 2) {
                    float d  = v + bias[n];
                    float sp = fmaxf(d, 0.f) + log1pf(__expf(-fabsf(d)));
                    float xcv = __bfloat162float(xc[(size_t)m * DINNER + n]);
                    C0[(size_t)m * ldc + n] = sp * xcv * dec;
                } else if (MODE == 4) {
                    Cb[(size_t)m * ldc + n] = __float2bfloat16(v);
                } else {
                    C0[(size_t)m * ldc + n] = v;
                }
            }
        }
    }
}

// transpose + f32->bf16: out[c][r] = in[r*ldin + c], out row stride R
__global__ __launch_bounds__(256)
void transpose_bf16_k(const float* __restrict__ in, __hip_bfloat16* __restrict__ out,
                      int R, int C, int ldin)
{
    __shared__ float t[32][33];
    int bx = blockIdx.x * 32, by = blockIdx.y * 32;
    int tx = threadIdx.x & 31, ty = threadIdx.x >> 5;
#pragma unroll
    for (int q = 0; q < 4; ++q)
        t[ty + q * 8][tx] = in[(size_t)(by + ty + q * 8) * ldin + bx + tx];
    __syncthreads();
#pragma unroll
    for (int q = 0; q < 4; ++q)
        out[(size_t)(bx + ty + q * 8) * R + by + tx] = __float2bfloat16(t[tx][ty + q * 8]);
}

// f32 -> bf16, first C cols of each row (ldin-strided source)
__global__ __launch_bounds__(256)
void cvt_slice_k(const float* __restrict__ in, __hip_bfloat16* __restrict__ out,
                 int ldin, int c4cnt)
{
    int idx = blockIdx.x * 256 + threadIdx.x;
    int r = idx / c4cnt, c = (idx - r * c4cnt) * 4;
    float4 v = *reinterpret_cast<const float4*>(in + (size_t)r * ldin + c);
    __hip_bfloat16 tmp[4] = {__float2bfloat16(v.x), __float2bfloat16(v.y),
                             __float2bfloat16(v.z), __float2bfloat16(v.w)};
    *reinterpret_cast<ushort4*>(&out[(size_t)r * (c4cnt * 4) + c]) =
        *reinterpret_cast<const ushort4*>(tmp);
}

// Bm = xc@wB + bB ; Cm = xc@wC + bC   (one token per block, bf16 xc)
__global__ __launch_bounds__(256)
void bc_k(const __hip_bfloat16* __restrict__ xc,
          const float* __restrict__ wB, const float* __restrict__ bB,
          const float* __restrict__ wC, const float* __restrict__ bC,
          float* __restrict__ Bm, float* __restrict__ Cm)
{
    __shared__ float xr[DINNER];
    __shared__ float part[8][32];
    int t = blockIdx.x;
    int tid = threadIdx.x;
    {
        ushort4 v = *reinterpret_cast<const ushort4*>(&xc[(size_t)t * DINNER + tid * 4]);
        xr[tid * 4 + 0] = __bfloat162float(*(const __hip_bfloat16*)&v.x);
        xr[tid * 4 + 1] = __bfloat162float(*(const __hip_bfloat16*)&v.y);
        xr[tid * 4 + 2] = __bfloat162float(*(const __hip_bfloat16*)&v.z);
        xr[tid * 4 + 3] = __bfloat162float(*(const __hip_bfloat16*)&v.w);
    }
    __syncthreads();
    int s = tid & 31;
    int p = tid >> 5;
    const float* W = (s < 16) ? wB : wC;
    int col = s & 15;
    float acc = 0.f;
    for (int k = p * 128; k < p * 128 + 128; ++k)
        acc += xr[k] * W[k * DSTATE + col];
    part[p][s] = acc;
    __syncthreads();
    if (tid < 32) {
        float sum = 0.f;
#pragma unroll
        for (int pp = 0; pp < 8; ++pp) sum += part[pp][tid];
        if (tid < 16) Bm[(size_t)t * DSTATE + tid] = sum + bB[tid];
        else          Cm[(size_t)t * DSTATE + (tid - 16)] = sum + bC[tid - 16];
    }
}

// per-chunk state S[bc][n][s] = sum_{t in chunk} w[t,n]*Bm[t,s]
__global__ __launch_bounds__(256)
void chunkS_k(const float* __restrict__ w, const float* __restrict__ Bm,
              float* __restrict__ S)
{
    int bc = blockIdx.x;
    int n0 = blockIdx.y * 16;
    int t0 = bc * CHUNK;
    __shared__ float wsh[CHUNK][16];
    __shared__ float bsh[CHUNK][17];
    int tid = threadIdx.x;
#pragma unroll
    for (int q = 0; q < 4; ++q) {
        int lin = tid + q * 256;
        int j = lin >> 4, col = lin & 15;
        wsh[j][col] = w[(size_t)(t0 + j) * DINNER + n0 + col];
        bsh[j][col] = Bm[(size_t)(t0 + j) * DSTATE + col];
    }
    __syncthreads();
    int ni = tid & 15, s = tid >> 4;
    float acc = 0.f;
#pragma unroll
    for (int j = 0; j < CHUNK; ++j)
        acc += wsh[j][ni] * bsh[j][s];
    S[((size_t)bc * DINNER + n0 + ni) * DSTATE + s] = acc;
}

// exclusive prefix over chunks
__global__ __launch_bounds__(256)
void hpre_k(const float* __restrict__ S, float* __restrict__ H)
{
    int idx = blockIdx.x * 256 + threadIdx.x;
    int b  = idx >> 14;
    int ns = idx & 16383;
    float acc = 0.f;
    for (int c = 0; c < NCHUNK; ++c) {
        size_t off = ((size_t)(b * NCHUNK + c)) * (DINNER * DSTATE) + ns;
        H[off] = acc;
        acc += S[off];
    }
}

// intra-chunk + inter combine + gate -> gb (bf16); z input bf16
__global__ __launch_bounds__(256)
void intra_k(const float* __restrict__ wbuf,
             const float* __restrict__ Bm, const float* __restrict__ Cm,
             const float* __restrict__ H,
             const __hip_bfloat16* __restrict__ zb,
             __hip_bfloat16* __restrict__ gb)
{
    int bc = blockIdx.x;
    int t0 = bc * CHUNK;
    int n0 = blockIdx.y * 64;
    __shared__ float wsh[CHUNK][65];
    __shared__ float Psh[CHUNK][CHUNK + 1];
    __shared__ float bsh[CHUNK][17];
    __shared__ float csh[CHUNK][17];
    int tid = threadIdx.x;
#pragma unroll
    for (int q = 0; q < 16; ++q) {
        int lin = tid + q * 256;
        int j = lin >> 6, col = lin & 63;
        wsh[j][col] = wbuf[(size_t)(t0 + j) * DINNER + n0 + col];
    }
#pragma unroll
    for (int q = 0; q < 4; ++q) {
        int lin = tid + q * 256;
        int j = lin >> 4, sc = lin & 15;
        bsh[j][sc] = Bm[(size_t)(t0 + j) * DSTATE + sc];
        csh[j][sc] = Cm[(size_t)(t0 + j) * DSTATE + sc];
    }
    __syncthreads();
#pragma unroll
    for (int q = 0; q < 16; ++q) {
        int lin = tid + q * 256;
        int l = lin >> 6, t = lin & 63;
        float p = 0.f;
#pragma unroll
        for (int s = 0; s < DSTATE; ++s) p += csh[l][s] * bsh[t][s];
        Psh[l][t] = p;
    }
    __syncthreads();
    int n  = tid & 63;
    int lg = tid >> 6;
    float hv[DSTATE];
#pragma unroll
    for (int s = 0; s < DSTATE; ++s)
        hv[s] = H[(size_t)bc * (DINNER * DSTATE) + (size_t)(n0 + n) * DSTATE + s];
#pragma unroll
    for (int q = 0; q < 16; ++q) {
        int l = lg * 16 + q;
        float y = 0.f;
#pragma unroll
        for (int s = 0; s < DSTATE; ++s) y += hv[s] * csh[l][s];
        for (int t = 0; t <= l; ++t) y += Psh[l][t] * wsh[t][n];
        int token = t0 + l;
        float z = __bfloat162float(zb[(size_t)token * DINNER + n0 + n]);
        gb[(size_t)token * DINNER + n0 + n] = __float2bfloat16(y * silu_f(z));
    }
}

extern "C" void kernel_launch(void* const* d_in, const int* in_sizes, int n_in,
                              void* d_out, int out_size, void* d_ws, size_t ws_size,
                              hipStream_t stream) {
    const float* x      = (const float*)d_in[0];
    const float* w_in   = (const float*)d_in[1];
    const float* conv_k = (const float*)d_in[2];
    const float* conv_b = (const float*)d_in[3];
    const float* w_del  = (const float*)d_in[4];
    const float* b_del  = (const float*)d_in[5];
    const float* w_B    = (const float*)d_in[6];
    const float* b_B    = (const float*)d_in[7];
    const float* w_C    = (const float*)d_in[8];
    const float* b_C    = (const float*)d_in[9];
    const float* w_out  = (const float*)d_in[11];
    float* out = (float*)d_out;

    // f32 region
    float* wbuf  = (float*)d_ws;                          // 4M
    float* Bm    = wbuf  + (size_t)NTOK * DINNER;
    float* Cm    = Bm    + (size_t)NTOK * DSTATE;
    float* S     = Cm    + (size_t)NTOK * DSTATE;         // 1M
    float* H     = S     + (size_t)2 * NCHUNK * DINNER * DSTATE;  // 1M
    // bf16 region
    __hip_bfloat16* xb    = (__hip_bfloat16*)(H + (size_t)2 * NCHUNK * DINNER * DSTATE);
    __hip_bfloat16* xcb   = xb    + (size_t)NTOK * DMODEL;        // 4M elems
    __hip_bfloat16* zb    = xcb   + (size_t)NTOK * DINNER;        // 4M
    __hip_bfloat16* gb    = zb    + (size_t)NTOK * DINNER;        // 4M
    __hip_bfloat16* W1b   = gb    + (size_t)NTOK * DINNER;        // 0.5M
    __hip_bfloat16* w2T   = W1b   + (size_t)DMODEL * DINNER;      // 0.5M
    __hip_bfloat16* convT = w2T   + (size_t)DINNER * DMODEL;      // 4M
    __hip_bfloat16* wdelT = convT + (size_t)4 * DINNER * DINNER;  // 1M
    __hip_bfloat16* woutT = wdelT + (size_t)DINNER * DINNER;      // 0.5M
    __hip_bfloat16* FT    = woutT + (size_t)DINNER * DMODEL;      // 2M (1024 x 2048)
    __hip_bfloat16* zpage = FT    + (size_t)DINNER * 2048;        // 8K elems

    hipMemsetAsync(zpage, 0, 16384, stream);

    // input/weight prep
    cvt_slice_k<<<NTOK * DMODEL / 1024, 256, 0, stream>>>(x, xb, DMODEL, DMODEL / 4);
    cvt_slice_k<<<DMODEL * DINNER / 1024, 256, 0, stream>>>(w_in, W1b, 2 * DINNER, DINNER / 4);
    transpose_bf16_k<<<dim3(DINNER / 32, DMODEL / 32), 256, 0, stream>>>(
        w_in + DINNER, w2T, DMODEL, DINNER, 2 * DINNER);
    transpose_bf16_k<<<dim3(DINNER / 32, 4 * DINNER / 32), 256, 0, stream>>>(
        conv_k, convT, 4 * DINNER, DINNER, DINNER);
    transpose_bf16_k<<<dim3(DINNER / 32, DINNER / 32), 256, 0, stream>>>(
        w_del, wdelT, DINNER, DINNER, DINNER);
    transpose_bf16_k<<<dim3(DMODEL / 32, DINNER / 32), 256, 0, stream>>>(
        w_out, woutT, DINNER, DMODEL, DMODEL);

    // fused conv weights: FT[o][tap*512 + dm] = (W1 @ K_tap)[dm][o], row stride 2048
    mgemm<4, 128, 128><<<dim3(DMODEL / 128, DINNER / 128, 4), 256, 0, stream>>>(
        convT, 4 * DINNER, W1b, DINNER, nullptr, FT, nullptr, 4 * DMODEL, DINNER,
        nullptr, nullptr, nullptr, 0, zpage);
    // fused conv+z (dual path): bn<1024 conv (FT, K=2048) -> xcb bf16;
    //                           bn>=1024 z (w2T, K=512)   -> zb bf16
    mgemm<0, 128, 128><<<dim3(2 * DINNER / 128, NTOK / 128), 256, 0, stream>>>(
        xb, DMODEL, FT, 4 * DMODEL, nullptr, xcb, zb, DINNER, 4 * DMODEL,
        conv_b, nullptr, w2T, DMODEL, zpage);
    // Bm, Cm (bf16 xcb)
    bc_k<<<NTOK, 256, 0, stream>>>(xcb, w_B, b_B, w_C, b_C, Bm, Cm);
    // w = softplus(xc@w_delta+b) * xc * decay  (tile 128x64, grid 512)
    mgemm<2, 128, 64><<<dim3(DINNER / 64, NTOK / 128), 256, 0, stream>>>(
        xcb, DINNER, wdelT, DINNER, wbuf, nullptr, nullptr, DINNER, DINNER,
        b_del, xcb, nullptr, 0, zpage);
    // scan
    chunkS_k<<<dim3(2 * NCHUNK, DINNER / 16), 256, 0, stream>>>(wbuf, Bm, S);
    hpre_k<<<dim3(2 * DINNER * DSTATE / 256), 256, 0, stream>>>(S, H);
    intra_k<<<dim3(2 * NCHUNK, DINNER / 64), 256, 0, stream>>>(wbuf, Bm, Cm, H, zb, gb);
    // out = g @ w_out  (tile 64x128, grid 256)
    mgemm<3, 64, 128><<<dim3(DMODEL / 128, NTOK / 64), 256, 0, stream>>>(
        gb, DINNER, woutT, DINNER, out, nullptr, nullptr, DMODEL, DINNER,
        nullptr, nullptr, nullptr, 0, zpage);
}

// Round 12
// 223.651 us; speedup vs baseline: 1.5500x; 1.0001x over previous
//
#include <hip/hip_runtime.h>
#include <hip/hip_bf16.h>
#include <math.h>

#define DMODEL 512
#define DINNER 1024
#define DSTATE 16
#define SEQLEN 2048
#define NTOK   4096
#define CHUNK  64
#define NCHUNK (SEQLEN / CHUNK)  // 32

typedef __bf16 bf16x8 __attribute__((ext_vector_type(8)));
typedef float  f32x4  __attribute__((ext_vector_type(4)));

__device__ __forceinline__ float silu_f(float x) {
    return x / (1.0f + __expf(-x));
}

// swizzled LDS index (bf16 elems) for row r, 16B slot s (8 slots per 64-elem row)
__device__ __forceinline__ int swz(int r, int s) {
    return r * 64 + ((s ^ (r & 7)) << 3);
}

// async global->LDS 16B; LDS dest is wave-uniform base + lane*16
__device__ __forceinline__ void gload16(const void* g, void* l) {
    __builtin_amdgcn_global_load_lds(
        (const __attribute__((address_space(1))) void*)g,
        (__attribute__((address_space(3))) void*)l, 16, 0, 0);
}

// ---------------------------------------------------------------------------
// bf16 MFMA GEMM, tile TBM x TBN, BK=64, 4 waves (2x2), gload_lds staging,
// linear LDS + source-side XOR swizzle (involution) + same swizzle on ds_read.
// MODE 0: fused conv+z dual path (conv: tap-shifted rows, OOB -> zpage);
//         n<1024: silu(acc+bias) -> Cb bf16 ; else Czb bf16
// MODE 2: delta — softplus(acc+bias[n]) * bf16 xc[m,n] * 0.95^(l+1) -> C0 f32
// MODE 3: plain — C0 = acc (f32)
// MODE 4: fused-weight GEMM — per-tap (blockIdx.z), bf16 store at ldc stride
// ---------------------------------------------------------------------------
template<int MODE, int TBM, int TBN>
__global__ __launch_bounds__(256)
void mgemm(const __hip_bfloat16* __restrict__ A, int lda,
           const __hip_bfloat16* __restrict__ WT, int ldw,
           float* __restrict__ C0, __hip_bfloat16* __restrict__ Cb,
           __hip_bfloat16* __restrict__ Czb, int ldc,
           int K, const float* __restrict__ bias,
           const __hip_bfloat16* __restrict__ xc,
           const __hip_bfloat16* __restrict__ WT2, int ldw2,
           const __hip_bfloat16* __restrict__ zpage)
{
    constexpr int MI = TBM / 32;          // A frags per wave
    constexpr int MJ = TBN / 32;          // B frags per wave
    __shared__ __align__(16) __hip_bfloat16 As[TBM * 64];
    __shared__ __align__(16) __hip_bfloat16 Bs[TBN * 64];

    // bijective XCD swizzle (all launches have nb % 8 == 0)
    const int nb  = gridDim.x * gridDim.y;
    const int lin = blockIdx.y * gridDim.x + blockIdx.x;
    const int cpx = nb >> 3;
    const int sl  = (lin & 7) * cpx + (lin >> 3);
    const int bm  = (sl / gridDim.x) * TBM;
    const int bn  = (sl % gridDim.x) * TBN;

    if (MODE == 4) { A += blockIdx.z * 1024; Cb += blockIdx.z * 512; }

    const bool zblk = (MODE == 0) && (bn >= DINNER);
    const int  bnb  = zblk ? (bn - DINNER) : bn;
    const __hip_bfloat16* Wp = zblk ? WT2 : WT;
    const int  ldwp = zblk ? ldw2 : ldw;
    const int  Keff = zblk ? DMODEL : K;

    const int tid  = threadIdx.x;
    const int wid  = tid >> 6, lane = tid & 63;
    const int wr   = (wid >> 1) * (TBM / 2), wc = (wid & 1) * (TBN / 2);
    const int llo  = lane & 15, lhi = lane >> 4;

    f32x4 acc[MI][MJ] = {};

    // per-lane staging geometry: issue q covers rows q*32 + wid*8 + (lane>>3)
    const int srow0 = wid * 8 + (lane >> 3);
    const int sphys = lane & 7;

    auto stage_tile = [&](int k0) {
#pragma unroll
        for (int q = 0; q < MI; ++q) {
            int row  = q * 32 + srow0;
            int sdat = sphys ^ (row & 7);          // source pre-swizzle (involution)
            const __hip_bfloat16* srcA;
            if (MODE == 0 && !zblk) {
                int kid = k0 >> 9;                 // tap index (512 K per tap)
                int gr  = bm + row;
                int l2  = (gr & (SEQLEN - 1)) + kid - 1;
                srcA = ((unsigned)l2 < (unsigned)SEQLEN)
                     ? A + (size_t)(gr + kid - 1) * lda + (k0 & 511) + sdat * 8
                     : zpage;
            } else {
                srcA = A + (size_t)(bm + row) * lda + k0 + sdat * 8;
            }
            gload16(srcA, &As[q * 2048 + wid * 512]);
        }
#pragma unroll
        for (int q = 0; q < MJ; ++q) {
            int row  = q * 32 + srow0;
            int sdat = sphys ^ (row & 7);
            gload16(Wp + (size_t)(bnb + row) * ldwp + k0 + sdat * 8,
                    &Bs[q * 2048 + wid * 512]);
        }
    };

    const int NT = Keff / 64;
    for (int t = 0; t < NT; ++t) {
        stage_tile(t * 64);
        __syncthreads();                  // drains vmcnt per barrier semantics
#pragma unroll
        for (int kk = 0; kk < 2; ++kk) {
            bf16x8 af[MI], bv[MJ];
#pragma unroll
            for (int i = 0; i < MI; ++i)
                af[i] = *reinterpret_cast<const bf16x8*>(&As[swz(wr + i * 16 + llo, kk * 4 + lhi)]);
#pragma unroll
            for (int j = 0; j < MJ; ++j)
                bv[j] = *reinterpret_cast<const bf16x8*>(&Bs[swz(wc + j * 16 + llo, kk * 4 + lhi)]);
#pragma unroll
            for (int i = 0; i < MI; ++i)
#pragma unroll
                for (int j = 0; j < MJ; ++j)
                    acc[i][j] = __builtin_amdgcn_mfma_f32_16x16x32_bf16(af[i], bv[j], acc[i][j], 0, 0, 0);
        }
        __syncthreads();
    }

#pragma unroll
    for (int i = 0; i < MI; ++i) {
#pragma unroll
        for (int q = 0; q < 4; ++q) {
            int m = bm + wr + i * 16 + lhi * 4 + q;
            float dec = 1.0f;
            if (MODE == 2)
                dec = __expf((float)((m & (SEQLEN - 1)) + 1) * -0.051293294f); // ln 0.95
#pragma unroll
            for (int j = 0; j < MJ; ++j) {
                int nrel = wc + j * 16 + llo;
                int n = bn + nrel;
                float v = acc[i][j][q];
                if (MODE == 0) {
                    if (!zblk) {
                        v = silu_f(v + bias[n]);
                        Cb[(size_t)m * DINNER + n] = __float2bfloat16(v);
                    } else {
                        Czb[(size_t)m * DINNER + bnb + nrel] = __float2bfloat16(v);
                    }
                } else if (MODE == 2) {
                    float d  = v + bias[n];
                    float sp = fmaxf(d, 0.f) + log1pf(__expf(-fabsf(d)));
                    float xcv = __bfloat162float(xc[(size_t)m * DINNER + n]);
                    C0[(size_t)m * ldc + n] = sp * xcv * dec;
                } else if (MODE == 4) {
                    Cb[(size_t)m * ldc + n] = __float2bfloat16(v);
                } else {
                    C0[(size_t)m * ldc + n] = v;
                }
            }
        }
    }
}

// transpose + f32->bf16: out[c][r] = in[r*ldin + c], out row stride R
__global__ __launch_bounds__(256)
void transpose_bf16_k(const float* __restrict__ in, __hip_bfloat16* __restrict__ out,
                      int R, int C, int ldin)
{
    __shared__ float t[32][33];
    int bx = blockIdx.x * 32, by = blockIdx.y * 32;
    int tx = threadIdx.x & 31, ty = threadIdx.x >> 5;
#pragma unroll
    for (int q = 0; q < 4; ++q)
        t[ty + q * 8][tx] = in[(size_t)(by + ty + q * 8) * ldin + bx + tx];
    __syncthreads();
#pragma unroll
    for (int q = 0; q < 4; ++q)
        out[(size_t)(bx + ty + q * 8) * R + by + tx] = __float2bfloat16(t[tx][ty + q * 8]);
}

// f32 -> bf16, first C cols of each row (ldin-strided source)
__global__ __launch_bounds__(256)
void cvt_slice_k(const float* __restrict__ in, __hip_bfloat16* __restrict__ out,
                 int ldin, int c4cnt)
{
    int idx = blockIdx.x * 256 + threadIdx.x;
    int r = idx / c4cnt, c = (idx - r * c4cnt) * 4;
    float4 v = *reinterpret_cast<const float4*>(in + (size_t)r * ldin + c);
    __hip_bfloat16 tmp[4] = {__float2bfloat16(v.x), __float2bfloat16(v.y),
                             __float2bfloat16(v.z), __float2bfloat16(v.w)};
    *reinterpret_cast<ushort4*>(&out[(size_t)r * (c4cnt * 4) + c]) =
        *reinterpret_cast<const ushort4*>(tmp);
}

// Bm = xc@wB + bB ; Cm = xc@wC + bC   (one token per block, bf16 xc)
__global__ __launch_bounds__(256)
void bc_k(const __hip_bfloat16* __restrict__ xc,
          const float* __restrict__ wB, const float* __restrict__ bB,
          const float* __restrict__ wC, const float* __restrict__ bC,
          float* __restrict__ Bm, float* __restrict__ Cm)
{
    __shared__ float xr[DINNER];
    __shared__ float part[8][32];
    int t = blockIdx.x;
    int tid = threadIdx.x;
    {
        ushort4 v = *reinterpret_cast<const ushort4*>(&xc[(size_t)t * DINNER + tid * 4]);
        xr[tid * 4 + 0] = __bfloat162float(*(const __hip_bfloat16*)&v.x);
        xr[tid * 4 + 1] = __bfloat162float(*(const __hip_bfloat16*)&v.y);
        xr[tid * 4 + 2] = __bfloat162float(*(const __hip_bfloat16*)&v.z);
        xr[tid * 4 + 3] = __bfloat162float(*(const __hip_bfloat16*)&v.w);
    }
    __syncthreads();
    int s = tid & 31;
    int p = tid >> 5;
    const float* W = (s < 16) ? wB : wC;
    int col = s & 15;
    float acc = 0.f;
    for (int k = p * 128; k < p * 128 + 128; ++k)
        acc += xr[k] * W[k * DSTATE + col];
    part[p][s] = acc;
    __syncthreads();
    if (tid < 32) {
        float sum = 0.f;
#pragma unroll
        for (int pp = 0; pp < 8; ++pp) sum += part[pp][tid];
        if (tid < 16) Bm[(size_t)t * DSTATE + tid] = sum + bB[tid];
        else          Cm[(size_t)t * DSTATE + (tid - 16)] = sum + bC[tid - 16];
    }
}

// per-chunk state S[bc][n][s] = sum_{t in chunk} w[t,n]*Bm[t,s]
__global__ __launch_bounds__(256)
void chunkS_k(const float* __restrict__ w, const float* __restrict__ Bm,
              float* __restrict__ S)
{
    int bc = blockIdx.x;
    int n0 = blockIdx.y * 16;
    int t0 = bc * CHUNK;
    __shared__ float wsh[CHUNK][16];
    __shared__ float bsh[CHUNK][17];
    int tid = threadIdx.x;
#pragma unroll
    for (int q = 0; q < 4; ++q) {
        int lin = tid + q * 256;
        int j = lin >> 4, col = lin & 15;
        wsh[j][col] = w[(size_t)(t0 + j) * DINNER + n0 + col];
        bsh[j][col] = Bm[(size_t)(t0 + j) * DSTATE + col];
    }
    __syncthreads();
    int ni = tid & 15, s = tid >> 4;
    float acc = 0.f;
#pragma unroll
    for (int j = 0; j < CHUNK; ++j)
        acc += wsh[j][ni] * bsh[j][s];
    S[((size_t)bc * DINNER + n0 + ni) * DSTATE + s] = acc;
}

// exclusive prefix over chunks
__global__ __launch_bounds__(256)
void hpre_k(const float* __restrict__ S, float* __restrict__ H)
{
    int idx = blockIdx.x * 256 + threadIdx.x;
    int b  = idx >> 14;
    int ns = idx & 16383;
    float acc = 0.f;
    for (int c = 0; c < NCHUNK; ++c) {
        size_t off = ((size_t)(b * NCHUNK + c)) * (DINNER * DSTATE) + ns;
        H[off] = acc;
        acc += S[off];
    }
}

// intra-chunk + inter combine + gate -> gb (bf16); z input bf16
__global__ __launch_bounds__(256)
void intra_k(const float* __restrict__ wbuf,
             const float* __restrict__ Bm, const float* __restrict__ Cm,
             const float* __restrict__ H,
             const __hip_bfloat16* __restrict__ zb,
             __hip_bfloat16* __restrict__ gb)
{
    int bc = blockIdx.x;
    int t0 = bc * CHUNK;
    int n0 = blockIdx.y * 64;
    __shared__ float wsh[CHUNK][65];
    __shared__ float Psh[CHUNK][CHUNK + 1];
    __shared__ float bsh[CHUNK][17];
    __shared__ float csh[CHUNK][17];
    int tid = threadIdx.x;
#pragma unroll
    for (int q = 0; q < 16; ++q) {
        int lin = tid + q * 256;
        int j = lin >> 6, col = lin & 63;
        wsh[j][col] = wbuf[(size_t)(t0 + j) * DINNER + n0 + col];
    }
#pragma unroll
    for (int q = 0; q < 4; ++q) {
        int lin = tid + q * 256;
        int j = lin >> 4, sc = lin & 15;
        bsh[j][sc] = Bm[(size_t)(t0 + j) * DSTATE + sc];
        csh[j][sc] = Cm[(size_t)(t0 + j) * DSTATE + sc];
    }
    __syncthreads();
#pragma unroll
    for (int q = 0; q < 16; ++q) {
        int lin = tid + q * 256;
        int l = lin >> 6, t = lin & 63;
        float p = 0.f;
#pragma unroll
        for (int s = 0; s < DSTATE; ++s) p += csh[l][s] * bsh[t][s];
        Psh[l][t] = p;
    }
    __syncthreads();
    int n  = tid & 63;
    int lg = tid >> 6;
    float hv[DSTATE];
#pragma unroll
    for (int s = 0; s < DSTATE; ++s)
        hv[s] = H[(size_t)bc * (DINNER * DSTATE) + (size_t)(n0 + n) * DSTATE + s];
#pragma unroll
    for (int q = 0; q < 16; ++q) {
        int l = lg * 16 + q;
        float y = 0.f;
#pragma unroll
        for (int s = 0; s < DSTATE; ++s) y += hv[s] * csh[l][s];
        for (int t = 0; t <= l; ++t) y += Psh[l][t] * wsh[t][n];
        int token = t0 + l;
        float z = __bfloat162float(zb[(size_t)token * DINNER + n0 + n]);
        gb[(size_t)token * DINNER + n0 + n] = __float2bfloat16(y * silu_f(z));
    }
}

extern "C" void kernel_launch(void* const* d_in, const int* in_sizes, int n_in,
                              void* d_out, int out_size, void* d_ws, size_t ws_size,
                              hipStream_t stream) {
    const float* x      = (const float*)d_in[0];
    const float* w_in   = (const float*)d_in[1];
    const float* conv_k = (const float*)d_in[2];
    const float* conv_b = (const float*)d_in[3];
    const float* w_del  = (const float*)d_in[4];
    const float* b_del  = (const float*)d_in[5];
    const float* w_B    = (const float*)d_in[6];
    const float* b_B    = (const float*)d_in[7];
    const float* w_C    = (const float*)d_in[8];
    const float* b_C    = (const float*)d_in[9];
    const float* w_out  = (const float*)d_in[11];
    float* out = (float*)d_out;

    // f32 region
    float* wbuf  = (float*)d_ws;                          // 4M
    float* Bm    = wbuf  + (size_t)NTOK * DINNER;
    float* Cm    = Bm    + (size_t)NTOK * DSTATE;
    float* S     = Cm    + (size_t)NTOK * DSTATE;         // 1M
    float* H     = S     + (size_t)2 * NCHUNK * DINNER * DSTATE;  // 1M
    // bf16 region
    __hip_bfloat16* xb    = (__hip_bfloat16*)(H + (size_t)2 * NCHUNK * DINNER * DSTATE);
    __hip_bfloat16* xcb   = xb    + (size_t)NTOK * DMODEL;        // 4M elems
    __hip_bfloat16* zb    = xcb   + (size_t)NTOK * DINNER;        // 4M
    __hip_bfloat16* gb    = zb    + (size_t)NTOK * DINNER;        // 4M
    __hip_bfloat16* W1b   = gb    + (size_t)NTOK * DINNER;        // 0.5M
    __hip_bfloat16* w2T   = W1b   + (size_t)DMODEL * DINNER;      // 0.5M
    __hip_bfloat16* convT = w2T   + (size_t)DINNER * DMODEL;      // 4M
    __hip_bfloat16* wdelT = convT + (size_t)4 * DINNER * DINNER;  // 1M
    __hip_bfloat16* woutT = wdelT + (size_t)DINNER * DINNER;      // 0.5M
    __hip_bfloat16* FT    = woutT + (size_t)DINNER * DMODEL;      // 2M (1024 x 2048)
    __hip_bfloat16* zpage = FT    + (size_t)DINNER * 2048;        // 8K elems

    hipMemsetAsync(zpage, 0, 16384, stream);

    // input/weight prep
    cvt_slice_k<<<NTOK * DMODEL / 1024, 256, 0, stream>>>(x, xb, DMODEL, DMODEL / 4);
    cvt_slice_k<<<DMODEL * DINNER / 1024, 256, 0, stream>>>(w_in, W1b, 2 * DINNER, DINNER / 4);
    transpose_bf16_k<<<dim3(DINNER / 32, DMODEL / 32), 256, 0, stream>>>(
        w_in + DINNER, w2T, DMODEL, DINNER, 2 * DINNER);
    transpose_bf16_k<<<dim3(DINNER / 32, 4 * DINNER / 32), 256, 0, stream>>>(
        conv_k, convT, 4 * DINNER, DINNER, DINNER);
    transpose_bf16_k<<<dim3(DINNER / 32, DINNER / 32), 256, 0, stream>>>(
        w_del, wdelT, DINNER, DINNER, DINNER);
    transpose_bf16_k<<<dim3(DMODEL / 32, DINNER / 32), 256, 0, stream>>>(
        w_out, woutT, DINNER, DMODEL, DMODEL);

    // fused conv weights: FT[o][tap*512 + dm] = (W1 @ K_tap)[dm][o], row stride 2048
    mgemm<4, 128, 128><<<dim3(DMODEL / 128, DINNER / 128, 4), 256, 0, stream>>>(
        convT, 4 * DINNER, W1b, DINNER, nullptr, FT, nullptr, 4 * DMODEL, DINNER,
        nullptr, nullptr, nullptr, 0, zpage);
    // fused conv+z (dual path): bn<1024 conv (FT, K=2048) -> xcb bf16;
    //                           bn>=1024 z (w2T, K=512)   -> zb bf16
    mgemm<0, 128, 128><<<dim3(2 * DINNER / 128, NTOK / 128), 256, 0, stream>>>(
        xb, DMODEL, FT, 4 * DMODEL, nullptr, xcb, zb, DINNER, 4 * DMODEL,
        conv_b, nullptr, w2T, DMODEL, zpage);
    // Bm, Cm (bf16 xcb)
    bc_k<<<NTOK, 256, 0, stream>>>(xcb, w_B, b_B, w_C, b_C, Bm, Cm);
    // w = softplus(xc@w_delta+b) * xc * decay  (tile 128x64, grid 512)
    mgemm<2, 128, 64><<<dim3(DINNER / 64, NTOK / 128), 256, 0, stream>>>(
        xcb, DINNER, wdelT, DINNER, wbuf, nullptr, nullptr, DINNER, DINNER,
        b_del, xcb, nullptr, 0, zpage);
    // scan
    chunkS_k<<<dim3(2 * NCHUNK, DINNER / 16), 256, 0, stream>>>(wbuf, Bm, S);
    hpre_k<<<dim3(2 * DINNER * DSTATE / 256), 256, 0, stream>>>(S, H);
    intra_k<<<dim3(2 * NCHUNK, DINNER / 64), 256, 0, stream>>>(wbuf, Bm, Cm, H, zb, gb);
    // out = g @ w_out  (tile 64x128, grid 256)
    mgemm<3, 64, 128><<<dim3(DMODEL / 128, NTOK / 64), 256, 0, stream>>>(
        gb, DINNER, woutT, DINNER, out, nullptr, nullptr, DMODEL, DINNER,
        nullptr, nullptr, nullptr, 0, zpage);
}

// Round 13
// 213.594 us; speedup vs baseline: 1.6229x; 1.0471x over previous
//
#include <hip/hip_runtime.h>
#include <hip/hip_bf16.h>
#include <math.h>

#define DMODEL 512
#define DINNER 1024
#define DSTATE 16
#define SEQLEN 2048
#define NTOK   4096
#define CHUNK  64
#define NCHUNK (SEQLEN / CHUNK)  // 32

typedef __bf16 bf16x8 __attribute__((ext_vector_type(8)));
typedef float  f32x4  __attribute__((ext_vector_type(4)));

__device__ __forceinline__ float silu_f(float x) {
    return x / (1.0f + __expf(-x));
}

// swizzled LDS index (bf16 elems) for row r, 16B slot s (8 slots per 64-elem row)
__device__ __forceinline__ int swz(int r, int s) {
    return r * 64 + ((s ^ (r & 7)) << 3);
}

// async global->LDS 16B; LDS dest is wave-uniform base + lane*16
__device__ __forceinline__ void gload16(const void* g, void* l) {
    __builtin_amdgcn_global_load_lds(
        (const __attribute__((address_space(1))) void*)g,
        (__attribute__((address_space(3))) void*)l, 16, 0, 0);
}

// ---------------------------------------------------------------------------
// bf16 MFMA GEMM, tile TBM x TBN, BK=64, 4 waves (2x2), gload_lds staging,
// DOUBLE-BUFFERED LDS, one barrier per K-tile: {bar; stage(t+1); compute(t)}.
// Linear LDS + source-side XOR swizzle (involution) + same swizzle on ds_read.
// MODE 0: fused conv+z dual path (conv: tap-shifted rows, OOB -> zpage);
//         n<1024: silu(acc+bias) -> Cb bf16 ; else Czb bf16
// MODE 2: delta+BC — n<1024: softplus(acc+bias[n])*xc[m,n]*0.95^(l+1) -> C0;
//         n in [1024,1040): Bm = acc+bB ; [1040,1056): Cm = acc+bC ; else drop
// MODE 3: plain — C0 = acc (f32)
// MODE 4: fused-weight GEMM — per-tap (blockIdx.z), bf16 store at ldc stride
// ---------------------------------------------------------------------------
template<int MODE, int TBM, int TBN>
__global__ __launch_bounds__(256)
void mgemm(const __hip_bfloat16* __restrict__ A, int lda,
           const __hip_bfloat16* __restrict__ WT, int ldw,
           float* __restrict__ C0, __hip_bfloat16* __restrict__ Cb,
           __hip_bfloat16* __restrict__ Czb, int ldc,
           int K, const float* __restrict__ bias,
           const __hip_bfloat16* __restrict__ xc,
           const __hip_bfloat16* __restrict__ WT2, int ldw2,
           const __hip_bfloat16* __restrict__ zpage,
           const float* __restrict__ bB, const float* __restrict__ bC,
           float* __restrict__ BmO, float* __restrict__ CmO)
{
    constexpr int MI = TBM / 32;          // A frags per wave
    constexpr int MJ = TBN / 32;          // B frags per wave
    __shared__ __align__(16) __hip_bfloat16 As[2 * TBM * 64];
    __shared__ __align__(16) __hip_bfloat16 Bs[2 * TBN * 64];

    // bijective XCD swizzle (all launches have nb % 8 == 0)
    const int nb  = gridDim.x * gridDim.y;
    const int lin = blockIdx.y * gridDim.x + blockIdx.x;
    const int cpx = nb >> 3;
    const int sl  = (lin & 7) * cpx + (lin >> 3);
    const int bm  = (sl / gridDim.x) * TBM;
    const int bn  = (sl % gridDim.x) * TBN;

    if (MODE == 4) { A += blockIdx.z * 1024; Cb += blockIdx.z * 512; }

    const bool zblk = (MODE == 0) && (bn >= DINNER);
    const int  bnb  = zblk ? (bn - DINNER) : bn;
    const __hip_bfloat16* Wp = zblk ? WT2 : WT;
    const int  ldwp = zblk ? ldw2 : ldw;
    const int  Keff = zblk ? DMODEL : K;

    const int tid  = threadIdx.x;
    const int wid  = tid >> 6, lane = tid & 63;
    const int wr   = (wid >> 1) * (TBM / 2), wc = (wid & 1) * (TBN / 2);
    const int llo  = lane & 15, lhi = lane >> 4;

    f32x4 acc[MI][MJ] = {};

    // per-lane staging geometry: issue q covers rows q*32 + wid*8 + (lane>>3)
    const int srow0 = wid * 8 + (lane >> 3);
    const int sphys = lane & 7;

    auto stage_tile = [&](int k0, int buf) {
        __hip_bfloat16* Ad = As + buf * (TBM * 64);
        __hip_bfloat16* Bd = Bs + buf * (TBN * 64);
#pragma unroll
        for (int q = 0; q < MI; ++q) {
            int row  = q * 32 + srow0;
            int sdat = sphys ^ (row & 7);          // source pre-swizzle (involution)
            const __hip_bfloat16* srcA;
            if (MODE == 0 && !zblk) {
                int kid = k0 >> 9;                 // tap index (512 K per tap)
                int gr  = bm + row;
                int l2  = (gr & (SEQLEN - 1)) + kid - 1;
                srcA = ((unsigned)l2 < (unsigned)SEQLEN)
                     ? A + (size_t)(gr + kid - 1) * lda + (k0 & 511) + sdat * 8
                     : zpage;
            } else {
                srcA = A + (size_t)(bm + row) * lda + k0 + sdat * 8;
            }
            gload16(srcA, &Ad[q * 2048 + wid * 512]);
        }
#pragma unroll
        for (int q = 0; q < MJ; ++q) {
            int row  = q * 32 + srow0;
            int sdat = sphys ^ (row & 7);
            gload16(Wp + (size_t)(bnb + row) * ldwp + k0 + sdat * 8,
                    &Bd[q * 2048 + wid * 512]);
        }
    };

    const int NT = Keff / 64;
    stage_tile(0, 0);
    for (int t = 0; t < NT; ++t) {
        __syncthreads();                  // drains stage(t)'s loads (vmcnt), syncs waves
        if (t + 1 < NT) stage_tile((t + 1) * 64, (t + 1) & 1);  // overlaps with MFMA below
        const __hip_bfloat16* Ab = As + (t & 1) * (TBM * 64);
        const __hip_bfloat16* Bb = Bs + (t & 1) * (TBN * 64);
#pragma unroll
        for (int kk = 0; kk < 2; ++kk) {
            bf16x8 af[MI], bv[MJ];
#pragma unroll
            for (int i = 0; i < MI; ++i)
                af[i] = *reinterpret_cast<const bf16x8*>(&Ab[swz(wr + i * 16 + llo, kk * 4 + lhi)]);
#pragma unroll
            for (int j = 0; j < MJ; ++j)
                bv[j] = *reinterpret_cast<const bf16x8*>(&Bb[swz(wc + j * 16 + llo, kk * 4 + lhi)]);
#pragma unroll
            for (int i = 0; i < MI; ++i)
#pragma unroll
                for (int j = 0; j < MJ; ++j)
                    acc[i][j] = __builtin_amdgcn_mfma_f32_16x16x32_bf16(af[i], bv[j], acc[i][j], 0, 0, 0);
        }
    }

#pragma unroll
    for (int i = 0; i < MI; ++i) {
#pragma unroll
        for (int q = 0; q < 4; ++q) {
            int m = bm + wr + i * 16 + lhi * 4 + q;
            float dec = 1.0f;
            if (MODE == 2)
                dec = __expf((float)((m & (SEQLEN - 1)) + 1) * -0.051293294f); // ln 0.95
#pragma unroll
            for (int j = 0; j < MJ; ++j) {
                int nrel = wc + j * 16 + llo;
                int n = bn + nrel;
                float v = acc[i][j][q];
                if (MODE == 0) {
                    if (!zblk) {
                        v = silu_f(v + bias[n]);
                        Cb[(size_t)m * DINNER + n] = __float2bfloat16(v);
                    } else {
                        Czb[(size_t)m * DINNER + bnb + nrel] = __float2bfloat16(v);
                    }
                } else if (MODE == 2) {
                    if (n < DINNER) {
                        float d  = v + bias[n];
                        float sp = fmaxf(d, 0.f) + log1pf(__expf(-fabsf(d)));
                        float xcv = __bfloat162float(xc[(size_t)m * DINNER + n]);
                        C0[(size_t)m * ldc + n] = sp * xcv * dec;
                    } else {
                        int col = n - DINNER;
                        if (col < 16)
                            BmO[(size_t)m * DSTATE + col] = v + bB[col];
                        else if (col < 32)
                            CmO[(size_t)m * DSTATE + (col - 16)] = v + bC[col - 16];
                    }
                } else if (MODE == 4) {
                    Cb[(size_t)m * ldc + n] = __float2bfloat16(v);
                } else {
                    C0[(size_t)m * ldc + n] = v;
                }
            }
        }
    }
}

// transpose + f32->bf16: out[c][r] = in[r*ldin + c], out row stride R
__global__ __launch_bounds__(256)
void transpose_bf16_k(const float* __restrict__ in, __hip_bfloat16* __restrict__ out,
                      int R, int C, int ldin)
{
    __shared__ float t[32][33];
    int bx = blockIdx.x * 32, by = blockIdx.y * 32;
    int tx = threadIdx.x & 31, ty = threadIdx.x >> 5;
#pragma unroll
    for (int q = 0; q < 4; ++q)
        t[ty + q * 8][tx] = in[(size_t)(by + ty + q * 8) * ldin + bx + tx];
    __syncthreads();
#pragma unroll
    for (int q = 0; q < 4; ++q)
        out[(size_t)(bx + ty + q * 8) * R + by + tx] = __float2bfloat16(t[tx][ty + q * 8]);
}

// f32 -> bf16, first C cols of each row (ldin-strided source)
__global__ __launch_bounds__(256)
void cvt_slice_k(const float* __restrict__ in, __hip_bfloat16* __restrict__ out,
                 int ldin, int c4cnt)
{
    int idx = blockIdx.x * 256 + threadIdx.x;
    int r = idx / c4cnt, c = (idx - r * c4cnt) * 4;
    float4 v = *reinterpret_cast<const float4*>(in + (size_t)r * ldin + c);
    __hip_bfloat16 tmp[4] = {__float2bfloat16(v.x), __float2bfloat16(v.y),
                             __float2bfloat16(v.z), __float2bfloat16(v.w)};
    *reinterpret_cast<ushort4*>(&out[(size_t)r * (c4cnt * 4) + c]) =
        *reinterpret_cast<const ushort4*>(tmp);
}

// append wB^T/wC^T (bf16) at rows 1024.. of wdelT_ext: row 1024+sel*16+s, col k
__global__ __launch_bounds__(256)
void bcw_k(const float* __restrict__ wB, const float* __restrict__ wC,
           __hip_bfloat16* __restrict__ dst)
{
    int idx = blockIdx.x * 256 + threadIdx.x;    // 32768 total
    int sel = idx >> 14;
    int rem = idx & 16383;
    int s = rem >> 10, k = rem & 1023;
    const float* src = sel ? wC : wB;
    dst[(size_t)(1024 + sel * 16 + s) * DINNER + k] =
        __float2bfloat16(src[(size_t)k * DSTATE + s]);
}

// per-chunk state S[bc][n][s] = sum_{t in chunk} w[t,n]*Bm[t,s]
__global__ __launch_bounds__(256)
void chunkS_k(const float* __restrict__ w, const float* __restrict__ Bm,
              float* __restrict__ S)
{
    int bc = blockIdx.x;
    int n0 = blockIdx.y * 16;
    int t0 = bc * CHUNK;
    __shared__ float wsh[CHUNK][16];
    __shared__ float bsh[CHUNK][17];
    int tid = threadIdx.x;
#pragma unroll
    for (int q = 0; q < 4; ++q) {
        int lin = tid + q * 256;
        int j = lin >> 4, col = lin & 15;
        wsh[j][col] = w[(size_t)(t0 + j) * DINNER + n0 + col];
        bsh[j][col] = Bm[(size_t)(t0 + j) * DSTATE + col];
    }
    __syncthreads();
    int ni = tid & 15, s = tid >> 4;
    float acc = 0.f;
#pragma unroll
    for (int j = 0; j < CHUNK; ++j)
        acc += wsh[j][ni] * bsh[j][s];
    S[((size_t)bc * DINNER + n0 + ni) * DSTATE + s] = acc;
}

// exclusive prefix over chunks
__global__ __launch_bounds__(256)
void hpre_k(const float* __restrict__ S, float* __restrict__ H)
{
    int idx = blockIdx.x * 256 + threadIdx.x;
    int b  = idx >> 14;
    int ns = idx & 16383;
    float acc = 0.f;
    for (int c = 0; c < NCHUNK; ++c) {
        size_t off = ((size_t)(b * NCHUNK + c)) * (DINNER * DSTATE) + ns;
        H[off] = acc;
        acc += S[off];
    }
}

// intra-chunk + inter combine + gate -> gb (bf16); z input bf16
__global__ __launch_bounds__(256)
void intra_k(const float* __restrict__ wbuf,
             const float* __restrict__ Bm, const float* __restrict__ Cm,
             const float* __restrict__ H,
             const __hip_bfloat16* __restrict__ zb,
             __hip_bfloat16* __restrict__ gb)
{
    int bc = blockIdx.x;
    int t0 = bc * CHUNK;
    int n0 = blockIdx.y * 64;
    __shared__ float wsh[CHUNK][65];
    __shared__ float Psh[CHUNK][CHUNK + 1];
    __shared__ float bsh[CHUNK][17];
    __shared__ float csh[CHUNK][17];
    int tid = threadIdx.x;
#pragma unroll
    for (int q = 0; q < 16; ++q) {
        int lin = tid + q * 256;
        int j = lin >> 6, col = lin & 63;
        wsh[j][col] = wbuf[(size_t)(t0 + j) * DINNER + n0 + col];
    }
#pragma unroll
    for (int q = 0; q < 4; ++q) {
        int lin = tid + q * 256;
        int j = lin >> 4, sc = lin & 15;
        bsh[j][sc] = Bm[(size_t)(t0 + j) * DSTATE + sc];
        csh[j][sc] = Cm[(size_t)(t0 + j) * DSTATE + sc];
    }
    __syncthreads();
#pragma unroll
    for (int q = 0; q < 16; ++q) {
        int lin = tid + q * 256;
        int l = lin >> 6, t = lin & 63;
        float p = 0.f;
#pragma unroll
        for (int s = 0; s < DSTATE; ++s) p += csh[l][s] * bsh[t][s];
        Psh[l][t] = p;
    }
    __syncthreads();
    int n  = tid & 63;
    int lg = tid >> 6;
    float hv[DSTATE];
#pragma unroll
    for (int s = 0; s < DSTATE; ++s)
        hv[s] = H[(size_t)bc * (DINNER * DSTATE) + (size_t)(n0 + n) * DSTATE + s];
#pragma unroll
    for (int q = 0; q < 16; ++q) {
        int l = lg * 16 + q;
        float y = 0.f;
#pragma unroll
        for (int s = 0; s < DSTATE; ++s) y += hv[s] * csh[l][s];
        for (int t = 0; t <= l; ++t) y += Psh[l][t] * wsh[t][n];
        int token = t0 + l;
        float z = __bfloat162float(zb[(size_t)token * DINNER + n0 + n]);
        gb[(size_t)token * DINNER + n0 + n] = __float2bfloat16(y * silu_f(z));
    }
}

extern "C" void kernel_launch(void* const* d_in, const int* in_sizes, int n_in,
                              void* d_out, int out_size, void* d_ws, size_t ws_size,
                              hipStream_t stream) {
    const float* x      = (const float*)d_in[0];
    const float* w_in   = (const float*)d_in[1];
    const float* conv_k = (const float*)d_in[2];
    const float* conv_b = (const float*)d_in[3];
    const float* w_del  = (const float*)d_in[4];
    const float* b_del  = (const float*)d_in[5];
    const float* w_B    = (const float*)d_in[6];
    const float* b_B    = (const float*)d_in[7];
    const float* w_C    = (const float*)d_in[8];
    const float* b_C    = (const float*)d_in[9];
    const float* w_out  = (const float*)d_in[11];
    float* out = (float*)d_out;

    // f32 region
    float* wbuf  = (float*)d_ws;                          // 4M
    float* Bm    = wbuf  + (size_t)NTOK * DINNER;
    float* Cm    = Bm    + (size_t)NTOK * DSTATE;
    float* S     = Cm    + (size_t)NTOK * DSTATE;         // 1M
    float* H     = S     + (size_t)2 * NCHUNK * DINNER * DSTATE;  // 1M
    // bf16 region
    __hip_bfloat16* xb    = (__hip_bfloat16*)(H + (size_t)2 * NCHUNK * DINNER * DSTATE);
    __hip_bfloat16* xcb   = xb    + (size_t)NTOK * DMODEL;        // 4M elems
    __hip_bfloat16* zb    = xcb   + (size_t)NTOK * DINNER;        // 4M
    __hip_bfloat16* gb    = zb    + (size_t)NTOK * DINNER;        // 4M
    __hip_bfloat16* W1b   = gb    + (size_t)NTOK * DINNER;        // 0.5M
    __hip_bfloat16* w2T   = W1b   + (size_t)DMODEL * DINNER;      // 0.5M
    __hip_bfloat16* convT = w2T   + (size_t)DINNER * DMODEL;      // 4M
    __hip_bfloat16* wdelT = convT + (size_t)4 * DINNER * DINNER;  // 1088 x 1024
    __hip_bfloat16* woutT = wdelT + (size_t)1088 * DINNER;        // 0.5M
    __hip_bfloat16* FT    = woutT + (size_t)DINNER * DMODEL;      // 2M (1024 x 2048)
    __hip_bfloat16* zpage = FT    + (size_t)DINNER * 2048;        // 8K elems

    hipMemsetAsync(zpage, 0, 16384, stream);
    // zero pad rows 1056..1087 of wdelT_ext
    hipMemsetAsync(wdelT + (size_t)1056 * DINNER, 0, 32 * DINNER * 2, stream);

    // input/weight prep
    cvt_slice_k<<<NTOK * DMODEL / 1024, 256, 0, stream>>>(x, xb, DMODEL, DMODEL / 4);
    cvt_slice_k<<<DMODEL * DINNER / 1024, 256, 0, stream>>>(w_in, W1b, 2 * DINNER, DINNER / 4);
    transpose_bf16_k<<<dim3(DINNER / 32, DMODEL / 32), 256, 0, stream>>>(
        w_in + DINNER, w2T, DMODEL, DINNER, 2 * DINNER);
    transpose_bf16_k<<<dim3(DINNER / 32, 4 * DINNER / 32), 256, 0, stream>>>(
        conv_k, convT, 4 * DINNER, DINNER, DINNER);
    transpose_bf16_k<<<dim3(DINNER / 32, DINNER / 32), 256, 0, stream>>>(
        w_del, wdelT, DINNER, DINNER, DINNER);
    bcw_k<<<128, 256, 0, stream>>>(w_B, w_C, wdelT);
    transpose_bf16_k<<<dim3(DMODEL / 32, DINNER / 32), 256, 0, stream>>>(
        w_out, woutT, DINNER, DMODEL, DMODEL);

    // fused conv weights: FT[o][tap*512 + dm] = (W1 @ K_tap)[dm][o], row stride 2048
    mgemm<4, 128, 128><<<dim3(DMODEL / 128, DINNER / 128, 4), 256, 0, stream>>>(
        convT, 4 * DINNER, W1b, DINNER, nullptr, FT, nullptr, 4 * DMODEL, DINNER,
        nullptr, nullptr, nullptr, 0, zpage, nullptr, nullptr, nullptr, nullptr);
    // fused conv+z (dual path): bn<1024 conv (FT, K=2048) -> xcb bf16;
    //                           bn>=1024 z (w2T, K=512)   -> zb bf16
    mgemm<0, 128, 128><<<dim3(2 * DINNER / 128, NTOK / 128), 256, 0, stream>>>(
        xb, DMODEL, FT, 4 * DMODEL, nullptr, xcb, zb, DINNER, 4 * DMODEL,
        conv_b, nullptr, w2T, DMODEL, zpage, nullptr, nullptr, nullptr, nullptr);
    // delta + B/C fused: N=1088 (tile 128x64, grid 17x32=544, %8 ok)
    mgemm<2, 128, 64><<<dim3(1088 / 64, NTOK / 128), 256, 0, stream>>>(
        xcb, DINNER, wdelT, DINNER, wbuf, nullptr, nullptr, DINNER, DINNER,
        b_del, xcb, nullptr, 0, zpage, b_B, b_C, Bm, Cm);
    // scan
    chunkS_k<<<dim3(2 * NCHUNK, DINNER / 16), 256, 0, stream>>>(wbuf, Bm, S);
    hpre_k<<<dim3(2 * DINNER * DSTATE / 256), 256, 0, stream>>>(S, H);
    intra_k<<<dim3(2 * NCHUNK, DINNER / 64), 256, 0, stream>>>(wbuf, Bm, Cm, H, zb, gb);
    // out = g @ w_out  (tile 64x128, grid 256)
    mgemm<3, 64, 128><<<dim3(DMODEL / 128, NTOK / 64), 256, 0, stream>>>(
        gb, DINNER, woutT, DINNER, out, nullptr, nullptr, DMODEL, DINNER,
        nullptr, nullptr, nullptr, 0, zpage, nullptr, nullptr, nullptr, nullptr);
}

// Round 14
// 213.392 us; speedup vs baseline: 1.6245x; 1.0009x over previous
//
#include <hip/hip_runtime.h>
#include <hip/hip_bf16.h>
#include <math.h>

#define DMODEL 512
#define DINNER 1024
#define DSTATE 16
#define SEQLEN 2048
#define NTOK   4096
#define CHUNK  64
#define NCHUNK (SEQLEN / CHUNK)  // 32

typedef __bf16 bf16x8 __attribute__((ext_vector_type(8)));
typedef float  f32x4  __attribute__((ext_vector_type(4)));

__device__ __forceinline__ float silu_f(float x) {
    return x / (1.0f + __expf(-x));
}

// swizzled LDS index (bf16 elems) for row r, 16B slot s (8 slots per 64-elem row)
__device__ __forceinline__ int swz(int r, int s) {
    return r * 64 + ((s ^ (r & 7)) << 3);
}

// async global->LDS 16B; LDS dest is wave-uniform base + lane*16
__device__ __forceinline__ void gload16(const void* g, void* l) {
    __builtin_amdgcn_global_load_lds(
        (const __attribute__((address_space(1))) void*)g,
        (__attribute__((address_space(3))) void*)l, 16, 0, 0);
}

// ---------------------------------------------------------------------------
// bf16 MFMA GEMM, tile TBM x TBN, BK=64, 4 waves (2x2), gload_lds staging,
// DOUBLE-BUFFERED LDS, one barrier per K-tile: {bar; stage(t+1); compute(t)}.
// Linear LDS + source-side XOR swizzle (involution) + same swizzle on ds_read.
// MODE 0: fused conv+z dual path (conv: tap-shifted rows, OOB -> zpage);
//         n<1024: silu(acc+bias) -> Cb bf16 ; else Czb bf16
// MODE 2: delta+BC — n<1024: softplus(acc+bias[n])*xc[m,n]*0.95^(l+1) -> C0;
//         n in [1024,1040): Bm = acc+bB ; [1040,1056): Cm = acc+bC ; else drop
// MODE 3: plain — C0 = acc (f32)
// MODE 4: fused-weight GEMM — per-tap (blockIdx.z), bf16 store at ldc stride
// ---------------------------------------------------------------------------
template<int MODE, int TBM, int TBN>
__global__ __launch_bounds__(256)
void mgemm(const __hip_bfloat16* __restrict__ A, int lda,
           const __hip_bfloat16* __restrict__ WT, int ldw,
           float* __restrict__ C0, __hip_bfloat16* __restrict__ Cb,
           __hip_bfloat16* __restrict__ Czb, int ldc,
           int K, const float* __restrict__ bias,
           const __hip_bfloat16* __restrict__ xc,
           const __hip_bfloat16* __restrict__ WT2, int ldw2,
           const __hip_bfloat16* __restrict__ zpage,
           const float* __restrict__ bB, const float* __restrict__ bC,
           float* __restrict__ BmO, float* __restrict__ CmO)
{
    constexpr int MI = TBM / 32;          // A frags per wave
    constexpr int MJ = TBN / 32;          // B frags per wave
    __shared__ __align__(16) __hip_bfloat16 As[2 * TBM * 64];
    __shared__ __align__(16) __hip_bfloat16 Bs[2 * TBN * 64];

    // bijective XCD swizzle (all launches have nb % 8 == 0)
    const int nb  = gridDim.x * gridDim.y;
    const int lin = blockIdx.y * gridDim.x + blockIdx.x;
    const int cpx = nb >> 3;
    const int sl  = (lin & 7) * cpx + (lin >> 3);
    const int bm  = (sl / gridDim.x) * TBM;
    const int bn  = (sl % gridDim.x) * TBN;

    if (MODE == 4) { A += blockIdx.z * 1024; Cb += blockIdx.z * 512; }

    const bool zblk = (MODE == 0) && (bn >= DINNER);
    const int  bnb  = zblk ? (bn - DINNER) : bn;
    const __hip_bfloat16* Wp = zblk ? WT2 : WT;
    const int  ldwp = zblk ? ldw2 : ldw;
    const int  Keff = zblk ? DMODEL : K;

    const int tid  = threadIdx.x;
    const int wid  = tid >> 6, lane = tid & 63;
    const int wr   = (wid >> 1) * (TBM / 2), wc = (wid & 1) * (TBN / 2);
    const int llo  = lane & 15, lhi = lane >> 4;

    f32x4 acc[MI][MJ] = {};

    // per-lane staging geometry: issue q covers rows q*32 + wid*8 + (lane>>3)
    const int srow0 = wid * 8 + (lane >> 3);
    const int sphys = lane & 7;

    auto stage_tile = [&](int k0, int buf) {
        __hip_bfloat16* Ad = As + buf * (TBM * 64);
        __hip_bfloat16* Bd = Bs + buf * (TBN * 64);
#pragma unroll
        for (int q = 0; q < MI; ++q) {
            int row  = q * 32 + srow0;
            int sdat = sphys ^ (row & 7);          // source pre-swizzle (involution)
            const __hip_bfloat16* srcA;
            if (MODE == 0 && !zblk) {
                int kid = k0 >> 9;                 // tap index (512 K per tap)
                int gr  = bm + row;
                int l2  = (gr & (SEQLEN - 1)) + kid - 1;
                srcA = ((unsigned)l2 < (unsigned)SEQLEN)
                     ? A + (size_t)(gr + kid - 1) * lda + (k0 & 511) + sdat * 8
                     : zpage;
            } else {
                srcA = A + (size_t)(bm + row) * lda + k0 + sdat * 8;
            }
            gload16(srcA, &Ad[q * 2048 + wid * 512]);
        }
#pragma unroll
        for (int q = 0; q < MJ; ++q) {
            int row  = q * 32 + srow0;
            int sdat = sphys ^ (row & 7);
            gload16(Wp + (size_t)(bnb + row) * ldwp + k0 + sdat * 8,
                    &Bd[q * 2048 + wid * 512]);
        }
    };

    const int NT = Keff / 64;
    stage_tile(0, 0);
    for (int t = 0; t < NT; ++t) {
        __syncthreads();                  // drains stage(t)'s loads (vmcnt), syncs waves
        if (t + 1 < NT) stage_tile((t + 1) * 64, (t + 1) & 1);  // overlaps with MFMA below
        const __hip_bfloat16* Ab = As + (t & 1) * (TBM * 64);
        const __hip_bfloat16* Bb = Bs + (t & 1) * (TBN * 64);
#pragma unroll
        for (int kk = 0; kk < 2; ++kk) {
            bf16x8 af[MI], bv[MJ];
#pragma unroll
            for (int i = 0; i < MI; ++i)
                af[i] = *reinterpret_cast<const bf16x8*>(&Ab[swz(wr + i * 16 + llo, kk * 4 + lhi)]);
#pragma unroll
            for (int j = 0; j < MJ; ++j)
                bv[j] = *reinterpret_cast<const bf16x8*>(&Bb[swz(wc + j * 16 + llo, kk * 4 + lhi)]);
#pragma unroll
            for (int i = 0; i < MI; ++i)
#pragma unroll
                for (int j = 0; j < MJ; ++j)
                    acc[i][j] = __builtin_amdgcn_mfma_f32_16x16x32_bf16(af[i], bv[j], acc[i][j], 0, 0, 0);
        }
    }

#pragma unroll
    for (int i = 0; i < MI; ++i) {
#pragma unroll
        for (int q = 0; q < 4; ++q) {
            int m = bm + wr + i * 16 + lhi * 4 + q;
            float dec = 1.0f;
            if (MODE == 2)
                dec = __expf((float)((m & (SEQLEN - 1)) + 1) * -0.051293294f); // ln 0.95
#pragma unroll
            for (int j = 0; j < MJ; ++j) {
                int nrel = wc + j * 16 + llo;
                int n = bn + nrel;
                float v = acc[i][j][q];
                if (MODE == 0) {
                    if (!zblk) {
                        v = silu_f(v + bias[n]);
                        Cb[(size_t)m * DINNER + n] = __float2bfloat16(v);
                    } else {
                        Czb[(size_t)m * DINNER + bnb + nrel] = __float2bfloat16(v);
                    }
                } else if (MODE == 2) {
                    if (n < DINNER) {
                        float d  = v + bias[n];
                        float sp = fmaxf(d, 0.f) + log1pf(__expf(-fabsf(d)));
                        float xcv = __bfloat162float(xc[(size_t)m * DINNER + n]);
                        C0[(size_t)m * ldc + n] = sp * xcv * dec;
                    } else {
                        int col = n - DINNER;
                        if (col < 16)
                            BmO[(size_t)m * DSTATE + col] = v + bB[col];
                        else if (col < 32)
                            CmO[(size_t)m * DSTATE + (col - 16)] = v + bC[col - 16];
                    }
                } else if (MODE == 4) {
                    Cb[(size_t)m * ldc + n] = __float2bfloat16(v);
                } else {
                    C0[(size_t)m * ldc + n] = v;
                }
            }
        }
    }
}

// transpose + f32->bf16: out[c][r] = in[r*ldin + c], out row stride R
__global__ __launch_bounds__(256)
void transpose_bf16_k(const float* __restrict__ in, __hip_bfloat16* __restrict__ out,
                      int R, int C, int ldin)
{
    __shared__ float t[32][33];
    int bx = blockIdx.x * 32, by = blockIdx.y * 32;
    int tx = threadIdx.x & 31, ty = threadIdx.x >> 5;
#pragma unroll
    for (int q = 0; q < 4; ++q)
        t[ty + q * 8][tx] = in[(size_t)(by + ty + q * 8) * ldin + bx + tx];
    __syncthreads();
#pragma unroll
    for (int q = 0; q < 4; ++q)
        out[(size_t)(bx + ty + q * 8) * R + by + tx] = __float2bfloat16(t[tx][ty + q * 8]);
}

// f32 -> bf16, first C cols of each row (ldin-strided source)
__global__ __launch_bounds__(256)
void cvt_slice_k(const float* __restrict__ in, __hip_bfloat16* __restrict__ out,
                 int ldin, int c4cnt)
{
    int idx = blockIdx.x * 256 + threadIdx.x;
    int r = idx / c4cnt, c = (idx - r * c4cnt) * 4;
    float4 v = *reinterpret_cast<const float4*>(in + (size_t)r * ldin + c);
    __hip_bfloat16 tmp[4] = {__float2bfloat16(v.x), __float2bfloat16(v.y),
                             __float2bfloat16(v.z), __float2bfloat16(v.w)};
    *reinterpret_cast<ushort4*>(&out[(size_t)r * (c4cnt * 4) + c]) =
        *reinterpret_cast<const ushort4*>(tmp);
}

// append wB^T/wC^T (bf16) at rows 1024.. of wdelT_ext: row 1024+sel*16+s, col k
__global__ __launch_bounds__(256)
void bcw_k(const float* __restrict__ wB, const float* __restrict__ wC,
           __hip_bfloat16* __restrict__ dst)
{
    int idx = blockIdx.x * 256 + threadIdx.x;    // 32768 total
    int sel = idx >> 14;
    int rem = idx & 16383;
    int s = rem >> 10, k = rem & 1023;
    const float* src = sel ? wC : wB;
    dst[(size_t)(1024 + sel * 16 + s) * DINNER + k] =
        __float2bfloat16(src[(size_t)k * DSTATE + s]);
}

// per-chunk state S[bc][n][s] = sum_{t in chunk} w[t,n]*Bm[t,s]
__global__ __launch_bounds__(256)
void chunkS_k(const float* __restrict__ w, const float* __restrict__ Bm,
              float* __restrict__ S)
{
    int bc = blockIdx.x;
    int n0 = blockIdx.y * 16;
    int t0 = bc * CHUNK;
    __shared__ float wsh[CHUNK][16];
    __shared__ float bsh[CHUNK][17];
    int tid = threadIdx.x;
#pragma unroll
    for (int q = 0; q < 4; ++q) {
        int lin = tid + q * 256;
        int j = lin >> 4, col = lin & 15;
        wsh[j][col] = w[(size_t)(t0 + j) * DINNER + n0 + col];
        bsh[j][col] = Bm[(size_t)(t0 + j) * DSTATE + col];
    }
    __syncthreads();
    int ni = tid & 15, s = tid >> 4;
    float acc = 0.f;
#pragma unroll
    for (int j = 0; j < CHUNK; ++j)
        acc += wsh[j][ni] * bsh[j][s];
    S[((size_t)bc * DINNER + n0 + ni) * DSTATE + s] = acc;
}

// exclusive prefix over chunks
__global__ __launch_bounds__(256)
void hpre_k(const float* __restrict__ S, float* __restrict__ H)
{
    int idx = blockIdx.x * 256 + threadIdx.x;
    int b  = idx >> 14;
    int ns = idx & 16383;
    float acc = 0.f;
    for (int c = 0; c < NCHUNK; ++c) {
        size_t off = ((size_t)(b * NCHUNK + c)) * (DINNER * DSTATE) + ns;
        H[off] = acc;
        acc += S[off];
    }
}

// intra-chunk + inter combine + gate -> gb (bf16); z input bf16
__global__ __launch_bounds__(256)
void intra_k(const float* __restrict__ wbuf,
             const float* __restrict__ Bm, const float* __restrict__ Cm,
             const float* __restrict__ H,
             const __hip_bfloat16* __restrict__ zb,
             __hip_bfloat16* __restrict__ gb)
{
    int bc = blockIdx.x;
    int t0 = bc * CHUNK;
    int n0 = blockIdx.y * 64;
    __shared__ float wsh[CHUNK][65];
    __shared__ float Psh[CHUNK][CHUNK + 1];
    __shared__ float bsh[CHUNK][17];
    __shared__ float csh[CHUNK][17];
    int tid = threadIdx.x;
#pragma unroll
    for (int q = 0; q < 16; ++q) {
        int lin = tid + q * 256;
        int j = lin >> 6, col = lin & 63;
        wsh[j][col] = wbuf[(size_t)(t0 + j) * DINNER + n0 + col];
    }
#pragma unroll
    for (int q = 0; q < 4; ++q) {
        int lin = tid + q * 256;
        int j = lin >> 4, sc = lin & 15;
        bsh[j][sc] = Bm[(size_t)(t0 + j) * DSTATE + sc];
        csh[j][sc] = Cm[(size_t)(t0 + j) * DSTATE + sc];
    }
    __syncthreads();
#pragma unroll
    for (int q = 0; q < 16; ++q) {
        int lin = tid + q * 256;
        int l = lin >> 6, t = lin & 63;
        float p = 0.f;
#pragma unroll
        for (int s = 0; s < DSTATE; ++s) p += csh[l][s] * bsh[t][s];
        Psh[l][t] = p;
    }
    __syncthreads();
    int n  = tid & 63;
    int lg = tid >> 6;
    float hv[DSTATE];
#pragma unroll
    for (int s = 0; s < DSTATE; ++s)
        hv[s] = H[(size_t)bc * (DINNER * DSTATE) + (size_t)(n0 + n) * DSTATE + s];
#pragma unroll
    for (int q = 0; q < 16; ++q) {
        int l = lg * 16 + q;
        float y = 0.f;
#pragma unroll
        for (int s = 0; s < DSTATE; ++s) y += hv[s] * csh[l][s];
        for (int t = 0; t <= l; ++t) y += Psh[l][t] * wsh[t][n];
        int token = t0 + l;
        float z = __bfloat162float(zb[(size_t)token * DINNER + n0 + n]);
        gb[(size_t)token * DINNER + n0 + n] = __float2bfloat16(y * silu_f(z));
    }
}

extern "C" void kernel_launch(void* const* d_in, const int* in_sizes, int n_in,
                              void* d_out, int out_size, void* d_ws, size_t ws_size,
                              hipStream_t stream) {
    const float* x      = (const float*)d_in[0];
    const float* w_in   = (const float*)d_in[1];
    const float* conv_k = (const float*)d_in[2];
    const float* conv_b = (const float*)d_in[3];
    const float* w_del  = (const float*)d_in[4];
    const float* b_del  = (const float*)d_in[5];
    const float* w_B    = (const float*)d_in[6];
    const float* b_B    = (const float*)d_in[7];
    const float* w_C    = (const float*)d_in[8];
    const float* b_C    = (const float*)d_in[9];
    const float* w_out  = (const float*)d_in[11];
    float* out = (float*)d_out;

    // f32 region
    float* wbuf  = (float*)d_ws;                          // 4M
    float* Bm    = wbuf  + (size_t)NTOK * DINNER;
    float* Cm    = Bm    + (size_t)NTOK * DSTATE;
    float* S     = Cm    + (size_t)NTOK * DSTATE;         // 1M
    float* H     = S     + (size_t)2 * NCHUNK * DINNER * DSTATE;  // 1M
    // bf16 region
    __hip_bfloat16* xb    = (__hip_bfloat16*)(H + (size_t)2 * NCHUNK * DINNER * DSTATE);
    __hip_bfloat16* xcb   = xb    + (size_t)NTOK * DMODEL;        // 4M elems
    __hip_bfloat16* zb    = xcb   + (size_t)NTOK * DINNER;        // 4M
    __hip_bfloat16* gb    = zb    + (size_t)NTOK * DINNER;        // 4M
    __hip_bfloat16* W1b   = gb    + (size_t)NTOK * DINNER;        // 0.5M
    __hip_bfloat16* w2T   = W1b   + (size_t)DMODEL * DINNER;      // 0.5M
    __hip_bfloat16* convT = w2T   + (size_t)DINNER * DMODEL;      // 4M
    __hip_bfloat16* wdelT = convT + (size_t)4 * DINNER * DINNER;  // 1088 x 1024
    __hip_bfloat16* woutT = wdelT + (size_t)1088 * DINNER;        // 0.5M
    __hip_bfloat16* FT    = woutT + (size_t)DINNER * DMODEL;      // 2M (1024 x 2048)
    __hip_bfloat16* zpage = FT    + (size_t)DINNER * 2048;        // 8K elems

    hipMemsetAsync(zpage, 0, 16384, stream);
    // zero pad rows 1056..1087 of wdelT_ext
    hipMemsetAsync(wdelT + (size_t)1056 * DINNER, 0, 32 * DINNER * 2, stream);

    // input/weight prep
    cvt_slice_k<<<NTOK * DMODEL / 1024, 256, 0, stream>>>(x, xb, DMODEL, DMODEL / 4);
    cvt_slice_k<<<DMODEL * DINNER / 1024, 256, 0, stream>>>(w_in, W1b, 2 * DINNER, DINNER / 4);
    transpose_bf16_k<<<dim3(DINNER / 32, DMODEL / 32), 256, 0, stream>>>(
        w_in + DINNER, w2T, DMODEL, DINNER, 2 * DINNER);
    transpose_bf16_k<<<dim3(DINNER / 32, 4 * DINNER / 32), 256, 0, stream>>>(
        conv_k, convT, 4 * DINNER, DINNER, DINNER);
    transpose_bf16_k<<<dim3(DINNER / 32, DINNER / 32), 256, 0, stream>>>(
        w_del, wdelT, DINNER, DINNER, DINNER);
    bcw_k<<<128, 256, 0, stream>>>(w_B, w_C, wdelT);
    transpose_bf16_k<<<dim3(DMODEL / 32, DINNER / 32), 256, 0, stream>>>(
        w_out, woutT, DINNER, DMODEL, DMODEL);

    // fused conv weights: FT[o][tap*512 + dm] = (W1 @ K_tap)[dm][o], row stride 2048
    mgemm<4, 128, 128><<<dim3(DMODEL / 128, DINNER / 128, 4), 256, 0, stream>>>(
        convT, 4 * DINNER, W1b, DINNER, nullptr, FT, nullptr, 4 * DMODEL, DINNER,
        nullptr, nullptr, nullptr, 0, zpage, nullptr, nullptr, nullptr, nullptr);
    // fused conv+z (dual path): bn<1024 conv (FT, K=2048) -> xcb bf16;
    //                           bn>=1024 z (w2T, K=512)   -> zb bf16
    mgemm<0, 128, 128><<<dim3(2 * DINNER / 128, NTOK / 128), 256, 0, stream>>>(
        xb, DMODEL, FT, 4 * DMODEL, nullptr, xcb, zb, DINNER, 4 * DMODEL,
        conv_b, nullptr, w2T, DMODEL, zpage, nullptr, nullptr, nullptr, nullptr);
    // delta + B/C fused: N=1088 (tile 128x64, grid 17x32=544, %8 ok)
    mgemm<2, 128, 64><<<dim3(1088 / 64, NTOK / 128), 256, 0, stream>>>(
        xcb, DINNER, wdelT, DINNER, wbuf, nullptr, nullptr, DINNER, DINNER,
        b_del, xcb, nullptr, 0, zpage, b_B, b_C, Bm, Cm);
    // scan
    chunkS_k<<<dim3(2 * NCHUNK, DINNER / 16), 256, 0, stream>>>(wbuf, Bm, S);
    hpre_k<<<dim3(2 * DINNER * DSTATE / 256), 256, 0, stream>>>(S, H);
    intra_k<<<dim3(2 * NCHUNK, DINNER / 64), 256, 0, stream>>>(wbuf, Bm, Cm, H, zb, gb);
    // out = g @ w_out  (tile 64x128, grid 256)
    mgemm<3, 64, 128><<<dim3(DMODEL / 128, NTOK / 64), 256, 0, stream>>>(
        gb, DINNER, woutT, DINNER, out, nullptr, nullptr, DMODEL, DINNER,
        nullptr, nullptr, nullptr, 0, zpage, nullptr, nullptr, nullptr, nullptr);
}

// Round 15
// 195.676 us; speedup vs baseline: 1.7716x; 1.0905x over previous
//
#include <hip/hip_runtime.h>
#include <hip/hip_bf16.h>
#include <math.h>

#define DMODEL 512
#define DINNER 1024
#define DSTATE 16
#define SEQLEN 2048
#define NTOK   4096
#define CHUNK  64
#define NCHUNK (SEQLEN / CHUNK)  // 32

typedef __bf16 bf16x8 __attribute__((ext_vector_type(8)));
typedef float  f32x4  __attribute__((ext_vector_type(4)));

__device__ __forceinline__ float silu_f(float x) {
    return x / (1.0f + __expf(-x));
}

// swizzled LDS index (bf16 elems) for row r, 16B slot s (8 slots per 64-elem row)
__device__ __forceinline__ int swz(int r, int s) {
    return r * 64 + ((s ^ (r & 7)) << 3);
}

// async global->LDS 16B; LDS dest is wave-uniform base + lane*16
__device__ __forceinline__ void gload16(const void* g, void* l) {
    __builtin_amdgcn_global_load_lds(
        (const __attribute__((address_space(1))) void*)g,
        (__attribute__((address_space(3))) void*)l, 16, 0, 0);
}

// ---------------------------------------------------------------------------
// bf16 MFMA GEMM, tile TBM x TBN, BK=64, 4 waves (2x2), gload_lds staging,
// double-buffered LDS, one barrier per K-tile: {bar; stage(t+1); compute(t)}.
// Linear LDS + source-side XOR swizzle (involution) + same swizzle on ds_read.
// MODE 0: fused conv+z dual path (conv: tap-shifted rows, OOB -> zpage);
//         n<1024: silu(acc+bias) -> Cb bf16 ; else Czb bf16
// MODE 2: delta+BC — n<1024: softplus(acc+bias[n])*xc[m,n]*0.95^(l+1) -> Cb bf16;
//         n in [1024,1040): Bm = acc+bB ; [1040,1056): Cm = acc+bC ; else drop
// MODE 3: plain — C0 = acc (f32)
// MODE 4: fused-weight GEMM — per-tap (blockIdx.z), bf16 store at ldc stride
// ---------------------------------------------------------------------------
template<int MODE, int TBM, int TBN>
__global__ __launch_bounds__(256)
void mgemm(const __hip_bfloat16* __restrict__ A, int lda,
           const __hip_bfloat16* __restrict__ WT, int ldw,
           float* __restrict__ C0, __hip_bfloat16* __restrict__ Cb,
           __hip_bfloat16* __restrict__ Czb, int ldc,
           int K, const float* __restrict__ bias,
           const __hip_bfloat16* __restrict__ xc,
           const __hip_bfloat16* __restrict__ WT2, int ldw2,
           const __hip_bfloat16* __restrict__ zpage,
           const float* __restrict__ bB, const float* __restrict__ bC,
           float* __restrict__ BmO, float* __restrict__ CmO)
{
    constexpr int MI = TBM / 32;          // A staging issues / frags per wave
    constexpr int MJ = TBN / 32;          // B staging issues / frags per wave
    __shared__ __align__(16) __hip_bfloat16 As[2 * TBM * 64];
    __shared__ __align__(16) __hip_bfloat16 Bs[2 * TBN * 64];

    // bijective XCD swizzle (all launches have nb % 8 == 0)
    const int nb  = gridDim.x * gridDim.y;
    const int lin = blockIdx.y * gridDim.x + blockIdx.x;
    const int cpx = nb >> 3;
    const int sl  = (lin & 7) * cpx + (lin >> 3);
    const int bm  = (sl / gridDim.x) * TBM;
    const int bn  = (sl % gridDim.x) * TBN;

    if (MODE == 4) { A += blockIdx.z * 1024; Cb += blockIdx.z * 512; }

    const bool zblk = (MODE == 0) && (bn >= DINNER);
    const int  bnb  = zblk ? (bn - DINNER) : bn;
    const __hip_bfloat16* Wp = zblk ? WT2 : WT;
    const int  ldwp = zblk ? ldw2 : ldw;
    const int  Keff = zblk ? DMODEL : K;

    const int tid  = threadIdx.x;
    const int wid  = tid >> 6, lane = tid & 63;
    const int wr   = (wid >> 1) * (TBM / 2), wc = (wid & 1) * (TBN / 2);
    const int llo  = lane & 15, lhi = lane >> 4;

    f32x4 acc[MI][MJ] = {};

    // per-lane staging geometry: issue q covers rows q*32 + wid*8 + (lane>>3)
    const int srow0 = wid * 8 + (lane >> 3);
    const int sphys = lane & 7;

    auto stage_tile = [&](int k0, int buf) {
        __hip_bfloat16* Ad = As + buf * (TBM * 64);
        __hip_bfloat16* Bd = Bs + buf * (TBN * 64);
#pragma unroll
        for (int q = 0; q < MI; ++q) {
            int row  = q * 32 + srow0;
            int sdat = sphys ^ (row & 7);          // source pre-swizzle (involution)
            const __hip_bfloat16* srcA;
            if (MODE == 0 && !zblk) {
                int kid = k0 >> 9;                 // tap index (512 K per tap)
                int gr  = bm + row;
                int l2  = (gr & (SEQLEN - 1)) + kid - 1;
                srcA = ((unsigned)l2 < (unsigned)SEQLEN)
                     ? A + (size_t)(gr + kid - 1) * lda + (k0 & 511) + sdat * 8
                     : zpage;
            } else {
                srcA = A + (size_t)(bm + row) * lda + k0 + sdat * 8;
            }
            gload16(srcA, &Ad[q * 2048 + wid * 512]);
        }
#pragma unroll
        for (int q = 0; q < MJ; ++q) {
            int row  = q * 32 + srow0;
            int sdat = sphys ^ (row & 7);
            gload16(Wp + (size_t)(bnb + row) * ldwp + k0 + sdat * 8,
                    &Bd[q * 2048 + wid * 512]);
        }
    };

    const int NT = Keff / 64;
    stage_tile(0, 0);
    for (int t = 0; t < NT; ++t) {
        __syncthreads();                  // drains stage(t)'s loads (vmcnt), syncs waves
        if (t + 1 < NT) stage_tile((t + 1) * 64, (t + 1) & 1);  // overlaps compute below
        const __hip_bfloat16* Ab = As + (t & 1) * (TBM * 64);
        const __hip_bfloat16* Bb = Bs + (t & 1) * (TBN * 64);
#pragma unroll
        for (int kk = 0; kk < 2; ++kk) {
            bf16x8 af[MI], bv[MJ];
#pragma unroll
            for (int i = 0; i < MI; ++i)
                af[i] = *reinterpret_cast<const bf16x8*>(&Ab[swz(wr + i * 16 + llo, kk * 4 + lhi)]);
#pragma unroll
            for (int j = 0; j < MJ; ++j)
                bv[j] = *reinterpret_cast<const bf16x8*>(&Bb[swz(wc + j * 16 + llo, kk * 4 + lhi)]);
#pragma unroll
            for (int i = 0; i < MI; ++i)
#pragma unroll
                for (int j = 0; j < MJ; ++j)
                    acc[i][j] = __builtin_amdgcn_mfma_f32_16x16x32_bf16(af[i], bv[j], acc[i][j], 0, 0, 0);
        }
    }

#pragma unroll
    for (int i = 0; i < MI; ++i) {
#pragma unroll
        for (int q = 0; q < 4; ++q) {
            int m = bm + wr + i * 16 + lhi * 4 + q;
            float dec = 1.0f;
            if (MODE == 2)
                dec = __expf((float)((m & (SEQLEN - 1)) + 1) * -0.051293294f); // ln 0.95
#pragma unroll
            for (int j = 0; j < MJ; ++j) {
                int nrel = wc + j * 16 + llo;
                int n = bn + nrel;
                float v = acc[i][j][q];
                if (MODE == 0) {
                    if (!zblk) {
                        v = silu_f(v + bias[n]);
                        Cb[(size_t)m * DINNER + n] = __float2bfloat16(v);
                    } else {
                        Czb[(size_t)m * DINNER + bnb + nrel] = __float2bfloat16(v);
                    }
                } else if (MODE == 2) {
                    if (n < DINNER) {
                        float d  = v + bias[n];
                        float sp = fmaxf(d, 0.f) + log1pf(__expf(-fabsf(d)));
                        float xcv = __bfloat162float(xc[(size_t)m * DINNER + n]);
                        Cb[(size_t)m * DINNER + n] = __float2bfloat16(sp * xcv * dec);
                    } else {
                        int col = n - DINNER;
                        if (col < 16)
                            BmO[(size_t)m * DSTATE + col] = v + bB[col];
                        else if (col < 32)
                            CmO[(size_t)m * DSTATE + (col - 16)] = v + bC[col - 16];
                    }
                } else if (MODE == 4) {
                    Cb[(size_t)m * ldc + n] = __float2bfloat16(v);
                } else {
                    C0[(size_t)m * ldc + n] = v;
                }
            }
        }
    }
}

// transpose + f32->bf16: out[c][r] = in[r*ldin + c], out row stride R
__global__ __launch_bounds__(256)
void transpose_bf16_k(const float* __restrict__ in, __hip_bfloat16* __restrict__ out,
                      int R, int C, int ldin)
{
    __shared__ float t[32][33];
    int bx = blockIdx.x * 32, by = blockIdx.y * 32;
    int tx = threadIdx.x & 31, ty = threadIdx.x >> 5;
#pragma unroll
    for (int q = 0; q < 4; ++q)
        t[ty + q * 8][tx] = in[(size_t)(by + ty + q * 8) * ldin + bx + tx];
    __syncthreads();
#pragma unroll
    for (int q = 0; q < 4; ++q)
        out[(size_t)(bx + ty + q * 8) * R + by + tx] = __float2bfloat16(t[tx][ty + q * 8]);
}

// f32 -> bf16, first C cols of each row (ldin-strided source)
__global__ __launch_bounds__(256)
void cvt_slice_k(const float* __restrict__ in, __hip_bfloat16* __restrict__ out,
                 int ldin, int c4cnt)
{
    int idx = blockIdx.x * 256 + threadIdx.x;
    int r = idx / c4cnt, c = (idx - r * c4cnt) * 4;
    float4 v = *reinterpret_cast<const float4*>(in + (size_t)r * ldin + c);
    __hip_bfloat16 tmp[4] = {__float2bfloat16(v.x), __float2bfloat16(v.y),
                             __float2bfloat16(v.z), __float2bfloat16(v.w)};
    *reinterpret_cast<ushort4*>(&out[(size_t)r * (c4cnt * 4) + c]) =
        *reinterpret_cast<const ushort4*>(tmp);
}

// append wB^T/wC^T (bf16) at rows 1024.. of wdelT_ext: row 1024+sel*16+s, col k
__global__ __launch_bounds__(256)
void bcw_k(const float* __restrict__ wB, const float* __restrict__ wC,
           __hip_bfloat16* __restrict__ dst)
{
    int idx = blockIdx.x * 256 + threadIdx.x;    // 32768 total
    int sel = idx >> 14;
    int rem = idx & 16383;
    int s = rem >> 10, k = rem & 1023;
    const float* src = sel ? wC : wB;
    dst[(size_t)(1024 + sel * 16 + s) * DINNER + k] =
        __float2bfloat16(src[(size_t)k * DSTATE + s]);
}

// per-chunk state S[bc][n][s] = sum_{t in chunk} w[t,n]*Bm[t,s]  (bf16 w)
__global__ __launch_bounds__(256)
void chunkS_k(const __hip_bfloat16* __restrict__ w, const float* __restrict__ Bm,
              float* __restrict__ S)
{
    int bc = blockIdx.x;
    int n0 = blockIdx.y * 16;
    int t0 = bc * CHUNK;
    __shared__ float wsh[CHUNK][16];
    __shared__ float bsh[CHUNK][17];
    int tid = threadIdx.x;
#pragma unroll
    for (int q = 0; q < 4; ++q) {
        int lin = tid + q * 256;
        int j = lin >> 4, col = lin & 15;
        wsh[j][col] = __bfloat162float(w[(size_t)(t0 + j) * DINNER + n0 + col]);
        bsh[j][col] = Bm[(size_t)(t0 + j) * DSTATE + col];
    }
    __syncthreads();
    int ni = tid & 15, s = tid >> 4;
    float acc = 0.f;
#pragma unroll
    for (int j = 0; j < CHUNK; ++j)
        acc += wsh[j][ni] * bsh[j][s];
    S[((size_t)bc * DINNER + n0 + ni) * DSTATE + s] = acc;
}

// exclusive prefix over chunks
__global__ __launch_bounds__(256)
void hpre_k(const float* __restrict__ S, float* __restrict__ H)
{
    int idx = blockIdx.x * 256 + threadIdx.x;
    int b  = idx >> 14;
    int ns = idx & 16383;
    float acc = 0.f;
    for (int c = 0; c < NCHUNK; ++c) {
        size_t off = ((size_t)(b * NCHUNK + c)) * (DINNER * DSTATE) + ns;
        H[off] = acc;
        acc += S[off];
    }
}

// intra-chunk + inter combine + gate -> gb (bf16); w and z inputs bf16
__global__ __launch_bounds__(256)
void intra_k(const __hip_bfloat16* __restrict__ wb,
             const float* __restrict__ Bm, const float* __restrict__ Cm,
             const float* __restrict__ H,
             const __hip_bfloat16* __restrict__ zb,
             __hip_bfloat16* __restrict__ gb)
{
    int bc = blockIdx.x;
    int t0 = bc * CHUNK;
    int n0 = blockIdx.y * 64;
    __shared__ float wsh[CHUNK][65];
    __shared__ float Psh[CHUNK][CHUNK + 1];
    __shared__ float bsh[CHUNK][17];
    __shared__ float csh[CHUNK][17];
    int tid = threadIdx.x;
#pragma unroll
    for (int q = 0; q < 4; ++q) {
        int idx2 = tid + q * 256;            // 1024 4-col chunks
        int j = idx2 >> 4, c4 = (idx2 & 15) * 4;
        ushort4 v = *reinterpret_cast<const ushort4*>(
            &wb[(size_t)(t0 + j) * DINNER + n0 + c4]);
        wsh[j][c4 + 0] = __bfloat162float(*(const __hip_bfloat16*)&v.x);
        wsh[j][c4 + 1] = __bfloat162float(*(const __hip_bfloat16*)&v.y);
        wsh[j][c4 + 2] = __bfloat162float(*(const __hip_bfloat16*)&v.z);
        wsh[j][c4 + 3] = __bfloat162float(*(const __hip_bfloat16*)&v.w);
    }
#pragma unroll
    for (int q = 0; q < 4; ++q) {
        int lin = tid + q * 256;
        int j = lin >> 4, sc = lin & 15;
        bsh[j][sc] = Bm[(size_t)(t0 + j) * DSTATE + sc];
        csh[j][sc] = Cm[(size_t)(t0 + j) * DSTATE + sc];
    }
    __syncthreads();
#pragma unroll
    for (int q = 0; q < 16; ++q) {
        int lin = tid + q * 256;
        int l = lin >> 6, t = lin & 63;
        float p = 0.f;
#pragma unroll
        for (int s = 0; s < DSTATE; ++s) p += csh[l][s] * bsh[t][s];
        Psh[l][t] = p;
    }
    __syncthreads();
    int n  = tid & 63;
    int lg = tid >> 6;
    float hv[DSTATE];
#pragma unroll
    for (int s = 0; s < DSTATE; ++s)
        hv[s] = H[(size_t)bc * (DINNER * DSTATE) + (size_t)(n0 + n) * DSTATE + s];
#pragma unroll
    for (int q = 0; q < 16; ++q) {
        int l = lg * 16 + q;
        float y = 0.f;
#pragma unroll
        for (int s = 0; s < DSTATE; ++s) y += hv[s] * csh[l][s];
        for (int t = 0; t <= l; ++t) y += Psh[l][t] * wsh[t][n];
        int token = t0 + l;
        float z = __bfloat162float(zb[(size_t)token * DINNER + n0 + n]);
        gb[(size_t)token * DINNER + n0 + n] = __float2bfloat16(y * silu_f(z));
    }
}

extern "C" void kernel_launch(void* const* d_in, const int* in_sizes, int n_in,
                              void* d_out, int out_size, void* d_ws, size_t ws_size,
                              hipStream_t stream) {
    const float* x      = (const float*)d_in[0];
    const float* w_in   = (const float*)d_in[1];
    const float* conv_k = (const float*)d_in[2];
    const float* conv_b = (const float*)d_in[3];
    const float* w_del  = (const float*)d_in[4];
    const float* b_del  = (const float*)d_in[5];
    const float* w_B    = (const float*)d_in[6];
    const float* b_B    = (const float*)d_in[7];
    const float* w_C    = (const float*)d_in[8];
    const float* b_C    = (const float*)d_in[9];
    const float* w_out  = (const float*)d_in[11];
    float* out = (float*)d_out;

    // f32 region
    float* Bm    = (float*)d_ws;
    float* Cm    = Bm + (size_t)NTOK * DSTATE;
    float* S     = Cm + (size_t)NTOK * DSTATE;            // 1M
    float* H     = S  + (size_t)2 * NCHUNK * DINNER * DSTATE;  // 1M
    // bf16 region
    __hip_bfloat16* xb    = (__hip_bfloat16*)(H + (size_t)2 * NCHUNK * DINNER * DSTATE);
    __hip_bfloat16* xcb   = xb    + (size_t)NTOK * DMODEL;        // 4M elems
    __hip_bfloat16* zb    = xcb   + (size_t)NTOK * DINNER;        // 4M
    __hip_bfloat16* gb    = zb    + (size_t)NTOK * DINNER;        // 4M
    __hip_bfloat16* wbufb = gb    + (size_t)NTOK * DINNER;        // 4M
    __hip_bfloat16* W1b   = wbufb + (size_t)NTOK * DINNER;        // 0.5M
    __hip_bfloat16* w2T   = W1b   + (size_t)DMODEL * DINNER;      // 0.5M
    __hip_bfloat16* convT = w2T   + (size_t)DINNER * DMODEL;      // 4M
    __hip_bfloat16* wdelT = convT + (size_t)4 * DINNER * DINNER;  // 1088 x 1024
    __hip_bfloat16* woutT = wdelT + (size_t)1088 * DINNER;        // 0.5M
    __hip_bfloat16* FT    = woutT + (size_t)DINNER * DMODEL;      // 2M (1024 x 2048)
    __hip_bfloat16* zpage = FT    + (size_t)DINNER * 2048;        // 8K elems

    hipMemsetAsync(zpage, 0, 16384, stream);
    // zero pad rows 1056..1087 of wdelT_ext
    hipMemsetAsync(wdelT + (size_t)1056 * DINNER, 0, 32 * DINNER * 2, stream);

    // input/weight prep
    cvt_slice_k<<<NTOK * DMODEL / 1024, 256, 0, stream>>>(x, xb, DMODEL, DMODEL / 4);
    cvt_slice_k<<<DMODEL * DINNER / 1024, 256, 0, stream>>>(w_in, W1b, 2 * DINNER, DINNER / 4);
    transpose_bf16_k<<<dim3(DINNER / 32, DMODEL / 32), 256, 0, stream>>>(
        w_in + DINNER, w2T, DMODEL, DINNER, 2 * DINNER);
    transpose_bf16_k<<<dim3(DINNER / 32, 4 * DINNER / 32), 256, 0, stream>>>(
        conv_k, convT, 4 * DINNER, DINNER, DINNER);
    transpose_bf16_k<<<dim3(DINNER / 32, DINNER / 32), 256, 0, stream>>>(
        w_del, wdelT, DINNER, DINNER, DINNER);
    bcw_k<<<128, 256, 0, stream>>>(w_B, w_C, wdelT);
    transpose_bf16_k<<<dim3(DMODEL / 32, DINNER / 32), 256, 0, stream>>>(
        w_out, woutT, DINNER, DMODEL, DMODEL);

    // fused conv weights: FT[o][tap*512 + dm] = (W1 @ K_tap)[dm][o], row stride 2048
    // tile 64x64, grid (8,16,4) = 512 blocks
    mgemm<4, 64, 64><<<dim3(DMODEL / 64, DINNER / 64, 4), 256, 0, stream>>>(
        convT, 4 * DINNER, W1b, DINNER, nullptr, FT, nullptr, 4 * DMODEL, DINNER,
        nullptr, nullptr, nullptr, 0, zpage, nullptr, nullptr, nullptr, nullptr);
    // fused conv+z (dual path): bn<1024 conv (FT, K=2048) -> xcb bf16;
    //                           bn>=1024 z (w2T, K=512)   -> zb bf16
    // tile 128x64, grid (32,32) = 1024 blocks (3 blocks/CU resident + queue)
    mgemm<0, 128, 64><<<dim3(2 * DINNER / 64, NTOK / 128), 256, 0, stream>>>(
        xb, DMODEL, FT, 4 * DMODEL, nullptr, xcb, zb, DINNER, 4 * DMODEL,
        conv_b, nullptr, w2T, DMODEL, zpage, nullptr, nullptr, nullptr, nullptr);
    // delta + B/C fused: N=1088 (tile 128x64, grid 17x32=544); w -> bf16 wbufb
    mgemm<2, 128, 64><<<dim3(1088 / 64, NTOK / 128), 256, 0, stream>>>(
        xcb, DINNER, wdelT, DINNER, nullptr, wbufb, nullptr, DINNER, DINNER,
        b_del, xcb, nullptr, 0, zpage, b_B, b_C, Bm, Cm);
    // scan
    chunkS_k<<<dim3(2 * NCHUNK, DINNER / 16), 256, 0, stream>>>(wbufb, Bm, S);
    hpre_k<<<dim3(2 * DINNER * DSTATE / 256), 256, 0, stream>>>(S, H);
    intra_k<<<dim3(2 * NCHUNK, DINNER / 64), 256, 0, stream>>>(wbufb, Bm, Cm, H, zb, gb);
    // out = g @ w_out  (tile 64x64, grid (8,64) = 512 blocks)
    mgemm<3, 64, 64><<<dim3(DMODEL / 64, NTOK / 64), 256, 0, stream>>>(
        gb, DINNER, woutT, DINNER, out, nullptr, nullptr, DMODEL, DINNER,
        nullptr, nullptr, nullptr, 0, zpage, nullptr, nullptr, nullptr, nullptr);
}

// Round 16
// 193.939 us; speedup vs baseline: 1.7874x; 1.0090x over previous
//
#include <hip/hip_runtime.h>
#include <hip/hip_bf16.h>
#include <math.h>

#define DMODEL 512
#define DINNER 1024
#define DSTATE 16
#define SEQLEN 2048
#define NTOK   4096
#define CHUNK  64
#define NCHUNK (SEQLEN / CHUNK)  // 32

typedef __bf16 bf16x8 __attribute__((ext_vector_type(8)));
typedef float  f32x4  __attribute__((ext_vector_type(4)));

__device__ __forceinline__ float silu_f(float x) {
    return x / (1.0f + __expf(-x));
}

// swizzled LDS index (bf16 elems) for row r, 16B slot s (8 slots per 64-elem row)
__device__ __forceinline__ int swz(int r, int s) {
    return r * 64 + ((s ^ (r & 7)) << 3);
}

// async global->LDS 16B; LDS dest is wave-uniform base + lane*16
__device__ __forceinline__ void gload16(const void* g, void* l) {
    __builtin_amdgcn_global_load_lds(
        (const __attribute__((address_space(1))) void*)g,
        (__attribute__((address_space(3))) void*)l, 16, 0, 0);
}

// ---------------------------------------------------------------------------
// bf16 MFMA GEMM, tile TBM x TBN, BK=64, 4 waves (2x2), gload_lds staging,
// SINGLE-buffer LDS (24/16 KB -> 6+ blocks/CU), R12-proven 2-barrier loop:
// {stage(t); bar; MFMA(t); bar}. Cross-block overlap hides the stage drain.
// Linear LDS + source-side XOR swizzle (involution) + same swizzle on ds_read.
// MODE 0: fused conv+z dual path (conv: tap-shifted rows, OOB -> zpage);
//         n<1024: silu(acc+bias) -> Cb bf16 ; else Czb bf16
// MODE 2: delta+BC — n<1024: softplus(acc+bias[n])*xc[m,n]*0.95^(l+1) -> Cb bf16;
//         n in [1024,1040): Bm = acc+bB ; [1040,1056): Cm = acc+bC ; else drop
// MODE 3: plain — C0 = acc (f32)
// MODE 4: fused-weight GEMM — per-tap (blockIdx.z), bf16 store at ldc stride
// ---------------------------------------------------------------------------
template<int MODE, int TBM, int TBN>
__global__ __launch_bounds__(256)
void mgemm(const __hip_bfloat16* __restrict__ A, int lda,
           const __hip_bfloat16* __restrict__ WT, int ldw,
           float* __restrict__ C0, __hip_bfloat16* __restrict__ Cb,
           __hip_bfloat16* __restrict__ Czb, int ldc,
           int K, const float* __restrict__ bias,
           const __hip_bfloat16* __restrict__ xc,
           const __hip_bfloat16* __restrict__ WT2, int ldw2,
           const __hip_bfloat16* __restrict__ zpage,
           const float* __restrict__ bB, const float* __restrict__ bC,
           float* __restrict__ BmO, float* __restrict__ CmO)
{
    constexpr int MI = TBM / 32;          // A staging issues / frags per wave
    constexpr int MJ = TBN / 32;          // B staging issues / frags per wave
    __shared__ __align__(16) __hip_bfloat16 As[TBM * 64];
    __shared__ __align__(16) __hip_bfloat16 Bs[TBN * 64];

    // bijective XCD swizzle (all launches have nb % 8 == 0)
    const int nb  = gridDim.x * gridDim.y;
    const int lin = blockIdx.y * gridDim.x + blockIdx.x;
    const int cpx = nb >> 3;
    const int sl  = (lin & 7) * cpx + (lin >> 3);
    const int bm  = (sl / gridDim.x) * TBM;
    const int bn  = (sl % gridDim.x) * TBN;

    if (MODE == 4) { A += blockIdx.z * 1024; Cb += blockIdx.z * 512; }

    const bool zblk = (MODE == 0) && (bn >= DINNER);
    const int  bnb  = zblk ? (bn - DINNER) : bn;
    const __hip_bfloat16* Wp = zblk ? WT2 : WT;
    const int  ldwp = zblk ? ldw2 : ldw;
    const int  Keff = zblk ? DMODEL : K;

    const int tid  = threadIdx.x;
    const int wid  = tid >> 6, lane = tid & 63;
    const int wr   = (wid >> 1) * (TBM / 2), wc = (wid & 1) * (TBN / 2);
    const int llo  = lane & 15, lhi = lane >> 4;

    f32x4 acc[MI][MJ] = {};

    // per-lane staging geometry: issue q covers rows q*32 + wid*8 + (lane>>3)
    const int srow0 = wid * 8 + (lane >> 3);
    const int sphys = lane & 7;

    auto stage_tile = [&](int k0) {
#pragma unroll
        for (int q = 0; q < MI; ++q) {
            int row  = q * 32 + srow0;
            int sdat = sphys ^ (row & 7);          // source pre-swizzle (involution)
            const __hip_bfloat16* srcA;
            if (MODE == 0 && !zblk) {
                int kid = k0 >> 9;                 // tap index (512 K per tap)
                int gr  = bm + row;
                int l2  = (gr & (SEQLEN - 1)) + kid - 1;
                srcA = ((unsigned)l2 < (unsigned)SEQLEN)
                     ? A + (size_t)(gr + kid - 1) * lda + (k0 & 511) + sdat * 8
                     : zpage;
            } else {
                srcA = A + (size_t)(bm + row) * lda + k0 + sdat * 8;
            }
            gload16(srcA, &As[q * 2048 + wid * 512]);
        }
#pragma unroll
        for (int q = 0; q < MJ; ++q) {
            int row  = q * 32 + srow0;
            int sdat = sphys ^ (row & 7);
            gload16(Wp + (size_t)(bnb + row) * ldwp + k0 + sdat * 8,
                    &Bs[q * 2048 + wid * 512]);
        }
    };

    const int NT = Keff / 64;
    for (int t = 0; t < NT; ++t) {
        stage_tile(t * 64);
        __syncthreads();                  // drains vmcnt per barrier semantics
#pragma unroll
        for (int kk = 0; kk < 2; ++kk) {
            bf16x8 af[MI], bv[MJ];
#pragma unroll
            for (int i = 0; i < MI; ++i)
                af[i] = *reinterpret_cast<const bf16x8*>(&As[swz(wr + i * 16 + llo, kk * 4 + lhi)]);
#pragma unroll
            for (int j = 0; j < MJ; ++j)
                bv[j] = *reinterpret_cast<const bf16x8*>(&Bs[swz(wc + j * 16 + llo, kk * 4 + lhi)]);
#pragma unroll
            for (int i = 0; i < MI; ++i)
#pragma unroll
                for (int j = 0; j < MJ; ++j)
                    acc[i][j] = __builtin_amdgcn_mfma_f32_16x16x32_bf16(af[i], bv[j], acc[i][j], 0, 0, 0);
        }
        __syncthreads();
    }

#pragma unroll
    for (int i = 0; i < MI; ++i) {
#pragma unroll
        for (int q = 0; q < 4; ++q) {
            int m = bm + wr + i * 16 + lhi * 4 + q;
            float dec = 1.0f;
            if (MODE == 2)
                dec = __expf((float)((m & (SEQLEN - 1)) + 1) * -0.051293294f); // ln 0.95
#pragma unroll
            for (int j = 0; j < MJ; ++j) {
                int nrel = wc + j * 16 + llo;
                int n = bn + nrel;
                float v = acc[i][j][q];
                if (MODE == 0) {
                    if (!zblk) {
                        v = silu_f(v + bias[n]);
                        Cb[(size_t)m * DINNER + n] = __float2bfloat16(v);
                    } else {
                        Czb[(size_t)m * DINNER + bnb + nrel] = __float2bfloat16(v);
                    }
                } else if (MODE == 2) {
                    if (n < DINNER) {
                        float d  = v + bias[n];
                        float sp = fmaxf(d, 0.f) + log1pf(__expf(-fabsf(d)));
                        float xcv = __bfloat162float(xc[(size_t)m * DINNER + n]);
                        Cb[(size_t)m * DINNER + n] = __float2bfloat16(sp * xcv * dec);
                    } else {
                        int col = n - DINNER;
                        if (col < 16)
                            BmO[(size_t)m * DSTATE + col] = v + bB[col];
                        else if (col < 32)
                            CmO[(size_t)m * DSTATE + (col - 16)] = v + bC[col - 16];
                    }
                } else if (MODE == 4) {
                    Cb[(size_t)m * ldc + n] = __float2bfloat16(v);
                } else {
                    C0[(size_t)m * ldc + n] = v;
                }
            }
        }
    }
}

// transpose + f32->bf16: out[c][r] = in[r*ldin + c], out row stride R
__global__ __launch_bounds__(256)
void transpose_bf16_k(const float* __restrict__ in, __hip_bfloat16* __restrict__ out,
                      int R, int C, int ldin)
{
    __shared__ float t[32][33];
    int bx = blockIdx.x * 32, by = blockIdx.y * 32;
    int tx = threadIdx.x & 31, ty = threadIdx.x >> 5;
#pragma unroll
    for (int q = 0; q < 4; ++q)
        t[ty + q * 8][tx] = in[(size_t)(by + ty + q * 8) * ldin + bx + tx];
    __syncthreads();
#pragma unroll
    for (int q = 0; q < 4; ++q)
        out[(size_t)(bx + ty + q * 8) * R + by + tx] = __float2bfloat16(t[tx][ty + q * 8]);
}

// f32 -> bf16, first C cols of each row (ldin-strided source)
__global__ __launch_bounds__(256)
void cvt_slice_k(const float* __restrict__ in, __hip_bfloat16* __restrict__ out,
                 int ldin, int c4cnt)
{
    int idx = blockIdx.x * 256 + threadIdx.x;
    int r = idx / c4cnt, c = (idx - r * c4cnt) * 4;
    float4 v = *reinterpret_cast<const float4*>(in + (size_t)r * ldin + c);
    __hip_bfloat16 tmp[4] = {__float2bfloat16(v.x), __float2bfloat16(v.y),
                             __float2bfloat16(v.z), __float2bfloat16(v.w)};
    *reinterpret_cast<ushort4*>(&out[(size_t)r * (c4cnt * 4) + c]) =
        *reinterpret_cast<const ushort4*>(tmp);
}

// append wB^T/wC^T (bf16) at rows 1024.. of wdelT_ext: row 1024+sel*16+s, col k
__global__ __launch_bounds__(256)
void bcw_k(const float* __restrict__ wB, const float* __restrict__ wC,
           __hip_bfloat16* __restrict__ dst)
{
    int idx = blockIdx.x * 256 + threadIdx.x;    // 32768 total
    int sel = idx >> 14;
    int rem = idx & 16383;
    int s = rem >> 10, k = rem & 1023;
    const float* src = sel ? wC : wB;
    dst[(size_t)(1024 + sel * 16 + s) * DINNER + k] =
        __float2bfloat16(src[(size_t)k * DSTATE + s]);
}

// per-chunk state S[bc][n][s] = sum_{t in chunk} w[t,n]*Bm[t,s]  (bf16 w)
__global__ __launch_bounds__(256)
void chunkS_k(const __hip_bfloat16* __restrict__ w, const float* __restrict__ Bm,
              float* __restrict__ S)
{
    int bc = blockIdx.x;
    int n0 = blockIdx.y * 16;
    int t0 = bc * CHUNK;
    __shared__ float wsh[CHUNK][16];
    __shared__ float bsh[CHUNK][17];
    int tid = threadIdx.x;
#pragma unroll
    for (int q = 0; q < 4; ++q) {
        int lin = tid + q * 256;
        int j = lin >> 4, col = lin & 15;
        wsh[j][col] = __bfloat162float(w[(size_t)(t0 + j) * DINNER + n0 + col]);
        bsh[j][col] = Bm[(size_t)(t0 + j) * DSTATE + col];
    }
    __syncthreads();
    int ni = tid & 15, s = tid >> 4;
    float acc = 0.f;
#pragma unroll
    for (int j = 0; j < CHUNK; ++j)
        acc += wsh[j][ni] * bsh[j][s];
    S[((size_t)bc * DINNER + n0 + ni) * DSTATE + s] = acc;
}

// exclusive prefix over chunks
__global__ __launch_bounds__(256)
void hpre_k(const float* __restrict__ S, float* __restrict__ H)
{
    int idx = blockIdx.x * 256 + threadIdx.x;
    int b  = idx >> 14;
    int ns = idx & 16383;
    float acc = 0.f;
    for (int c = 0; c < NCHUNK; ++c) {
        size_t off = ((size_t)(b * NCHUNK + c)) * (DINNER * DSTATE) + ns;
        H[off] = acc;
        acc += S[off];
    }
}

// intra-chunk + inter combine + gate -> gb (bf16); w and z inputs bf16
__global__ __launch_bounds__(256)
void intra_k(const __hip_bfloat16* __restrict__ wb,
             const float* __restrict__ Bm, const float* __restrict__ Cm,
             const float* __restrict__ H,
             const __hip_bfloat16* __restrict__ zb,
             __hip_bfloat16* __restrict__ gb)
{
    int bc = blockIdx.x;
    int t0 = bc * CHUNK;
    int n0 = blockIdx.y * 64;
    __shared__ float wsh[CHUNK][65];
    __shared__ float Psh[CHUNK][CHUNK + 1];
    __shared__ float bsh[CHUNK][17];
    __shared__ float csh[CHUNK][17];
    int tid = threadIdx.x;
#pragma unroll
    for (int q = 0; q < 4; ++q) {
        int idx2 = tid + q * 256;            // 1024 4-col chunks
        int j = idx2 >> 4, c4 = (idx2 & 15) * 4;
        ushort4 v = *reinterpret_cast<const ushort4*>(
            &wb[(size_t)(t0 + j) * DINNER + n0 + c4]);
        wsh[j][c4 + 0] = __bfloat162float(*(const __hip_bfloat16*)&v.x);
        wsh[j][c4 + 1] = __bfloat162float(*(const __hip_bfloat16*)&v.y);
        wsh[j][c4 + 2] = __bfloat162float(*(const __hip_bfloat16*)&v.z);
        wsh[j][c4 + 3] = __bfloat162float(*(const __hip_bfloat16*)&v.w);
    }
#pragma unroll
    for (int q = 0; q < 4; ++q) {
        int lin = tid + q * 256;
        int j = lin >> 4, sc = lin & 15;
        bsh[j][sc] = Bm[(size_t)(t0 + j) * DSTATE + sc];
        csh[j][sc] = Cm[(size_t)(t0 + j) * DSTATE + sc];
    }
    __syncthreads();
#pragma unroll
    for (int q = 0; q < 16; ++q) {
        int lin = tid + q * 256;
        int l = lin >> 6, t = lin & 63;
        float p = 0.f;
#pragma unroll
        for (int s = 0; s < DSTATE; ++s) p += csh[l][s] * bsh[t][s];
        Psh[l][t] = p;
    }
    __syncthreads();
    int n  = tid & 63;
    int lg = tid >> 6;
    float hv[DSTATE];
#pragma unroll
    for (int s = 0; s < DSTATE; ++s)
        hv[s] = H[(size_t)bc * (DINNER * DSTATE) + (size_t)(n0 + n) * DSTATE + s];
#pragma unroll
    for (int q = 0; q < 16; ++q) {
        int l = lg * 16 + q;
        float y = 0.f;
#pragma unroll
        for (int s = 0; s < DSTATE; ++s) y += hv[s] * csh[l][s];
        for (int t = 0; t <= l; ++t) y += Psh[l][t] * wsh[t][n];
        int token = t0 + l;
        float z = __bfloat162float(zb[(size_t)token * DINNER + n0 + n]);
        gb[(size_t)token * DINNER + n0 + n] = __float2bfloat16(y * silu_f(z));
    }
}

extern "C" void kernel_launch(void* const* d_in, const int* in_sizes, int n_in,
                              void* d_out, int out_size, void* d_ws, size_t ws_size,
                              hipStream_t stream) {
    const float* x      = (const float*)d_in[0];
    const float* w_in   = (const float*)d_in[1];
    const float* conv_k = (const float*)d_in[2];
    const float* conv_b = (const float*)d_in[3];
    const float* w_del  = (const float*)d_in[4];
    const float* b_del  = (const float*)d_in[5];
    const float* w_B    = (const float*)d_in[6];
    const float* b_B    = (const float*)d_in[7];
    const float* w_C    = (const float*)d_in[8];
    const float* b_C    = (const float*)d_in[9];
    const float* w_out  = (const float*)d_in[11];
    float* out = (float*)d_out;

    // f32 region
    float* Bm    = (float*)d_ws;
    float* Cm    = Bm + (size_t)NTOK * DSTATE;
    float* S     = Cm + (size_t)NTOK * DSTATE;            // 1M
    float* H     = S  + (size_t)2 * NCHUNK * DINNER * DSTATE;  // 1M
    // bf16 region
    __hip_bfloat16* xb    = (__hip_bfloat16*)(H + (size_t)2 * NCHUNK * DINNER * DSTATE);
    __hip_bfloat16* xcb   = xb    + (size_t)NTOK * DMODEL;        // 4M elems
    __hip_bfloat16* zb    = xcb   + (size_t)NTOK * DINNER;        // 4M
    __hip_bfloat16* gb    = zb    + (size_t)NTOK * DINNER;        // 4M
    __hip_bfloat16* wbufb = gb    + (size_t)NTOK * DINNER;        // 4M
    __hip_bfloat16* W1b   = wbufb + (size_t)NTOK * DINNER;        // 0.5M
    __hip_bfloat16* w2T   = W1b   + (size_t)DMODEL * DINNER;      // 0.5M
    __hip_bfloat16* convT = w2T   + (size_t)DINNER * DMODEL;      // 4M
    __hip_bfloat16* wdelT = convT + (size_t)4 * DINNER * DINNER;  // 1088 x 1024
    __hip_bfloat16* woutT = wdelT + (size_t)1088 * DINNER;        // 0.5M
    __hip_bfloat16* FT    = woutT + (size_t)DINNER * DMODEL;      // 2M (1024 x 2048)
    __hip_bfloat16* zpage = FT    + (size_t)DINNER * 2048;        // 8K elems

    hipMemsetAsync(zpage, 0, 16384, stream);
    // zero pad rows 1056..1087 of wdelT_ext
    hipMemsetAsync(wdelT + (size_t)1056 * DINNER, 0, 32 * DINNER * 2, stream);

    // input/weight prep
    cvt_slice_k<<<NTOK * DMODEL / 1024, 256, 0, stream>>>(x, xb, DMODEL, DMODEL / 4);
    cvt_slice_k<<<DMODEL * DINNER / 1024, 256, 0, stream>>>(w_in, W1b, 2 * DINNER, DINNER / 4);
    transpose_bf16_k<<<dim3(DINNER / 32, DMODEL / 32), 256, 0, stream>>>(
        w_in + DINNER, w2T, DMODEL, DINNER, 2 * DINNER);
    transpose_bf16_k<<<dim3(DINNER / 32, 4 * DINNER / 32), 256, 0, stream>>>(
        conv_k, convT, 4 * DINNER, DINNER, DINNER);
    transpose_bf16_k<<<dim3(DINNER / 32, DINNER / 32), 256, 0, stream>>>(
        w_del, wdelT, DINNER, DINNER, DINNER);
    bcw_k<<<128, 256, 0, stream>>>(w_B, w_C, wdelT);
    transpose_bf16_k<<<dim3(DMODEL / 32, DINNER / 32), 256, 0, stream>>>(
        w_out, woutT, DINNER, DMODEL, DMODEL);

    // fused conv weights: FT[o][tap*512 + dm] = (W1 @ K_tap)[dm][o], row stride 2048
    // tile 64x64, grid (8,16,4) = 512 blocks
    mgemm<4, 64, 64><<<dim3(DMODEL / 64, DINNER / 64, 4), 256, 0, stream>>>(
        convT, 4 * DINNER, W1b, DINNER, nullptr, FT, nullptr, 4 * DMODEL, DINNER,
        nullptr, nullptr, nullptr, 0, zpage, nullptr, nullptr, nullptr, nullptr);
    // fused conv+z (dual path): bn<1024 conv (FT, K=2048) -> xcb bf16;
    //                           bn>=1024 z (w2T, K=512)   -> zb bf16
    // tile 128x64, grid (32,32) = 1024 blocks; 24 KB LDS -> 6 blocks/CU
    mgemm<0, 128, 64><<<dim3(2 * DINNER / 64, NTOK / 128), 256, 0, stream>>>(
        xb, DMODEL, FT, 4 * DMODEL, nullptr, xcb, zb, DINNER, 4 * DMODEL,
        conv_b, nullptr, w2T, DMODEL, zpage, nullptr, nullptr, nullptr, nullptr);
    // delta + B/C fused: N=1088 (tile 128x64, grid 17x32=544); w -> bf16 wbufb
    mgemm<2, 128, 64><<<dim3(1088 / 64, NTOK / 128), 256, 0, stream>>>(
        xcb, DINNER, wdelT, DINNER, nullptr, wbufb, nullptr, DINNER, DINNER,
        b_del, xcb, nullptr, 0, zpage, b_B, b_C, Bm, Cm);
    // scan
    chunkS_k<<<dim3(2 * NCHUNK, DINNER / 16), 256, 0, stream>>>(wbufb, Bm, S);
    hpre_k<<<dim3(2 * DINNER * DSTATE / 256), 256, 0, stream>>>(S, H);
    intra_k<<<dim3(2 * NCHUNK, DINNER / 64), 256, 0, stream>>>(wbufb, Bm, Cm, H, zb, gb);
    // out = g @ w_out  (tile 64x64, grid (8,64) = 512 blocks, 16 KB LDS)
    mgemm<3, 64, 64><<<dim3(DMODEL / 64, NTOK / 64), 256, 0, stream>>>(
        gb, DINNER, woutT, DINNER, out, nullptr, nullptr, DMODEL, DINNER,
        nullptr, nullptr, nullptr, 0, zpage, nullptr, nullptr, nullptr, nullptr);
}

// Round 17
// 158.602 us; speedup vs baseline: 2.1857x; 1.2228x over previous
//
#include <hip/hip_runtime.h>
#include <hip/hip_bf16.h>
#include <math.h>

#define DMODEL 512
#define DINNER 1024
#define DSTATE 16
#define SEQLEN 2048
#define NTOK   4096
#define CHUNK  64
#define NCHUNK (SEQLEN / CHUNK)  // 32

typedef __bf16 bf16x8 __attribute__((ext_vector_type(8)));
typedef float  f32x4  __attribute__((ext_vector_type(4)));

__device__ __forceinline__ float silu_f(float x) {
    return x / (1.0f + __expf(-x));
}

// swizzled LDS index (bf16 elems) for row r, 16B slot s (8 slots per 64-elem row)
__device__ __forceinline__ int swz(int r, int s) {
    return r * 64 + ((s ^ (r & 7)) << 3);
}

// async global->LDS 16B; LDS dest is wave-uniform base + lane*16
__device__ __forceinline__ void gload16(const void* g, void* l) {
    __builtin_amdgcn_global_load_lds(
        (const __attribute__((address_space(1))) void*)g,
        (__attribute__((address_space(3))) void*)l, 16, 0, 0);
}

// ---------------------------------------------------------------------------
// bf16 MFMA GEMM, tile TBM x TBN, BK=64, 4 waves (2x2), gload_lds staging,
// single-buffer LDS, R12-proven 2-barrier loop: {stage(t); bar; MFMA(t); bar}.
// Linear LDS + source-side XOR swizzle (involution) + same swizzle on ds_read.
// MODE 0: fused conv+z dual path (conv: tap-shifted rows, OOB -> zpage);
//         n<1024: silu(acc+bias) -> Cb bf16 ; else Czb bf16
// MODE 2: delta+BC — n<1024: softplus(acc+bias[n])*xc[m,n]*0.95^(l+1) -> Cb bf16;
//         n in [1024,1040): Bm = acc+bB ; [1040,1056): Cm = acc+bC ; else drop
// MODE 3: plain — C0 = acc (f32)
// MODE 4: fused-weight GEMM — per-tap (blockIdx.z), bf16 store at ldc stride
// ---------------------------------------------------------------------------
template<int MODE, int TBM, int TBN>
__global__ __launch_bounds__(256)
void mgemm(const __hip_bfloat16* __restrict__ A, int lda,
           const __hip_bfloat16* __restrict__ WT, int ldw,
           float* __restrict__ C0, __hip_bfloat16* __restrict__ Cb,
           __hip_bfloat16* __restrict__ Czb, int ldc,
           int K, const float* __restrict__ bias,
           const __hip_bfloat16* __restrict__ xc,
           const __hip_bfloat16* __restrict__ WT2, int ldw2,
           const __hip_bfloat16* __restrict__ zpage,
           const float* __restrict__ bB, const float* __restrict__ bC,
           float* __restrict__ BmO, float* __restrict__ CmO)
{
    constexpr int MI = TBM / 32;          // A staging issues / frags per wave
    constexpr int MJ = TBN / 32;          // B staging issues / frags per wave
    __shared__ __align__(16) __hip_bfloat16 As[TBM * 64];
    __shared__ __align__(16) __hip_bfloat16 Bs[TBN * 64];

    // bijective XCD swizzle (all launches have nb % 8 == 0)
    const int nb  = gridDim.x * gridDim.y;
    const int lin = blockIdx.y * gridDim.x + blockIdx.x;
    const int cpx = nb >> 3;
    const int sl  = (lin & 7) * cpx + (lin >> 3);
    const int bm  = (sl / gridDim.x) * TBM;
    const int bn  = (sl % gridDim.x) * TBN;

    if (MODE == 4) { A += blockIdx.z * 1024; Cb += blockIdx.z * 512; }

    const bool zblk = (MODE == 0) && (bn >= DINNER);
    const int  bnb  = zblk ? (bn - DINNER) : bn;
    const __hip_bfloat16* Wp = zblk ? WT2 : WT;
    const int  ldwp = zblk ? ldw2 : ldw;
    const int  Keff = zblk ? DMODEL : K;

    const int tid  = threadIdx.x;
    const int wid  = tid >> 6, lane = tid & 63;
    const int wr   = (wid >> 1) * (TBM / 2), wc = (wid & 1) * (TBN / 2);
    const int llo  = lane & 15, lhi = lane >> 4;

    f32x4 acc[MI][MJ] = {};

    // per-lane staging geometry: issue q covers rows q*32 + wid*8 + (lane>>3)
    const int srow0 = wid * 8 + (lane >> 3);
    const int sphys = lane & 7;

    auto stage_tile = [&](int k0) {
#pragma unroll
        for (int q = 0; q < MI; ++q) {
            int row  = q * 32 + srow0;
            int sdat = sphys ^ (row & 7);          // source pre-swizzle (involution)
            const __hip_bfloat16* srcA;
            if (MODE == 0 && !zblk) {
                int kid = k0 >> 9;                 // tap index (512 K per tap)
                int gr  = bm + row;
                int l2  = (gr & (SEQLEN - 1)) + kid - 1;
                srcA = ((unsigned)l2 < (unsigned)SEQLEN)
                     ? A + (size_t)(gr + kid - 1) * lda + (k0 & 511) + sdat * 8
                     : zpage;
            } else {
                srcA = A + (size_t)(bm + row) * lda + k0 + sdat * 8;
            }
            gload16(srcA, &As[q * 2048 + wid * 512]);
        }
#pragma unroll
        for (int q = 0; q < MJ; ++q) {
            int row  = q * 32 + srow0;
            int sdat = sphys ^ (row & 7);
            gload16(Wp + (size_t)(bnb + row) * ldwp + k0 + sdat * 8,
                    &Bs[q * 2048 + wid * 512]);
        }
    };

    const int NT = Keff / 64;
    for (int t = 0; t < NT; ++t) {
        stage_tile(t * 64);
        __syncthreads();                  // drains vmcnt per barrier semantics
#pragma unroll
        for (int kk = 0; kk < 2; ++kk) {
            bf16x8 af[MI], bv[MJ];
#pragma unroll
            for (int i = 0; i < MI; ++i)
                af[i] = *reinterpret_cast<const bf16x8*>(&As[swz(wr + i * 16 + llo, kk * 4 + lhi)]);
#pragma unroll
            for (int j = 0; j < MJ; ++j)
                bv[j] = *reinterpret_cast<const bf16x8*>(&Bs[swz(wc + j * 16 + llo, kk * 4 + lhi)]);
#pragma unroll
            for (int i = 0; i < MI; ++i)
#pragma unroll
                for (int j = 0; j < MJ; ++j)
                    acc[i][j] = __builtin_amdgcn_mfma_f32_16x16x32_bf16(af[i], bv[j], acc[i][j], 0, 0, 0);
        }
        __syncthreads();
    }

#pragma unroll
    for (int i = 0; i < MI; ++i) {
#pragma unroll
        for (int q = 0; q < 4; ++q) {
            int m = bm + wr + i * 16 + lhi * 4 + q;
            float dec = 1.0f;
            if (MODE == 2)
                dec = __expf((float)((m & (SEQLEN - 1)) + 1) * -0.051293294f); // ln 0.95
#pragma unroll
            for (int j = 0; j < MJ; ++j) {
                int nrel = wc + j * 16 + llo;
                int n = bn + nrel;
                float v = acc[i][j][q];
                if (MODE == 0) {
                    if (!zblk) {
                        v = silu_f(v + bias[n]);
                        Cb[(size_t)m * DINNER + n] = __float2bfloat16(v);
                    } else {
                        Czb[(size_t)m * DINNER + bnb + nrel] = __float2bfloat16(v);
                    }
                } else if (MODE == 2) {
                    if (n < DINNER) {
                        float d  = v + bias[n];
                        float sp = fmaxf(d, 0.f) + log1pf(__expf(-fabsf(d)));
                        float xcv = __bfloat162float(xc[(size_t)m * DINNER + n]);
                        Cb[(size_t)m * DINNER + n] = __float2bfloat16(sp * xcv * dec);
                    } else {
                        int col = n - DINNER;
                        if (col < 16)
                            BmO[(size_t)m * DSTATE + col] = v + bB[col];
                        else if (col < 32)
                            CmO[(size_t)m * DSTATE + (col - 16)] = v + bC[col - 16];
                    }
                } else if (MODE == 4) {
                    Cb[(size_t)m * ldc + n] = __float2bfloat16(v);
                } else {
                    C0[(size_t)m * ldc + n] = v;
                }
            }
        }
    }
}

// transpose + f32->bf16: out[c][r] = in[r*ldin + c], out row stride R
__global__ __launch_bounds__(256)
void transpose_bf16_k(const float* __restrict__ in, __hip_bfloat16* __restrict__ out,
                      int R, int C, int ldin)
{
    __shared__ float t[32][33];
    int bx = blockIdx.x * 32, by = blockIdx.y * 32;
    int tx = threadIdx.x & 31, ty = threadIdx.x >> 5;
#pragma unroll
    for (int q = 0; q < 4; ++q)
        t[ty + q * 8][tx] = in[(size_t)(by + ty + q * 8) * ldin + bx + tx];
    __syncthreads();
#pragma unroll
    for (int q = 0; q < 4; ++q)
        out[(size_t)(bx + ty + q * 8) * R + by + tx] = __float2bfloat16(t[tx][ty + q * 8]);
}

// f32 -> bf16, first C cols of each row (ldin-strided source)
__global__ __launch_bounds__(256)
void cvt_slice_k(const float* __restrict__ in, __hip_bfloat16* __restrict__ out,
                 int ldin, int c4cnt)
{
    int idx = blockIdx.x * 256 + threadIdx.x;
    int r = idx / c4cnt, c = (idx - r * c4cnt) * 4;
    float4 v = *reinterpret_cast<const float4*>(in + (size_t)r * ldin + c);
    __hip_bfloat16 tmp[4] = {__float2bfloat16(v.x), __float2bfloat16(v.y),
                             __float2bfloat16(v.z), __float2bfloat16(v.w)};
    *reinterpret_cast<ushort4*>(&out[(size_t)r * (c4cnt * 4) + c]) =
        *reinterpret_cast<const ushort4*>(tmp);
}

// append wB^T/wC^T (bf16) at rows 1024.. of wdelT_ext: row 1024+sel*16+s, col k
__global__ __launch_bounds__(256)
void bcw_k(const float* __restrict__ wB, const float* __restrict__ wC,
           __hip_bfloat16* __restrict__ dst)
{
    int idx = blockIdx.x * 256 + threadIdx.x;    // 32768 total
    int sel = idx >> 14;
    int rem = idx & 16383;
    int s = rem >> 10, k = rem & 1023;
    const float* src = sel ? wC : wB;
    dst[(size_t)(1024 + sel * 16 + s) * DINNER + k] =
        __float2bfloat16(src[(size_t)k * DSTATE + s]);
}

// per-chunk state S[bc][n][s] = sum_{t in chunk} w[t,n]*Bm[t,s]  (bf16 w)
__global__ __launch_bounds__(256)
void chunkS_k(const __hip_bfloat16* __restrict__ w, const float* __restrict__ Bm,
              float* __restrict__ S)
{
    int bc = blockIdx.x;
    int n0 = blockIdx.y * 16;
    int t0 = bc * CHUNK;
    __shared__ float wsh[CHUNK][16];
    __shared__ float bsh[CHUNK][17];
    int tid = threadIdx.x;
#pragma unroll
    for (int q = 0; q < 4; ++q) {
        int lin = tid + q * 256;
        int j = lin >> 4, col = lin & 15;
        wsh[j][col] = __bfloat162float(w[(size_t)(t0 + j) * DINNER + n0 + col]);
        bsh[j][col] = Bm[(size_t)(t0 + j) * DSTATE + col];
    }
    __syncthreads();
    int ni = tid & 15, s = tid >> 4;
    float acc = 0.f;
#pragma unroll
    for (int j = 0; j < CHUNK; ++j)
        acc += wsh[j][ni] * bsh[j][s];
    S[((size_t)bc * DINNER + n0 + ni) * DSTATE + s] = acc;
}

// exclusive prefix over chunks -> bf16 H
__global__ __launch_bounds__(256)
void hpre_k(const float* __restrict__ S, __hip_bfloat16* __restrict__ Hb)
{
    int idx = blockIdx.x * 256 + threadIdx.x;
    int b  = idx >> 14;
    int ns = idx & 16383;
    float acc = 0.f;
    for (int c = 0; c < NCHUNK; ++c) {
        size_t off = ((size_t)(b * NCHUNK + c)) * (DINNER * DSTATE) + ns;
        Hb[off] = __float2bfloat16(acc);
        acc += S[off];
    }
}

// ---------------------------------------------------------------------------
// MFMA intra-chunk: per block (bc, n0-block of 64):
//   P = Cm_chunk @ Bm_chunk^T (64x64, K=16 pad 32), mask t<=l, bf16 -> LDS
//   Y = [P | Cm | 0] (64x96) @ [w^T ; H^T ; 0] -> 64x64 ; g = Y * silu(z)
// ---------------------------------------------------------------------------
__global__ __launch_bounds__(256)
void intra_k(const __hip_bfloat16* __restrict__ wb,
             const float* __restrict__ Bm, const float* __restrict__ Cm,
             const __hip_bfloat16* __restrict__ Hb,
             const __hip_bfloat16* __restrict__ zb,
             __hip_bfloat16* __restrict__ gb)
{
    constexpr int LDP  = 104;   // row stride (elems) for Pb/Wb (96 + pad)
    constexpr int LDC  = 40;    // row stride for csb/bsb (32 + pad)
    __shared__ __align__(16) __hip_bfloat16 csb[64 * LDC];
    __shared__ __align__(16) __hip_bfloat16 bsb[64 * LDC];
    __shared__ __align__(16) __hip_bfloat16 Pb [64 * LDP];
    __shared__ __align__(16) __hip_bfloat16 Wb [64 * LDP];

    const int bc = blockIdx.x;            // b*NCHUNK + c
    const int n0 = blockIdx.y * 64;
    const int t0 = bc * CHUNK;
    const int tid = threadIdx.x;
    const int wid = tid >> 6, lane = tid & 63;
    const int llo = lane & 15, lhi = lane >> 4;
    const int wr = (wid >> 1) * 32, wc = (wid & 1) * 32;
    const __hip_bfloat16 z16 = __float2bfloat16(0.f);

    // ---- stage Cm/Bm (K-padded), H slice, zero pads
#pragma unroll
    for (int q = 0; q < 4; ++q) {
        int idx = tid + q * 256;          // 0..1023
        int j = idx >> 4, s = idx & 15;
        __hip_bfloat16 cb = __float2bfloat16(Cm[(size_t)(t0 + j) * DSTATE + s]);
        csb[j * LDC + s]      = cb;
        csb[j * LDC + 16 + s] = z16;
        bsb[j * LDC + s]      = __float2bfloat16(Bm[(size_t)(t0 + j) * DSTATE + s]);
        bsb[j * LDC + 16 + s] = z16;
        Pb[j * LDP + 64 + s]  = cb;
        Pb[j * LDP + 80 + s]  = z16;
        Wb[j * LDP + 64 + s]  = Hb[((size_t)bc * DINNER + n0 + j) * DSTATE + s];
        Wb[j * LDP + 80 + s]  = z16;
    }
    // ---- w transpose into Wb[n][t]
#pragma unroll
    for (int q = 0; q < 4; ++q) {
        int c = tid + q * 256;            // 0..1023
        int t = c >> 4, c4 = (c & 15) * 4;
        ushort4 v = *reinterpret_cast<const ushort4*>(
            &wb[(size_t)(t0 + t) * DINNER + n0 + c4]);
        Wb[(c4 + 0) * LDP + t] = *(const __hip_bfloat16*)&v.x;
        Wb[(c4 + 1) * LDP + t] = *(const __hip_bfloat16*)&v.y;
        Wb[(c4 + 2) * LDP + t] = *(const __hip_bfloat16*)&v.z;
        Wb[(c4 + 3) * LDP + t] = *(const __hip_bfloat16*)&v.w;
    }
    __syncthreads();

    // ---- P pass: P[l][t] = sum_s Cm[l][s]*Bm[t][s]  (one K=32 step)
    {
        f32x4 pacc[2][2] = {};
        bf16x8 ap[2], bp[2];
#pragma unroll
        for (int i = 0; i < 2; ++i)
            ap[i] = *reinterpret_cast<const bf16x8*>(&csb[(wr + i * 16 + llo) * LDC + lhi * 8]);
#pragma unroll
        for (int j = 0; j < 2; ++j)
            bp[j] = *reinterpret_cast<const bf16x8*>(&bsb[(wc + j * 16 + llo) * LDC + lhi * 8]);
#pragma unroll
        for (int i = 0; i < 2; ++i)
#pragma unroll
            for (int j = 0; j < 2; ++j)
                pacc[i][j] = __builtin_amdgcn_mfma_f32_16x16x32_bf16(ap[i], bp[j], pacc[i][j], 0, 0, 0);
        // mask (t<=l) and store bf16 P
#pragma unroll
        for (int i = 0; i < 2; ++i)
#pragma unroll
            for (int q = 0; q < 4; ++q) {
                int l = wr + i * 16 + lhi * 4 + q;
#pragma unroll
                for (int j = 0; j < 2; ++j) {
                    int t = wc + j * 16 + llo;
                    float pv = (t <= l) ? pacc[i][j][q] : 0.f;
                    Pb[l * LDP + t] = __float2bfloat16(pv);
                }
            }
    }
    __syncthreads();

    // ---- Y pass: K=96 (3 steps of 32)
    f32x4 yacc[2][2] = {};
#pragma unroll
    for (int k0 = 0; k0 < 3; ++k0) {
        bf16x8 af[2], bv[2];
#pragma unroll
        for (int i = 0; i < 2; ++i)
            af[i] = *reinterpret_cast<const bf16x8*>(&Pb[(wr + i * 16 + llo) * LDP + k0 * 32 + lhi * 8]);
#pragma unroll
        for (int j = 0; j < 2; ++j)
            bv[j] = *reinterpret_cast<const bf16x8*>(&Wb[(wc + j * 16 + llo) * LDP + k0 * 32 + lhi * 8]);
#pragma unroll
        for (int i = 0; i < 2; ++i)
#pragma unroll
            for (int j = 0; j < 2; ++j)
                yacc[i][j] = __builtin_amdgcn_mfma_f32_16x16x32_bf16(af[i], bv[j], yacc[i][j], 0, 0, 0);
    }

    // ---- gate + store
#pragma unroll
    for (int i = 0; i < 2; ++i)
#pragma unroll
        for (int q = 0; q < 4; ++q) {
            int l = wr + i * 16 + lhi * 4 + q;
            int token = t0 + l;
#pragma unroll
            for (int j = 0; j < 2; ++j) {
                int n = wc + j * 16 + llo;
                float z = __bfloat162float(zb[(size_t)token * DINNER + n0 + n]);
                gb[(size_t)token * DINNER + n0 + n] =
                    __float2bfloat16(yacc[i][j][q] * silu_f(z));
            }
        }
}

extern "C" void kernel_launch(void* const* d_in, const int* in_sizes, int n_in,
                              void* d_out, int out_size, void* d_ws, size_t ws_size,
                              hipStream_t stream) {
    const float* x      = (const float*)d_in[0];
    const float* w_in   = (const float*)d_in[1];
    const float* conv_k = (const float*)d_in[2];
    const float* conv_b = (const float*)d_in[3];
    const float* w_del  = (const float*)d_in[4];
    const float* b_del  = (const float*)d_in[5];
    const float* w_B    = (const float*)d_in[6];
    const float* b_B    = (const float*)d_in[7];
    const float* w_C    = (const float*)d_in[8];
    const float* b_C    = (const float*)d_in[9];
    const float* w_out  = (const float*)d_in[11];
    float* out = (float*)d_out;

    // f32 region
    float* Bm    = (float*)d_ws;
    float* Cm    = Bm + (size_t)NTOK * DSTATE;
    float* S     = Cm + (size_t)NTOK * DSTATE;            // 1M f32
    // bf16 region
    __hip_bfloat16* Hb    = (__hip_bfloat16*)(S + (size_t)2 * NCHUNK * DINNER * DSTATE);
    __hip_bfloat16* xb    = Hb    + (size_t)2 * NCHUNK * DINNER * DSTATE;  // 1M elems
    __hip_bfloat16* xcb   = xb    + (size_t)NTOK * DMODEL;        // 4M elems
    __hip_bfloat16* zb    = xcb   + (size_t)NTOK * DINNER;        // 4M
    __hip_bfloat16* gb    = zb    + (size_t)NTOK * DINNER;        // 4M
    __hip_bfloat16* wbufb = gb    + (size_t)NTOK * DINNER;        // 4M
    __hip_bfloat16* W1b   = wbufb + (size_t)NTOK * DINNER;        // 0.5M
    __hip_bfloat16* w2T   = W1b   + (size_t)DMODEL * DINNER;      // 0.5M
    __hip_bfloat16* convT = w2T   + (size_t)DINNER * DMODEL;      // 4M
    __hip_bfloat16* wdelT = convT + (size_t)4 * DINNER * DINNER;  // 1088 x 1024
    __hip_bfloat16* woutT = wdelT + (size_t)1088 * DINNER;        // 0.5M
    __hip_bfloat16* FT    = woutT + (size_t)DINNER * DMODEL;      // 2M (1024 x 2048)
    __hip_bfloat16* zpage = FT    + (size_t)DINNER * 2048;        // 8K elems

    hipMemsetAsync(zpage, 0, 16384, stream);
    // zero pad rows 1056..1087 of wdelT_ext
    hipMemsetAsync(wdelT + (size_t)1056 * DINNER, 0, 32 * DINNER * 2, stream);

    // input/weight prep
    cvt_slice_k<<<NTOK * DMODEL / 1024, 256, 0, stream>>>(x, xb, DMODEL, DMODEL / 4);
    cvt_slice_k<<<DMODEL * DINNER / 1024, 256, 0, stream>>>(w_in, W1b, 2 * DINNER, DINNER / 4);
    transpose_bf16_k<<<dim3(DINNER / 32, DMODEL / 32), 256, 0, stream>>>(
        w_in + DINNER, w2T, DMODEL, DINNER, 2 * DINNER);
    transpose_bf16_k<<<dim3(DINNER / 32, 4 * DINNER / 32), 256, 0, stream>>>(
        conv_k, convT, 4 * DINNER, DINNER, DINNER);
    transpose_bf16_k<<<dim3(DINNER / 32, DINNER / 32), 256, 0, stream>>>(
        w_del, wdelT, DINNER, DINNER, DINNER);
    bcw_k<<<128, 256, 0, stream>>>(w_B, w_C, wdelT);
    transpose_bf16_k<<<dim3(DMODEL / 32, DINNER / 32), 256, 0, stream>>>(
        w_out, woutT, DINNER, DMODEL, DMODEL);

    // fused conv weights: FT[o][tap*512 + dm] = (W1 @ K_tap)[dm][o], row stride 2048
    mgemm<4, 64, 64><<<dim3(DMODEL / 64, DINNER / 64, 4), 256, 0, stream>>>(
        convT, 4 * DINNER, W1b, DINNER, nullptr, FT, nullptr, 4 * DMODEL, DINNER,
        nullptr, nullptr, nullptr, 0, zpage, nullptr, nullptr, nullptr, nullptr);
    // fused conv+z (dual path): bn<1024 conv (FT, K=2048) -> xcb bf16;
    //                           bn>=1024 z (w2T, K=512)   -> zb bf16
    mgemm<0, 128, 64><<<dim3(2 * DINNER / 64, NTOK / 128), 256, 0, stream>>>(
        xb, DMODEL, FT, 4 * DMODEL, nullptr, xcb, zb, DINNER, 4 * DMODEL,
        conv_b, nullptr, w2T, DMODEL, zpage, nullptr, nullptr, nullptr, nullptr);
    // delta + B/C fused: N=1088 (tile 128x64, grid 17x32=544); w -> bf16 wbufb
    mgemm<2, 128, 64><<<dim3(1088 / 64, NTOK / 128), 256, 0, stream>>>(
        xcb, DINNER, wdelT, DINNER, nullptr, wbufb, nullptr, DINNER, DINNER,
        b_del, xcb, nullptr, 0, zpage, b_B, b_C, Bm, Cm);
    // scan
    chunkS_k<<<dim3(2 * NCHUNK, DINNER / 16), 256, 0, stream>>>(wbufb, Bm, S);
    hpre_k<<<dim3(2 * DINNER * DSTATE / 256), 256, 0, stream>>>(S, Hb);
    intra_k<<<dim3(2 * NCHUNK, DINNER / 64), 256, 0, stream>>>(wbufb, Bm, Cm, Hb, zb, gb);
    // out = g @ w_out  (tile 64x64, grid (8,64) = 512 blocks, 16 KB LDS)
    mgemm<3, 64, 64><<<dim3(DMODEL / 64, NTOK / 64), 256, 0, stream>>>(
        gb, DINNER, woutT, DINNER, out, nullptr, nullptr, DMODEL, DINNER,
        nullptr, nullptr, nullptr, 0, zpage, nullptr, nullptr, nullptr, nullptr);
}

// Round 18
// 134.928 us; speedup vs baseline: 2.5692x; 1.1755x over previous
//
#include <hip/hip_runtime.h>
#include <hip/hip_bf16.h>
#include <math.h>

#define DMODEL 512
#define DINNER 1024
#define DSTATE 16
#define SEQLEN 2048
#define NTOK   4096
#define CHUNK  64
#define NCHUNK (SEQLEN / CHUNK)  // 32

typedef __bf16 bf16x8 __attribute__((ext_vector_type(8)));
typedef float  f32x4  __attribute__((ext_vector_type(4)));

__device__ __forceinline__ float silu_f(float x) {
    return x / (1.0f + __expf(-x));
}

// swizzled LDS index (bf16 elems) for row r, 16B slot s (8 slots per 64-elem row)
__device__ __forceinline__ int swz(int r, int s) {
    return r * 64 + ((s ^ (r & 7)) << 3);
}

// async global->LDS 16B; LDS dest is wave-uniform base + lane*16
__device__ __forceinline__ void gload16(const void* g, void* l) {
    __builtin_amdgcn_global_load_lds(
        (const __attribute__((address_space(1))) void*)g,
        (__attribute__((address_space(3))) void*)l, 16, 0, 0);
}

__device__ __forceinline__ void cvt4(const float* src, __hip_bfloat16* dst) {
    float4 v = *reinterpret_cast<const float4*>(src);
    __hip_bfloat16 tmp[4] = {__float2bfloat16(v.x), __float2bfloat16(v.y),
                             __float2bfloat16(v.z), __float2bfloat16(v.w)};
    *reinterpret_cast<ushort4*>(dst) = *reinterpret_cast<const ushort4*>(tmp);
}

// ---------------------------------------------------------------------------
// bf16 MFMA GEMM, tile TBM x TBN, BK=64, 4 waves (2x2), gload_lds staging,
// single-buffer LDS, 2-barrier loop: {stage(t); bar; MFMA(t); bar}.
// Linear LDS + source-side XOR swizzle (involution) + same swizzle on ds_read.
// MODE 0: fused conv+z dual path (conv: tap-shifted rows, OOB -> zpage);
//         n<1024: silu(acc+bias) -> Cb bf16 ; else Czb bf16
// MODE 2: delta+BC — n<1024: softplus(acc+bias[n])*xc[m,n]*0.95^(l+1) -> Cb bf16;
//         n in [1024,1040): Bm = acc+bB ; [1040,1056): Cm = acc+bC ; else drop
// MODE 3: plain — C0 = acc (f32)
// MODE 4: fused-weight GEMM — per-tap (blockIdx.z), bf16 store at ldc stride
// ---------------------------------------------------------------------------
template<int MODE, int TBM, int TBN>
__global__ __launch_bounds__(256)
void mgemm(const __hip_bfloat16* __restrict__ A, int lda,
           const __hip_bfloat16* __restrict__ WT, int ldw,
           float* __restrict__ C0, __hip_bfloat16* __restrict__ Cb,
           __hip_bfloat16* __restrict__ Czb, int ldc,
           int K, const float* __restrict__ bias,
           const __hip_bfloat16* __restrict__ xc,
           const __hip_bfloat16* __restrict__ WT2, int ldw2,
           const __hip_bfloat16* __restrict__ zpage,
           const float* __restrict__ bB, const float* __restrict__ bC,
           float* __restrict__ BmO, float* __restrict__ CmO)
{
    constexpr int MI = TBM / 32;
    constexpr int MJ = TBN / 32;
    __shared__ __align__(16) __hip_bfloat16 As[TBM * 64];
    __shared__ __align__(16) __hip_bfloat16 Bs[TBN * 64];

    // bijective XCD swizzle (all launches have nb % 8 == 0)
    const int nb  = gridDim.x * gridDim.y;
    const int lin = blockIdx.y * gridDim.x + blockIdx.x;
    const int cpx = nb >> 3;
    const int sl  = (lin & 7) * cpx + (lin >> 3);
    const int bm  = (sl / gridDim.x) * TBM;
    const int bn  = (sl % gridDim.x) * TBN;

    if (MODE == 4) { A += blockIdx.z * 1024; Cb += blockIdx.z * 512; }

    const bool zblk = (MODE == 0) && (bn >= DINNER);
    const int  bnb  = zblk ? (bn - DINNER) : bn;
    const __hip_bfloat16* Wp = zblk ? WT2 : WT;
    const int  ldwp = zblk ? ldw2 : ldw;
    const int  Keff = zblk ? DMODEL : K;

    const int tid  = threadIdx.x;
    const int wid  = tid >> 6, lane = tid & 63;
    const int wr   = (wid >> 1) * (TBM / 2), wc = (wid & 1) * (TBN / 2);
    const int llo  = lane & 15, lhi = lane >> 4;

    f32x4 acc[MI][MJ] = {};

    const int srow0 = wid * 8 + (lane >> 3);
    const int sphys = lane & 7;

    auto stage_tile = [&](int k0) {
#pragma unroll
        for (int q = 0; q < MI; ++q) {
            int row  = q * 32 + srow0;
            int sdat = sphys ^ (row & 7);
            const __hip_bfloat16* srcA;
            if (MODE == 0 && !zblk) {
                int kid = k0 >> 9;
                int gr  = bm + row;
                int l2  = (gr & (SEQLEN - 1)) + kid - 1;
                srcA = ((unsigned)l2 < (unsigned)SEQLEN)
                     ? A + (size_t)(gr + kid - 1) * lda + (k0 & 511) + sdat * 8
                     : zpage;
            } else {
                srcA = A + (size_t)(bm + row) * lda + k0 + sdat * 8;
            }
            gload16(srcA, &As[q * 2048 + wid * 512]);
        }
#pragma unroll
        for (int q = 0; q < MJ; ++q) {
            int row  = q * 32 + srow0;
            int sdat = sphys ^ (row & 7);
            gload16(Wp + (size_t)(bnb + row) * ldwp + k0 + sdat * 8,
                    &Bs[q * 2048 + wid * 512]);
        }
    };

    const int NT = Keff / 64;
    for (int t = 0; t < NT; ++t) {
        stage_tile(t * 64);
        __syncthreads();
#pragma unroll
        for (int kk = 0; kk < 2; ++kk) {
            bf16x8 af[MI], bv[MJ];
#pragma unroll
            for (int i = 0; i < MI; ++i)
                af[i] = *reinterpret_cast<const bf16x8*>(&As[swz(wr + i * 16 + llo, kk * 4 + lhi)]);
#pragma unroll
            for (int j = 0; j < MJ; ++j)
                bv[j] = *reinterpret_cast<const bf16x8*>(&Bs[swz(wc + j * 16 + llo, kk * 4 + lhi)]);
#pragma unroll
            for (int i = 0; i < MI; ++i)
#pragma unroll
                for (int j = 0; j < MJ; ++j)
                    acc[i][j] = __builtin_amdgcn_mfma_f32_16x16x32_bf16(af[i], bv[j], acc[i][j], 0, 0, 0);
        }
        __syncthreads();
    }

#pragma unroll
    for (int i = 0; i < MI; ++i) {
#pragma unroll
        for (int q = 0; q < 4; ++q) {
            int m = bm + wr + i * 16 + lhi * 4 + q;
            float dec = 1.0f;
            if (MODE == 2)
                dec = __expf((float)((m & (SEQLEN - 1)) + 1) * -0.051293294f); // ln 0.95
#pragma unroll
            for (int j = 0; j < MJ; ++j) {
                int nrel = wc + j * 16 + llo;
                int n = bn + nrel;
                float v = acc[i][j][q];
                if (MODE == 0) {
                    if (!zblk) {
                        v = silu_f(v + bias[n]);
                        Cb[(size_t)m * DINNER + n] = __float2bfloat16(v);
                    } else {
                        Czb[(size_t)m * DINNER + bnb + nrel] = __float2bfloat16(v);
                    }
                } else if (MODE == 2) {
                    if (n < DINNER) {
                        float d  = v + bias[n];
                        float sp = fmaxf(d, 0.f) + log1pf(__expf(-fabsf(d)));
                        float xcv = __bfloat162float(xc[(size_t)m * DINNER + n]);
                        Cb[(size_t)m * DINNER + n] = __float2bfloat16(sp * xcv * dec);
                    } else {
                        int col = n - DINNER;
                        if (col < 16)
                            BmO[(size_t)m * DSTATE + col] = v + bB[col];
                        else if (col < 32)
                            CmO[(size_t)m * DSTATE + (col - 16)] = v + bC[col - 16];
                    }
                } else if (MODE == 4) {
                    Cb[(size_t)m * ldc + n] = __float2bfloat16(v);
                } else {
                    C0[(size_t)m * ldc + n] = v;
                }
            }
        }
    }
}

// ---------------------------------------------------------------------------
// prep megakernel — one launch for all input/weight prep:
//  blocks [0,2048)   : x -> xb (bf16)
//  blocks [2048,2560): w_in[:, :1024] -> W1b
//  blocks [2560,8704): 4 transposes (w2T, convT, wdelT, woutT)
//  blocks [8704,8832): bcw (wB^T/wC^T -> wdelT rows 1024..1055)
//  blocks [8832,8872): zero fills (zpage, wdelT rows 1056..1087)
// ---------------------------------------------------------------------------
__global__ __launch_bounds__(256)
void prep_k(const float* __restrict__ x, const float* __restrict__ w_in,
            const float* __restrict__ conv_k, const float* __restrict__ w_del,
            const float* __restrict__ w_B, const float* __restrict__ w_C,
            const float* __restrict__ w_out,
            __hip_bfloat16* __restrict__ xb, __hip_bfloat16* __restrict__ W1b,
            __hip_bfloat16* __restrict__ w2T, __hip_bfloat16* __restrict__ convT,
            __hip_bfloat16* __restrict__ wdelT, __hip_bfloat16* __restrict__ woutT,
            __hip_bfloat16* __restrict__ zpage)
{
    __shared__ float t[32][33];
    const int b = blockIdx.x, tid = threadIdx.x;
    if (b < 2048) {
        int idx = b * 256 + tid;
        int r = idx >> 7, c = (idx & 127) * 4;
        cvt4(x + (size_t)r * DMODEL + c, xb + (size_t)r * DMODEL + c);
    } else if (b < 2560) {
        int idx = (b - 2048) * 256 + tid;
        int r = idx >> 8, c = (idx & 255) * 4;
        cvt4(w_in + (size_t)r * (2 * DINNER) + c, W1b + (size_t)r * DINNER + c);
    } else if (b < 8704) {
        const float* in; __hip_bfloat16* outp; int R, ldin, ntx, local;
        if (b < 3072)      { local = b - 2560; in = w_in + DINNER; outp = w2T;   R = 512;  ldin = 2048; ntx = 32; }
        else if (b < 7168) { local = b - 3072; in = conv_k;        outp = convT; R = 4096; ldin = 1024; ntx = 32; }
        else if (b < 8192) { local = b - 7168; in = w_del;         outp = wdelT; R = 1024; ldin = 1024; ntx = 32; }
        else               { local = b - 8192; in = w_out;         outp = woutT; R = 1024; ldin = 512;  ntx = 16; }
        int bx = (local % ntx) * 32, by = (local / ntx) * 32;
        int tx = tid & 31, ty = tid >> 5;
#pragma unroll
        for (int q = 0; q < 4; ++q)
            t[ty + q * 8][tx] = in[(size_t)(by + ty + q * 8) * ldin + bx + tx];
        __syncthreads();
#pragma unroll
        for (int q = 0; q < 4; ++q)
            outp[(size_t)(bx + ty + q * 8) * R + by + tx] = __float2bfloat16(t[tx][ty + q * 8]);
    } else if (b < 8832) {
        int idx = (b - 8704) * 256 + tid;    // 0..32767
        int sel = idx >> 14;
        int rem = idx & 16383;
        int s = rem >> 10, k = rem & 1023;
        const float* src = sel ? w_C : w_B;
        wdelT[(size_t)(1024 + sel * 16 + s) * DINNER + k] =
            __float2bfloat16(src[(size_t)k * DSTATE + s]);
    } else {
        int local = b - 8832;
        ushort4 zero = {0, 0, 0, 0};
        if (local < 8) {
            int idx = local * 256 + tid;     // 0..2047 quads (8192 elems)
            *reinterpret_cast<ushort4*>(&zpage[idx * 4]) = zero;
        } else {
            int idx = (local - 8) * 256 + tid;  // 0..8191 quads (32768 elems)
            *reinterpret_cast<ushort4*>(&wdelT[(size_t)1056 * DINNER + idx * 4]) = zero;
        }
    }
}

// ---------------------------------------------------------------------------
// MFMA chunkS: per block (bc, n-block of 128): S[n][s] = sum_t w[t,n]*Bm[t,s]
// A = w^T [n][t] (XOR-swizzled LDS transpose), B = Bm^T [s][t]; M=128,N=16,K=64
// ---------------------------------------------------------------------------
__global__ __launch_bounds__(256)
void chunkS_k(const __hip_bfloat16* __restrict__ wb, const float* __restrict__ Bm,
              float* __restrict__ S)
{
    constexpr int LDW = 72;
    __shared__ __align__(16) __hip_bfloat16 wT[128 * LDW];  // 18 KB
    __shared__ __align__(16) __hip_bfloat16 bT[16 * 80];    // 2.5 KB
    const int bc = blockIdx.x, n0 = blockIdx.y * 128, t0 = bc * CHUNK;
    const int tid = threadIdx.x;
    // stage w^T: 64 t x 128 n; store (n,t) at n*LDW + (t ^ (((n>>2)&7)<<3))
#pragma unroll
    for (int q = 0; q < 8; ++q) {
        int idx = tid + q * 256;             // 0..2047 quads
        int t = idx >> 5, n4 = (idx & 31) * 4;
        int key = ((n4 >> 2) & 7) << 3;
        int tx = t ^ key;
        ushort4 v = *reinterpret_cast<const ushort4*>(
            &wb[(size_t)(t0 + t) * DINNER + n0 + n4]);
        wT[(n4 + 0) * LDW + tx] = *(const __hip_bfloat16*)&v.x;
        wT[(n4 + 1) * LDW + tx] = *(const __hip_bfloat16*)&v.y;
        wT[(n4 + 2) * LDW + tx] = *(const __hip_bfloat16*)&v.z;
        wT[(n4 + 3) * LDW + tx] = *(const __hip_bfloat16*)&v.w;
    }
    // stage Bm^T: 64 t x 16 s
#pragma unroll
    for (int q = 0; q < 4; ++q) {
        int idx = tid + q * 256;             // 0..1023
        int t = idx >> 4, s = idx & 15;
        bT[s * 80 + t] = __float2bfloat16(Bm[(size_t)(t0 + t) * DSTATE + s]);
    }
    __syncthreads();
    const int wid = tid >> 6, lane = tid & 63;
    const int llo = lane & 15, lhi = lane >> 4;
    f32x4 acc[2] = {};
#pragma unroll
    for (int kk = 0; kk < 2; ++kk) {
        bf16x8 bv = *reinterpret_cast<const bf16x8*>(&bT[llo * 80 + kk * 32 + lhi * 8]);
#pragma unroll
        for (int i = 0; i < 2; ++i) {
            int r = wid * 32 + i * 16 + llo;
            int kbase = (kk * 32 + lhi * 8) ^ (((r >> 2) & 7) << 3);
            bf16x8 af = *reinterpret_cast<const bf16x8*>(&wT[r * LDW + kbase]);
            acc[i] = __builtin_amdgcn_mfma_f32_16x16x32_bf16(af, bv, acc[i], 0, 0, 0);
        }
    }
#pragma unroll
    for (int i = 0; i < 2; ++i)
#pragma unroll
        for (int q = 0; q < 4; ++q) {
            int n = wid * 32 + i * 16 + lhi * 4 + q;
            S[((size_t)bc * DINNER + n0 + n) * DSTATE + llo] = acc[i][q];
        }
}

// exclusive prefix over chunks -> bf16 H
__global__ __launch_bounds__(256)
void hpre_k(const float* __restrict__ S, __hip_bfloat16* __restrict__ Hb)
{
    int idx = blockIdx.x * 256 + threadIdx.x;
    int b  = idx >> 14;
    int ns = idx & 16383;
    float acc = 0.f;
    for (int c = 0; c < NCHUNK; ++c) {
        size_t off = ((size_t)(b * NCHUNK + c)) * (DINNER * DSTATE) + ns;
        Hb[off] = __float2bfloat16(acc);
        acc += S[off];
    }
}

// ---------------------------------------------------------------------------
// MFMA intra-chunk: P = Cm@Bm^T (mask t<=l) -> bf16 LDS; Y = [P|Cm]@[w^T;H^T];
// g = Y * silu(z)
// ---------------------------------------------------------------------------
__global__ __launch_bounds__(256)
void intra_k(const __hip_bfloat16* __restrict__ wb,
             const float* __restrict__ Bm, const float* __restrict__ Cm,
             const __hip_bfloat16* __restrict__ Hb,
             const __hip_bfloat16* __restrict__ zb,
             __hip_bfloat16* __restrict__ gb)
{
    constexpr int LDP  = 104;
    constexpr int LDC  = 40;
    __shared__ __align__(16) __hip_bfloat16 csb[64 * LDC];
    __shared__ __align__(16) __hip_bfloat16 bsb[64 * LDC];
    __shared__ __align__(16) __hip_bfloat16 Pb [64 * LDP];
    __shared__ __align__(16) __hip_bfloat16 Wb [64 * LDP];

    const int bc = blockIdx.x;
    const int n0 = blockIdx.y * 64;
    const int t0 = bc * CHUNK;
    const int tid = threadIdx.x;
    const int wid = tid >> 6, lane = tid & 63;
    const int llo = lane & 15, lhi = lane >> 4;
    const int wr = (wid >> 1) * 32, wc = (wid & 1) * 32;
    const __hip_bfloat16 z16 = __float2bfloat16(0.f);

#pragma unroll
    for (int q = 0; q < 4; ++q) {
        int idx = tid + q * 256;
        int j = idx >> 4, s = idx & 15;
        __hip_bfloat16 cb = __float2bfloat16(Cm[(size_t)(t0 + j) * DSTATE + s]);
        csb[j * LDC + s]      = cb;
        csb[j * LDC + 16 + s] = z16;
        bsb[j * LDC + s]      = __float2bfloat16(Bm[(size_t)(t0 + j) * DSTATE + s]);
        bsb[j * LDC + 16 + s] = z16;
        Pb[j * LDP + 64 + s]  = cb;
        Pb[j * LDP + 80 + s]  = z16;
        Wb[j * LDP + 64 + s]  = Hb[((size_t)bc * DINNER + n0 + j) * DSTATE + s];
        Wb[j * LDP + 80 + s]  = z16;
    }
#pragma unroll
    for (int q = 0; q < 4; ++q) {
        int c = tid + q * 256;
        int t = c >> 4, c4 = (c & 15) * 4;
        ushort4 v = *reinterpret_cast<const ushort4*>(
            &wb[(size_t)(t0 + t) * DINNER + n0 + c4]);
        Wb[(c4 + 0) * LDP + t] = *(const __hip_bfloat16*)&v.x;
        Wb[(c4 + 1) * LDP + t] = *(const __hip_bfloat16*)&v.y;
        Wb[(c4 + 2) * LDP + t] = *(const __hip_bfloat16*)&v.z;
        Wb[(c4 + 3) * LDP + t] = *(const __hip_bfloat16*)&v.w;
    }
    __syncthreads();

    {
        f32x4 pacc[2][2] = {};
        bf16x8 ap[2], bp[2];
#pragma unroll
        for (int i = 0; i < 2; ++i)
            ap[i] = *reinterpret_cast<const bf16x8*>(&csb[(wr + i * 16 + llo) * LDC + lhi * 8]);
#pragma unroll
        for (int j = 0; j < 2; ++j)
            bp[j] = *reinterpret_cast<const bf16x8*>(&bsb[(wc + j * 16 + llo) * LDC + lhi * 8]);
#pragma unroll
        for (int i = 0; i < 2; ++i)
#pragma unroll
            for (int j = 0; j < 2; ++j)
                pacc[i][j] = __builtin_amdgcn_mfma_f32_16x16x32_bf16(ap[i], bp[j], pacc[i][j], 0, 0, 0);
#pragma unroll
        for (int i = 0; i < 2; ++i)
#pragma unroll
            for (int q = 0; q < 4; ++q) {
                int l = wr + i * 16 + lhi * 4 + q;
#pragma unroll
                for (int j = 0; j < 2; ++j) {
                    int t = wc + j * 16 + llo;
                    float pv = (t <= l) ? pacc[i][j][q] : 0.f;
                    Pb[l * LDP + t] = __float2bfloat16(pv);
                }
            }
    }
    __syncthreads();

    f32x4 yacc[2][2] = {};
#pragma unroll
    for (int k0 = 0; k0 < 3; ++k0) {
        bf16x8 af[2], bv[2];
#pragma unroll
        for (int i = 0; i < 2; ++i)
            af[i] = *reinterpret_cast<const bf16x8*>(&Pb[(wr + i * 16 + llo) * LDP + k0 * 32 + lhi * 8]);
#pragma unroll
        for (int j = 0; j < 2; ++j)
            bv[j] = *reinterpret_cast<const bf16x8*>(&Wb[(wc + j * 16 + llo) * LDP + k0 * 32 + lhi * 8]);
#pragma unroll
        for (int i = 0; i < 2; ++i)
#pragma unroll
            for (int j = 0; j < 2; ++j)
                yacc[i][j] = __builtin_amdgcn_mfma_f32_16x16x32_bf16(af[i], bv[j], yacc[i][j], 0, 0, 0);
    }

#pragma unroll
    for (int i = 0; i < 2; ++i)
#pragma unroll
        for (int q = 0; q < 4; ++q) {
            int l = wr + i * 16 + lhi * 4 + q;
            int token = t0 + l;
#pragma unroll
            for (int j = 0; j < 2; ++j) {
                int n = wc + j * 16 + llo;
                float z = __bfloat162float(zb[(size_t)token * DINNER + n0 + n]);
                gb[(size_t)token * DINNER + n0 + n] =
                    __float2bfloat16(yacc[i][j][q] * silu_f(z));
            }
        }
}

extern "C" void kernel_launch(void* const* d_in, const int* in_sizes, int n_in,
                              void* d_out, int out_size, void* d_ws, size_t ws_size,
                              hipStream_t stream) {
    const float* x      = (const float*)d_in[0];
    const float* w_in   = (const float*)d_in[1];
    const float* conv_k = (const float*)d_in[2];
    const float* conv_b = (const float*)d_in[3];
    const float* w_del  = (const float*)d_in[4];
    const float* b_del  = (const float*)d_in[5];
    const float* w_B    = (const float*)d_in[6];
    const float* b_B    = (const float*)d_in[7];
    const float* w_C    = (const float*)d_in[8];
    const float* b_C    = (const float*)d_in[9];
    const float* w_out  = (const float*)d_in[11];
    float* out = (float*)d_out;

    // f32 region
    float* Bm    = (float*)d_ws;
    float* Cm    = Bm + (size_t)NTOK * DSTATE;
    float* S     = Cm + (size_t)NTOK * DSTATE;            // 1M f32
    // bf16 region
    __hip_bfloat16* Hb    = (__hip_bfloat16*)(S + (size_t)2 * NCHUNK * DINNER * DSTATE);
    __hip_bfloat16* xb    = Hb    + (size_t)2 * NCHUNK * DINNER * DSTATE;  // 1M elems
    __hip_bfloat16* xcb   = xb    + (size_t)NTOK * DMODEL;        // 4M elems
    __hip_bfloat16* zb    = xcb   + (size_t)NTOK * DINNER;        // 4M
    __hip_bfloat16* gb    = zb    + (size_t)NTOK * DINNER;        // 4M
    __hip_bfloat16* wbufb = gb    + (size_t)NTOK * DINNER;        // 4M
    __hip_bfloat16* W1b   = wbufb + (size_t)NTOK * DINNER;        // 0.5M
    __hip_bfloat16* w2T   = W1b   + (size_t)DMODEL * DINNER;      // 0.5M
    __hip_bfloat16* convT = w2T   + (size_t)DINNER * DMODEL;      // 4M
    __hip_bfloat16* wdelT = convT + (size_t)4 * DINNER * DINNER;  // 1088 x 1024
    __hip_bfloat16* woutT = wdelT + (size_t)1088 * DINNER;        // 0.5M
    __hip_bfloat16* FT    = woutT + (size_t)DINNER * DMODEL;      // 2M (1024 x 2048)
    __hip_bfloat16* zpage = FT    + (size_t)DINNER * 2048;        // 8K elems

    // one-launch prep: cvts + transposes + bcw + zero fills
    prep_k<<<8872, 256, 0, stream>>>(x, w_in, conv_k, w_del, w_B, w_C, w_out,
                                     xb, W1b, w2T, convT, wdelT, woutT, zpage);

    // fused conv weights: FT[o][tap*512 + dm] = (W1 @ K_tap)[dm][o], row stride 2048
    mgemm<4, 64, 64><<<dim3(DMODEL / 64, DINNER / 64, 4), 256, 0, stream>>>(
        convT, 4 * DINNER, W1b, DINNER, nullptr, FT, nullptr, 4 * DMODEL, DINNER,
        nullptr, nullptr, nullptr, 0, zpage, nullptr, nullptr, nullptr, nullptr);
    // fused conv+z (dual path): bn<1024 conv (FT, K=2048) -> xcb bf16;
    //                           bn>=1024 z (w2T, K=512)   -> zb bf16
    mgemm<0, 128, 64><<<dim3(2 * DINNER / 64, NTOK / 128), 256, 0, stream>>>(
        xb, DMODEL, FT, 4 * DMODEL, nullptr, xcb, zb, DINNER, 4 * DMODEL,
        conv_b, nullptr, w2T, DMODEL, zpage, nullptr, nullptr, nullptr, nullptr);
    // delta + B/C fused: N=1088 (tile 128x64, grid 17x32=544); w -> bf16 wbufb
    mgemm<2, 128, 64><<<dim3(1088 / 64, NTOK / 128), 256, 0, stream>>>(
        xcb, DINNER, wdelT, DINNER, nullptr, wbufb, nullptr, DINNER, DINNER,
        b_del, xcb, nullptr, 0, zpage, b_B, b_C, Bm, Cm);
    // scan
    chunkS_k<<<dim3(2 * NCHUNK, DINNER / 128), 256, 0, stream>>>(wbufb, Bm, S);
    hpre_k<<<dim3(2 * DINNER * DSTATE / 256), 256, 0, stream>>>(S, Hb);
    intra_k<<<dim3(2 * NCHUNK, DINNER / 64), 256, 0, stream>>>(wbufb, Bm, Cm, Hb, zb, gb);
    // out = g @ w_out  (tile 64x64, grid (8,64) = 512 blocks, 16 KB LDS)
    mgemm<3, 64, 64><<<dim3(DMODEL / 64, NTOK / 64), 256, 0, stream>>>(
        gb, DINNER, woutT, DINNER, out, nullptr, nullptr, DMODEL, DINNER,
        nullptr, nullptr, nullptr, 0, zpage, nullptr, nullptr, nullptr, nullptr);
}

// Round 19
// 132.358 us; speedup vs baseline: 2.6191x; 1.0194x over previous
//
#include <hip/hip_runtime.h>
#include <hip/hip_bf16.h>
#include <math.h>

#define DMODEL 512
#define DINNER 1024
#define DSTATE 16
#define SEQLEN 2048
#define NTOK   4096
#define CHUNK  64
#define NCHUNK (SEQLEN / CHUNK)  // 32

typedef __bf16 bf16x8 __attribute__((ext_vector_type(8)));
typedef float  f32x4  __attribute__((ext_vector_type(4)));

__device__ __forceinline__ float silu_f(float x) {
    return x / (1.0f + __expf(-x));
}

// swizzled LDS index (bf16 elems) for row r, 16B slot s (8 slots per 64-elem row)
__device__ __forceinline__ int swz(int r, int s) {
    return r * 64 + ((s ^ (r & 7)) << 3);
}

// async global->LDS 16B; LDS dest is wave-uniform base + lane*16
__device__ __forceinline__ void gload16(const void* g, void* l) {
    __builtin_amdgcn_global_load_lds(
        (const __attribute__((address_space(1))) void*)g,
        (__attribute__((address_space(3))) void*)l, 16, 0, 0);
}

__device__ __forceinline__ void cvt4(const float* src, __hip_bfloat16* dst) {
    float4 v = *reinterpret_cast<const float4*>(src);
    __hip_bfloat16 tmp[4] = {__float2bfloat16(v.x), __float2bfloat16(v.y),
                             __float2bfloat16(v.z), __float2bfloat16(v.w)};
    *reinterpret_cast<ushort4*>(dst) = *reinterpret_cast<const ushort4*>(tmp);
}

// ---------------------------------------------------------------------------
// bf16 MFMA GEMM, tile TBM x TBN, BK=64, 4 waves (2x2), gload_lds staging,
// single-buffer LDS, 2-barrier loop: {stage(t); bar; MFMA(t); bar}.
// Linear LDS + source-side XOR swizzle (involution) + same swizzle on ds_read.
// MODE 0: fused conv(split-K2)+z triple path, grid x=48:
//         x<16:  conv half 0 (taps 0-1, K=1024) -> P0 bf16 raw partial
//         x<32:  conv half 1 (taps 2-3, K=1024) -> P1 bf16 raw partial
//         else:  z (w2T, K=512) -> Czb bf16
// MODE 2: delta+BC — n<1024: softplus(acc+bias[n])*xc[m,n]*0.95^(l+1) -> Cb bf16;
//         n in [1024,1040): Bm = acc+bB ; [1040,1056): Cm = acc+bC ; else drop
// MODE 3: plain — C0 = acc (f32)
// MODE 4: fused-weight GEMM — per-tap (blockIdx.z), bf16 store at ldc stride
// ---------------------------------------------------------------------------
template<int MODE, int TBM, int TBN>
__global__ __launch_bounds__(256)
void mgemm(const __hip_bfloat16* __restrict__ A, int lda,
           const __hip_bfloat16* __restrict__ WT, int ldw,
           float* __restrict__ C0, __hip_bfloat16* __restrict__ Cb,
           __hip_bfloat16* __restrict__ Czb, int ldc,
           int K, const float* __restrict__ bias,
           const __hip_bfloat16* __restrict__ xc,
           const __hip_bfloat16* __restrict__ WT2, int ldw2,
           const __hip_bfloat16* __restrict__ zpage,
           const float* __restrict__ bB, const float* __restrict__ bC,
           float* __restrict__ BmO, float* __restrict__ CmO,
           __hip_bfloat16* __restrict__ Pb1)
{
    constexpr int MI = TBM / 32;
    constexpr int MJ = TBN / 32;
    __shared__ __align__(16) __hip_bfloat16 As[TBM * 64];
    __shared__ __align__(16) __hip_bfloat16 Bs[TBN * 64];

    // bijective XCD swizzle (all launches have nb % 8 == 0)
    const int nb  = gridDim.x * gridDim.y;
    const int lin = blockIdx.y * gridDim.x + blockIdx.x;
    const int cpx = nb >> 3;
    const int sl  = (lin & 7) * cpx + (lin >> 3);
    const int bm  = (sl / gridDim.x) * TBM;
    const int bn  = (sl % gridDim.x) * TBN;

    if (MODE == 4) { A += blockIdx.z * 1024; Cb += blockIdx.z * 512; }

    const int  xsel = (MODE == 0) ? (bn >> 10) : 0;   // 0,1: conv halves; 2: z
    const bool zblk = (MODE == 0) && (xsel == 2);
    const int  bnb  = (MODE == 0) ? (bn & 1023) : bn;
    const __hip_bfloat16* Wp = zblk ? WT2 : WT;
    const int  ldwp = zblk ? ldw2 : ldw;
    const int  Keff = (MODE == 0 && zblk) ? DMODEL : K;
    const int  koff = (MODE == 0 && xsel == 1) ? 1024 : 0;

    const int tid  = threadIdx.x;
    const int wid  = tid >> 6, lane = tid & 63;
    const int wr   = (wid >> 1) * (TBM / 2), wc = (wid & 1) * (TBN / 2);
    const int llo  = lane & 15, lhi = lane >> 4;

    f32x4 acc[MI][MJ] = {};

    const int srow0 = wid * 8 + (lane >> 3);
    const int sphys = lane & 7;

    auto stage_tile = [&](int k0) {
#pragma unroll
        for (int q = 0; q < MI; ++q) {
            int row  = q * 32 + srow0;
            int sdat = sphys ^ (row & 7);
            const __hip_bfloat16* srcA;
            if (MODE == 0 && !zblk) {
                int kg  = koff + k0;
                int kid = kg >> 9;
                int gr  = bm + row;
                int l2  = (gr & (SEQLEN - 1)) + kid - 1;
                srcA = ((unsigned)l2 < (unsigned)SEQLEN)
                     ? A + (size_t)(gr + kid - 1) * lda + (kg & 511) + sdat * 8
                     : zpage;
            } else {
                srcA = A + (size_t)(bm + row) * lda + k0 + sdat * 8;
            }
            gload16(srcA, &As[q * 2048 + wid * 512]);
        }
#pragma unroll
        for (int q = 0; q < MJ; ++q) {
            int row  = q * 32 + srow0;
            int sdat = sphys ^ (row & 7);
            gload16(Wp + (size_t)(bnb + row) * ldwp + koff + k0 + sdat * 8,
                    &Bs[q * 2048 + wid * 512]);
        }
    };

    const int NT = Keff / 64;
    for (int t = 0; t < NT; ++t) {
        stage_tile(t * 64);
        __syncthreads();
#pragma unroll
        for (int kk = 0; kk < 2; ++kk) {
            bf16x8 af[MI], bv[MJ];
#pragma unroll
            for (int i = 0; i < MI; ++i)
                af[i] = *reinterpret_cast<const bf16x8*>(&As[swz(wr + i * 16 + llo, kk * 4 + lhi)]);
#pragma unroll
            for (int j = 0; j < MJ; ++j)
                bv[j] = *reinterpret_cast<const bf16x8*>(&Bs[swz(wc + j * 16 + llo, kk * 4 + lhi)]);
#pragma unroll
            for (int i = 0; i < MI; ++i)
#pragma unroll
                for (int j = 0; j < MJ; ++j)
                    acc[i][j] = __builtin_amdgcn_mfma_f32_16x16x32_bf16(af[i], bv[j], acc[i][j], 0, 0, 0);
        }
        __syncthreads();
    }

#pragma unroll
    for (int i = 0; i < MI; ++i) {
#pragma unroll
        for (int q = 0; q < 4; ++q) {
            int m = bm + wr + i * 16 + lhi * 4 + q;
            float dec = 1.0f;
            if (MODE == 2)
                dec = __expf((float)((m & (SEQLEN - 1)) + 1) * -0.051293294f); // ln 0.95
#pragma unroll
            for (int j = 0; j < MJ; ++j) {
                int nrel = wc + j * 16 + llo;
                int n = bn + nrel;
                float v = acc[i][j][q];
                if (MODE == 0) {
                    int col = bnb + nrel;
                    if (zblk) {
                        Czb[(size_t)m * DINNER + col] = __float2bfloat16(v);
                    } else {
                        __hip_bfloat16* P = xsel ? Pb1 : Cb;
                        P[(size_t)m * DINNER + col] = __float2bfloat16(v);
                    }
                } else if (MODE == 2) {
                    if (n < DINNER) {
                        float d  = v + bias[n];
                        float sp = fmaxf(d, 0.f) + log1pf(__expf(-fabsf(d)));
                        float xcv = __bfloat162float(xc[(size_t)m * DINNER + n]);
                        Cb[(size_t)m * DINNER + n] = __float2bfloat16(sp * xcv * dec);
                    } else {
                        int col = n - DINNER;
                        if (col < 16)
                            BmO[(size_t)m * DSTATE + col] = v + bB[col];
                        else if (col < 32)
                            CmO[(size_t)m * DSTATE + (col - 16)] = v + bC[col - 16];
                    }
                } else if (MODE == 4) {
                    Cb[(size_t)m * ldc + n] = __float2bfloat16(v);
                } else {
                    C0[(size_t)m * ldc + n] = v;
                }
            }
        }
    }
}

// combine split-K conv halves: xcb = bf16(silu(P0 + P1 + bias[n]))
__global__ __launch_bounds__(256)
void combine_k(const __hip_bfloat16* __restrict__ P0,
               const __hip_bfloat16* __restrict__ P1,
               const float* __restrict__ bias,
               __hip_bfloat16* __restrict__ xcb)
{
    int idx = blockIdx.x * 256 + threadIdx.x;
    size_t off = (size_t)idx * 4;
    int n = (int)(off & 1023);
    ushort4 a = *reinterpret_cast<const ushort4*>(&P0[off]);
    ushort4 b = *reinterpret_cast<const ushort4*>(&P1[off]);
    __hip_bfloat16 o[4];
#pragma unroll
    for (int j = 0; j < 4; ++j) {
        float va = __bfloat162float(((const __hip_bfloat16*)&a)[j]);
        float vb = __bfloat162float(((const __hip_bfloat16*)&b)[j]);
        o[j] = __float2bfloat16(silu_f(va + vb + bias[n + j]));
    }
    *reinterpret_cast<ushort4*>(&xcb[off]) = *reinterpret_cast<const ushort4*>(o);
}

// ---------------------------------------------------------------------------
// prep megakernel — one launch for all input/weight prep
// ---------------------------------------------------------------------------
__global__ __launch_bounds__(256)
void prep_k(const float* __restrict__ x, const float* __restrict__ w_in,
            const float* __restrict__ conv_k, const float* __restrict__ w_del,
            const float* __restrict__ w_B, const float* __restrict__ w_C,
            const float* __restrict__ w_out,
            __hip_bfloat16* __restrict__ xb, __hip_bfloat16* __restrict__ W1b,
            __hip_bfloat16* __restrict__ w2T, __hip_bfloat16* __restrict__ convT,
            __hip_bfloat16* __restrict__ wdelT, __hip_bfloat16* __restrict__ woutT,
            __hip_bfloat16* __restrict__ zpage)
{
    __shared__ float t[32][33];
    const int b = blockIdx.x, tid = threadIdx.x;
    if (b < 2048) {
        int idx = b * 256 + tid;
        int r = idx >> 7, c = (idx & 127) * 4;
        cvt4(x + (size_t)r * DMODEL + c, xb + (size_t)r * DMODEL + c);
    } else if (b < 2560) {
        int idx = (b - 2048) * 256 + tid;
        int r = idx >> 8, c = (idx & 255) * 4;
        cvt4(w_in + (size_t)r * (2 * DINNER) + c, W1b + (size_t)r * DINNER + c);
    } else if (b < 8704) {
        const float* in; __hip_bfloat16* outp; int R, ldin, ntx, local;
        if (b < 3072)      { local = b - 2560; in = w_in + DINNER; outp = w2T;   R = 512;  ldin = 2048; ntx = 32; }
        else if (b < 7168) { local = b - 3072; in = conv_k;        outp = convT; R = 4096; ldin = 1024; ntx = 32; }
        else if (b < 8192) { local = b - 7168; in = w_del;         outp = wdelT; R = 1024; ldin = 1024; ntx = 32; }
        else               { local = b - 8192; in = w_out;         outp = woutT; R = 1024; ldin = 512;  ntx = 16; }
        int bx = (local % ntx) * 32, by = (local / ntx) * 32;
        int tx = tid & 31, ty = tid >> 5;
#pragma unroll
        for (int q = 0; q < 4; ++q)
            t[ty + q * 8][tx] = in[(size_t)(by + ty + q * 8) * ldin + bx + tx];
        __syncthreads();
#pragma unroll
        for (int q = 0; q < 4; ++q)
            outp[(size_t)(bx + ty + q * 8) * R + by + tx] = __float2bfloat16(t[tx][ty + q * 8]);
    } else if (b < 8832) {
        int idx = (b - 8704) * 256 + tid;    // 0..32767
        int sel = idx >> 14;
        int rem = idx & 16383;
        int s = rem >> 10, k = rem & 1023;
        const float* src = sel ? w_C : w_B;
        wdelT[(size_t)(1024 + sel * 16 + s) * DINNER + k] =
            __float2bfloat16(src[(size_t)k * DSTATE + s]);
    } else {
        int local = b - 8832;
        ushort4 zero = {0, 0, 0, 0};
        if (local < 8) {
            int idx = local * 256 + tid;
            *reinterpret_cast<ushort4*>(&zpage[idx * 4]) = zero;
        } else {
            int idx = (local - 8) * 256 + tid;
            *reinterpret_cast<ushort4*>(&wdelT[(size_t)1056 * DINNER + idx * 4]) = zero;
        }
    }
}

// ---------------------------------------------------------------------------
// MFMA chunkS: per block (bc, n-block of 128): S[n][s] = sum_t w[t,n]*Bm[t,s]
// ---------------------------------------------------------------------------
__global__ __launch_bounds__(256)
void chunkS_k(const __hip_bfloat16* __restrict__ wb, const float* __restrict__ Bm,
              float* __restrict__ S)
{
    constexpr int LDW = 72;
    __shared__ __align__(16) __hip_bfloat16 wT[128 * LDW];
    __shared__ __align__(16) __hip_bfloat16 bT[16 * 80];
    const int bc = blockIdx.x, n0 = blockIdx.y * 128, t0 = bc * CHUNK;
    const int tid = threadIdx.x;
#pragma unroll
    for (int q = 0; q < 8; ++q) {
        int idx = tid + q * 256;
        int t = idx >> 5, n4 = (idx & 31) * 4;
        int key = ((n4 >> 2) & 7) << 3;
        int tx = t ^ key;
        ushort4 v = *reinterpret_cast<const ushort4*>(
            &wb[(size_t)(t0 + t) * DINNER + n0 + n4]);
        wT[(n4 + 0) * LDW + tx] = *(const __hip_bfloat16*)&v.x;
        wT[(n4 + 1) * LDW + tx] = *(const __hip_bfloat16*)&v.y;
        wT[(n4 + 2) * LDW + tx] = *(const __hip_bfloat16*)&v.z;
        wT[(n4 + 3) * LDW + tx] = *(const __hip_bfloat16*)&v.w;
    }
#pragma unroll
    for (int q = 0; q < 4; ++q) {
        int idx = tid + q * 256;
        int t = idx >> 4, s = idx & 15;
        bT[s * 80 + t] = __float2bfloat16(Bm[(size_t)(t0 + t) * DSTATE + s]);
    }
    __syncthreads();
    const int wid = tid >> 6, lane = tid & 63;
    const int llo = lane & 15, lhi = lane >> 4;
    f32x4 acc[2] = {};
#pragma unroll
    for (int kk = 0; kk < 2; ++kk) {
        bf16x8 bv = *reinterpret_cast<const bf16x8*>(&bT[llo * 80 + kk * 32 + lhi * 8]);
#pragma unroll
        for (int i = 0; i < 2; ++i) {
            int r = wid * 32 + i * 16 + llo;
            int kbase = (kk * 32 + lhi * 8) ^ (((r >> 2) & 7) << 3);
            bf16x8 af = *reinterpret_cast<const bf16x8*>(&wT[r * LDW + kbase]);
            acc[i] = __builtin_amdgcn_mfma_f32_16x16x32_bf16(af, bv, acc[i], 0, 0, 0);
        }
    }
#pragma unroll
    for (int i = 0; i < 2; ++i)
#pragma unroll
        for (int q = 0; q < 4; ++q) {
            int n = wid * 32 + i * 16 + lhi * 4 + q;
            S[((size_t)bc * DINNER + n0 + n) * DSTATE + llo] = acc[i][q];
        }
}

// exclusive prefix over chunks -> bf16 H
__global__ __launch_bounds__(256)
void hpre_k(const float* __restrict__ S, __hip_bfloat16* __restrict__ Hb)
{
    int idx = blockIdx.x * 256 + threadIdx.x;
    int b  = idx >> 14;
    int ns = idx & 16383;
    float acc = 0.f;
    for (int c = 0; c < NCHUNK; ++c) {
        size_t off = ((size_t)(b * NCHUNK + c)) * (DINNER * DSTATE) + ns;
        Hb[off] = __float2bfloat16(acc);
        acc += S[off];
    }
}

// ---------------------------------------------------------------------------
// MFMA intra-chunk: P = Cm@Bm^T (mask t<=l) -> bf16 LDS; Y = [P|Cm]@[w^T;H^T];
// g = Y * silu(z)
// ---------------------------------------------------------------------------
__global__ __launch_bounds__(256)
void intra_k(const __hip_bfloat16* __restrict__ wb,
             const float* __restrict__ Bm, const float* __restrict__ Cm,
             const __hip_bfloat16* __restrict__ Hb,
             const __hip_bfloat16* __restrict__ zb,
             __hip_bfloat16* __restrict__ gb)
{
    constexpr int LDP  = 104;
    constexpr int LDC  = 40;
    __shared__ __align__(16) __hip_bfloat16 csb[64 * LDC];
    __shared__ __align__(16) __hip_bfloat16 bsb[64 * LDC];
    __shared__ __align__(16) __hip_bfloat16 Pb [64 * LDP];
    __shared__ __align__(16) __hip_bfloat16 Wb [64 * LDP];

    const int bc = blockIdx.x;
    const int n0 = blockIdx.y * 64;
    const int t0 = bc * CHUNK;
    const int tid = threadIdx.x;
    const int wid = tid >> 6, lane = tid & 63;
    const int llo = lane & 15, lhi = lane >> 4;
    const int wr = (wid >> 1) * 32, wc = (wid & 1) * 32;
    const __hip_bfloat16 z16 = __float2bfloat16(0.f);

#pragma unroll
    for (int q = 0; q < 4; ++q) {
        int idx = tid + q * 256;
        int j = idx >> 4, s = idx & 15;
        __hip_bfloat16 cb = __float2bfloat16(Cm[(size_t)(t0 + j) * DSTATE + s]);
        csb[j * LDC + s]      = cb;
        csb[j * LDC + 16 + s] = z16;
        bsb[j * LDC + s]      = __float2bfloat16(Bm[(size_t)(t0 + j) * DSTATE + s]);
        bsb[j * LDC + 16 + s] = z16;
        Pb[j * LDP + 64 + s]  = cb;
        Pb[j * LDP + 80 + s]  = z16;
        Wb[j * LDP + 64 + s]  = Hb[((size_t)bc * DINNER + n0 + j) * DSTATE + s];
        Wb[j * LDP + 80 + s]  = z16;
    }
#pragma unroll
    for (int q = 0; q < 4; ++q) {
        int c = tid + q * 256;
        int t = c >> 4, c4 = (c & 15) * 4;
        ushort4 v = *reinterpret_cast<const ushort4*>(
            &wb[(size_t)(t0 + t) * DINNER + n0 + c4]);
        Wb[(c4 + 0) * LDP + t] = *(const __hip_bfloat16*)&v.x;
        Wb[(c4 + 1) * LDP + t] = *(const __hip_bfloat16*)&v.y;
        Wb[(c4 + 2) * LDP + t] = *(const __hip_bfloat16*)&v.z;
        Wb[(c4 + 3) * LDP + t] = *(const __hip_bfloat16*)&v.w;
    }
    __syncthreads();

    {
        f32x4 pacc[2][2] = {};
        bf16x8 ap[2], bp[2];
#pragma unroll
        for (int i = 0; i < 2; ++i)
            ap[i] = *reinterpret_cast<const bf16x8*>(&csb[(wr + i * 16 + llo) * LDC + lhi * 8]);
#pragma unroll
        for (int j = 0; j < 2; ++j)
            bp[j] = *reinterpret_cast<const bf16x8*>(&bsb[(wc + j * 16 + llo) * LDC + lhi * 8]);
#pragma unroll
        for (int i = 0; i < 2; ++i)
#pragma unroll
            for (int j = 0; j < 2; ++j)
                pacc[i][j] = __builtin_amdgcn_mfma_f32_16x16x32_bf16(ap[i], bp[j], pacc[i][j], 0, 0, 0);
#pragma unroll
        for (int i = 0; i < 2; ++i)
#pragma unroll
            for (int q = 0; q < 4; ++q) {
                int l = wr + i * 16 + lhi * 4 + q;
#pragma unroll
                for (int j = 0; j < 2; ++j) {
                    int t = wc + j * 16 + llo;
                    float pv = (t <= l) ? pacc[i][j][q] : 0.f;
                    Pb[l * LDP + t] = __float2bfloat16(pv);
                }
            }
    }
    __syncthreads();

    f32x4 yacc[2][2] = {};
#pragma unroll
    for (int k0 = 0; k0 < 3; ++k0) {
        bf16x8 af[2], bv[2];
#pragma unroll
        for (int i = 0; i < 2; ++i)
            af[i] = *reinterpret_cast<const bf16x8*>(&Pb[(wr + i * 16 + llo) * LDP + k0 * 32 + lhi * 8]);
#pragma unroll
        for (int j = 0; j < 2; ++j)
            bv[j] = *reinterpret_cast<const bf16x8*>(&Wb[(wc + j * 16 + llo) * LDP + k0 * 32 + lhi * 8]);
#pragma unroll
        for (int i = 0; i < 2; ++i)
#pragma unroll
            for (int j = 0; j < 2; ++j)
                yacc[i][j] = __builtin_amdgcn_mfma_f32_16x16x32_bf16(af[i], bv[j], yacc[i][j], 0, 0, 0);
    }

#pragma unroll
    for (int i = 0; i < 2; ++i)
#pragma unroll
        for (int q = 0; q < 4; ++q) {
            int l = wr + i * 16 + lhi * 4 + q;
            int token = t0 + l;
#pragma unroll
            for (int j = 0; j < 2; ++j) {
                int n = wc + j * 16 + llo;
                float z = __bfloat162float(zb[(size_t)token * DINNER + n0 + n]);
                gb[(size_t)token * DINNER + n0 + n] =
                    __float2bfloat16(yacc[i][j][q] * silu_f(z));
            }
        }
}

extern "C" void kernel_launch(void* const* d_in, const int* in_sizes, int n_in,
                              void* d_out, int out_size, void* d_ws, size_t ws_size,
                              hipStream_t stream) {
    const float* x      = (const float*)d_in[0];
    const float* w_in   = (const float*)d_in[1];
    const float* conv_k = (const float*)d_in[2];
    const float* conv_b = (const float*)d_in[3];
    const float* w_del  = (const float*)d_in[4];
    const float* b_del  = (const float*)d_in[5];
    const float* w_B    = (const float*)d_in[6];
    const float* b_B    = (const float*)d_in[7];
    const float* w_C    = (const float*)d_in[8];
    const float* b_C    = (const float*)d_in[9];
    const float* w_out  = (const float*)d_in[11];
    float* out = (float*)d_out;

    // f32 region
    float* Bm    = (float*)d_ws;
    float* Cm    = Bm + (size_t)NTOK * DSTATE;
    float* S     = Cm + (size_t)NTOK * DSTATE;            // 1M f32
    // bf16 region
    __hip_bfloat16* Hb    = (__hip_bfloat16*)(S + (size_t)2 * NCHUNK * DINNER * DSTATE);
    __hip_bfloat16* xb    = Hb    + (size_t)2 * NCHUNK * DINNER * DSTATE;  // 1M elems
    __hip_bfloat16* xcb   = xb    + (size_t)NTOK * DMODEL;        // 4M elems
    __hip_bfloat16* zb    = xcb   + (size_t)NTOK * DINNER;        // 4M
    __hip_bfloat16* gb    = zb    + (size_t)NTOK * DINNER;        // 4M
    __hip_bfloat16* wbufb = gb    + (size_t)NTOK * DINNER;        // 4M
    __hip_bfloat16* W1b   = wbufb + (size_t)NTOK * DINNER;        // 0.5M
    __hip_bfloat16* w2T   = W1b   + (size_t)DMODEL * DINNER;      // 0.5M
    __hip_bfloat16* convT = w2T   + (size_t)DINNER * DMODEL;      // 4M
    __hip_bfloat16* wdelT = convT + (size_t)4 * DINNER * DINNER;  // 1088 x 1024
    __hip_bfloat16* woutT = wdelT + (size_t)1088 * DINNER;        // 0.5M
    __hip_bfloat16* FT    = woutT + (size_t)DINNER * DMODEL;      // 2M (1024 x 2048)
    __hip_bfloat16* zpage = FT    + (size_t)DINNER * 2048;        // 8K elems
    __hip_bfloat16* P0    = zpage + 8192;                         // 4M elems
    __hip_bfloat16* P1    = P0    + (size_t)NTOK * DINNER;        // 4M elems

    // one-launch prep: cvts + transposes + bcw + zero fills
    prep_k<<<8872, 256, 0, stream>>>(x, w_in, conv_k, w_del, w_B, w_C, w_out,
                                     xb, W1b, w2T, convT, wdelT, woutT, zpage);

    // fused conv weights: FT[o][tap*512 + dm] = (W1 @ K_tap)[dm][o], row stride 2048
    mgemm<4, 64, 64><<<dim3(DMODEL / 64, DINNER / 64, 4), 256, 0, stream>>>(
        convT, 4 * DINNER, W1b, DINNER, nullptr, FT, nullptr, 4 * DMODEL, DINNER,
        nullptr, nullptr, nullptr, 0, zpage, nullptr, nullptr, nullptr, nullptr, nullptr);
    // fused conv(split-K2)+z: x<16 -> P0 (taps 0-1); x<32 -> P1 (taps 2-3);
    //                         x<48 -> zb (w2T, K=512). grid 48x32=1536 (%8 ok)
    mgemm<0, 128, 64><<<dim3(48, NTOK / 128), 256, 0, stream>>>(
        xb, DMODEL, FT, 4 * DMODEL, nullptr, P0, zb, DINNER, 1024,
        nullptr, nullptr, w2T, DMODEL, zpage, nullptr, nullptr, nullptr, nullptr, P1);
    // combine halves: xcb = bf16(silu(P0+P1+conv_b))
    combine_k<<<NTOK * DINNER / 1024, 256, 0, stream>>>(P0, P1, conv_b, xcb);
    // delta + B/C fused: N=1088 (tile 128x64, grid 17x32=544); w -> bf16 wbufb
    mgemm<2, 128, 64><<<dim3(1088 / 64, NTOK / 128), 256, 0, stream>>>(
        xcb, DINNER, wdelT, DINNER, nullptr, wbufb, nullptr, DINNER, DINNER,
        b_del, xcb, nullptr, 0, zpage, b_B, b_C, Bm, Cm, nullptr);
    // scan
    chunkS_k<<<dim3(2 * NCHUNK, DINNER / 128), 256, 0, stream>>>(wbufb, Bm, S);
    hpre_k<<<dim3(2 * DINNER * DSTATE / 256), 256, 0, stream>>>(S, Hb);
    intra_k<<<dim3(2 * NCHUNK, DINNER / 64), 256, 0, stream>>>(wbufb, Bm, Cm, Hb, zb, gb);
    // out = g @ w_out  (tile 64x64, grid (8,64) = 512 blocks, 16 KB LDS)
    mgemm<3, 64, 64><<<dim3(DMODEL / 64, NTOK / 64), 256, 0, stream>>>(
        gb, DINNER, woutT, DINNER, out, nullptr, nullptr, DMODEL, DINNER,
        nullptr, nullptr, nullptr, 0, zpage, nullptr, nullptr, nullptr, nullptr, nullptr);
}

// Round 20
// 113.877 us; speedup vs baseline: 3.0441x; 1.1623x over previous
//
#include <hip/hip_runtime.h>
#include <hip/hip_bf16.h>
#include <math.h>

#define DMODEL 512
#define DINNER 1024
#define DSTATE 16
#define SEQLEN 2048
#define NTOK   4096
#define CHUNK  64
#define NCHUNK (SEQLEN / CHUNK)  // 32

typedef __bf16 bf16x8 __attribute__((ext_vector_type(8)));
typedef float  f32x4  __attribute__((ext_vector_type(4)));

__device__ __forceinline__ float silu_f(float x) {
    return x / (1.0f + __expf(-x));
}

// fast softplus: abs err ~1e-7, negligible at bf16 output precision
__device__ __forceinline__ float softplus_f(float x) {
    return fmaxf(x, 0.f) + __logf(1.0f + __expf(-fabsf(x)));
}

// swizzled LDS index (bf16 elems) for row r, 16B slot s (8 slots per 64-elem row)
__device__ __forceinline__ int swz(int r, int s) {
    return r * 64 + ((s ^ (r & 7)) << 3);
}

// async global->LDS 16B; LDS dest is wave-uniform base + lane*16
__device__ __forceinline__ void gload16(const void* g, void* l) {
    __builtin_amdgcn_global_load_lds(
        (const __attribute__((address_space(1))) void*)g,
        (__attribute__((address_space(3))) void*)l, 16, 0, 0);
}

__device__ __forceinline__ void cvt4(const float* src, __hip_bfloat16* dst) {
    float4 v = *reinterpret_cast<const float4*>(src);
    __hip_bfloat16 tmp[4] = {__float2bfloat16(v.x), __float2bfloat16(v.y),
                             __float2bfloat16(v.z), __float2bfloat16(v.w)};
    *reinterpret_cast<ushort4*>(dst) = *reinterpret_cast<const ushort4*>(tmp);
}

// ---------------------------------------------------------------------------
// bf16 MFMA GEMM, tile TBM x TBN, BK=64, 4 waves (2x2), gload_lds staging,
// single-buffer LDS, 2-barrier loop: {stage(t); bar; MFMA(t); bar}.
// Linear LDS + source-side XOR swizzle (involution) + same swizzle on ds_read.
// MODE 0: fused conv(split-K2)+z triple path, grid x=48:
//         x<16:  conv half 0 (taps 0-1, K=1024) -> P0 bf16 raw partial
//         x<32:  conv half 1 (taps 2-3, K=1024) -> P1 bf16 raw partial
//         else:  z (w2T, K=512) -> Czb bf16
// MODE 2: delta+BC — n<1024: softplus(acc+bias[n])*xc[m,n]*0.95^(l+1) -> Cb bf16;
//         n in [1024,1040): Bm = acc+bB ; [1040,1056): Cm = acc+bC ; else drop
// MODE 3: plain — C0 = acc (f32)
// MODE 4: fused-weight GEMM — per-tap (blockIdx.z), bf16 store at ldc stride
// ---------------------------------------------------------------------------
template<int MODE, int TBM, int TBN>
__global__ __launch_bounds__(256)
void mgemm(const __hip_bfloat16* __restrict__ A, int lda,
           const __hip_bfloat16* __restrict__ WT, int ldw,
           float* __restrict__ C0, __hip_bfloat16* __restrict__ Cb,
           __hip_bfloat16* __restrict__ Czb, int ldc,
           int K, const float* __restrict__ bias,
           const __hip_bfloat16* __restrict__ xc,
           const __hip_bfloat16* __restrict__ WT2, int ldw2,
           const __hip_bfloat16* __restrict__ zpage,
           const float* __restrict__ bB, const float* __restrict__ bC,
           float* __restrict__ BmO, float* __restrict__ CmO,
           __hip_bfloat16* __restrict__ Pb1)
{
    constexpr int MI = TBM / 32;
    constexpr int MJ = TBN / 32;
    __shared__ __align__(16) __hip_bfloat16 As[TBM * 64];
    __shared__ __align__(16) __hip_bfloat16 Bs[TBN * 64];

    // bijective XCD swizzle (all launches have nb % 8 == 0)
    const int nb  = gridDim.x * gridDim.y;
    const int lin = blockIdx.y * gridDim.x + blockIdx.x;
    const int cpx = nb >> 3;
    const int sl  = (lin & 7) * cpx + (lin >> 3);
    const int bm  = (sl / gridDim.x) * TBM;
    const int bn  = (sl % gridDim.x) * TBN;

    if (MODE == 4) { A += blockIdx.z * 1024; Cb += blockIdx.z * 512; }

    const int  xsel = (MODE == 0) ? (bn >> 10) : 0;   // 0,1: conv halves; 2: z
    const bool zblk = (MODE == 0) && (xsel == 2);
    const int  bnb  = (MODE == 0) ? (bn & 1023) : bn;
    const __hip_bfloat16* Wp = zblk ? WT2 : WT;
    const int  ldwp = zblk ? ldw2 : ldw;
    const int  Keff = (MODE == 0 && zblk) ? DMODEL : K;
    const int  koff = (MODE == 0 && xsel == 1) ? 1024 : 0;

    const int tid  = threadIdx.x;
    const int wid  = tid >> 6, lane = tid & 63;
    const int wr   = (wid >> 1) * (TBM / 2), wc = (wid & 1) * (TBN / 2);
    const int llo  = lane & 15, lhi = lane >> 4;

    f32x4 acc[MI][MJ] = {};

    const int srow0 = wid * 8 + (lane >> 3);
    const int sphys = lane & 7;

    auto stage_tile = [&](int k0) {
#pragma unroll
        for (int q = 0; q < MI; ++q) {
            int row  = q * 32 + srow0;
            int sdat = sphys ^ (row & 7);
            const __hip_bfloat16* srcA;
            if (MODE == 0 && !zblk) {
                int kg  = koff + k0;
                int kid = kg >> 9;
                int gr  = bm + row;
                int l2  = (gr & (SEQLEN - 1)) + kid - 1;
                srcA = ((unsigned)l2 < (unsigned)SEQLEN)
                     ? A + (size_t)(gr + kid - 1) * lda + (kg & 511) + sdat * 8
                     : zpage;
            } else {
                srcA = A + (size_t)(bm + row) * lda + k0 + sdat * 8;
            }
            gload16(srcA, &As[q * 2048 + wid * 512]);
        }
#pragma unroll
        for (int q = 0; q < MJ; ++q) {
            int row  = q * 32 + srow0;
            int sdat = sphys ^ (row & 7);
            gload16(Wp + (size_t)(bnb + row) * ldwp + koff + k0 + sdat * 8,
                    &Bs[q * 2048 + wid * 512]);
        }
    };

    const int NT = Keff / 64;
    for (int t = 0; t < NT; ++t) {
        stage_tile(t * 64);
        __syncthreads();
#pragma unroll
        for (int kk = 0; kk < 2; ++kk) {
            bf16x8 af[MI], bv[MJ];
#pragma unroll
            for (int i = 0; i < MI; ++i)
                af[i] = *reinterpret_cast<const bf16x8*>(&As[swz(wr + i * 16 + llo, kk * 4 + lhi)]);
#pragma unroll
            for (int j = 0; j < MJ; ++j)
                bv[j] = *reinterpret_cast<const bf16x8*>(&Bs[swz(wc + j * 16 + llo, kk * 4 + lhi)]);
#pragma unroll
            for (int i = 0; i < MI; ++i)
#pragma unroll
                for (int j = 0; j < MJ; ++j)
                    acc[i][j] = __builtin_amdgcn_mfma_f32_16x16x32_bf16(af[i], bv[j], acc[i][j], 0, 0, 0);
        }
        __syncthreads();
    }

#pragma unroll
    for (int i = 0; i < MI; ++i) {
#pragma unroll
        for (int q = 0; q < 4; ++q) {
            int m = bm + wr + i * 16 + lhi * 4 + q;
            float dec = 1.0f;
            if (MODE == 2)
                dec = __expf((float)((m & (SEQLEN - 1)) + 1) * -0.051293294f); // ln 0.95
#pragma unroll
            for (int j = 0; j < MJ; ++j) {
                int nrel = wc + j * 16 + llo;
                int n = bn + nrel;
                float v = acc[i][j][q];
                if (MODE == 0) {
                    int col = bnb + nrel;
                    if (zblk) {
                        Czb[(size_t)m * DINNER + col] = __float2bfloat16(v);
                    } else {
                        __hip_bfloat16* P = xsel ? Pb1 : Cb;
                        P[(size_t)m * DINNER + col] = __float2bfloat16(v);
                    }
                } else if (MODE == 2) {
                    if (n < DINNER) {
                        float sp = softplus_f(v + bias[n]);
                        float xcv = __bfloat162float(xc[(size_t)m * DINNER + n]);
                        Cb[(size_t)m * DINNER + n] = __float2bfloat16(sp * xcv * dec);
                    } else {
                        int col = n - DINNER;
                        if (col < 16)
                            BmO[(size_t)m * DSTATE + col] = v + bB[col];
                        else if (col < 32)
                            CmO[(size_t)m * DSTATE + (col - 16)] = v + bC[col - 16];
                    }
                } else if (MODE == 4) {
                    Cb[(size_t)m * ldc + n] = __float2bfloat16(v);
                } else {
                    C0[(size_t)m * ldc + n] = v;
                }
            }
        }
    }
}

// combine split-K conv halves: xcb = bf16(silu(P0 + P1 + bias[n]))
__global__ __launch_bounds__(256)
void combine_k(const __hip_bfloat16* __restrict__ P0,
               const __hip_bfloat16* __restrict__ P1,
               const float* __restrict__ bias,
               __hip_bfloat16* __restrict__ xcb)
{
    int idx = blockIdx.x * 256 + threadIdx.x;
    size_t off = (size_t)idx * 4;
    int n = (int)(off & 1023);
    ushort4 a = *reinterpret_cast<const ushort4*>(&P0[off]);
    ushort4 b = *reinterpret_cast<const ushort4*>(&P1[off]);
    __hip_bfloat16 o[4];
#pragma unroll
    for (int j = 0; j < 4; ++j) {
        float va = __bfloat162float(((const __hip_bfloat16*)&a)[j]);
        float vb = __bfloat162float(((const __hip_bfloat16*)&b)[j]);
        o[j] = __float2bfloat16(silu_f(va + vb + bias[n + j]));
    }
    *reinterpret_cast<ushort4*>(&xcb[off]) = *reinterpret_cast<const ushort4*>(o);
}

// ---------------------------------------------------------------------------
// prep megakernel — one launch for all input/weight prep
// ---------------------------------------------------------------------------
__global__ __launch_bounds__(256)
void prep_k(const float* __restrict__ x, const float* __restrict__ w_in,
            const float* __restrict__ conv_k, const float* __restrict__ w_del,
            const float* __restrict__ w_B, const float* __restrict__ w_C,
            const float* __restrict__ w_out,
            __hip_bfloat16* __restrict__ xb, __hip_bfloat16* __restrict__ W1b,
            __hip_bfloat16* __restrict__ w2T, __hip_bfloat16* __restrict__ convT,
            __hip_bfloat16* __restrict__ wdelT, __hip_bfloat16* __restrict__ woutT,
            __hip_bfloat16* __restrict__ zpage)
{
    __shared__ float t[32][33];
    const int b = blockIdx.x, tid = threadIdx.x;
    if (b < 2048) {
        int idx = b * 256 + tid;
        int r = idx >> 7, c = (idx & 127) * 4;
        cvt4(x + (size_t)r * DMODEL + c, xb + (size_t)r * DMODEL + c);
    } else if (b < 2560) {
        int idx = (b - 2048) * 256 + tid;
        int r = idx >> 8, c = (idx & 255) * 4;
        cvt4(w_in + (size_t)r * (2 * DINNER) + c, W1b + (size_t)r * DINNER + c);
    } else if (b < 8704) {
        const float* in; __hip_bfloat16* outp; int R, ldin, ntx, local;
        if (b < 3072)      { local = b - 2560; in = w_in + DINNER; outp = w2T;   R = 512;  ldin = 2048; ntx = 32; }
        else if (b < 7168) { local = b - 3072; in = conv_k;        outp = convT; R = 4096; ldin = 1024; ntx = 32; }
        else if (b < 8192) { local = b - 7168; in = w_del;         outp = wdelT; R = 1024; ldin = 1024; ntx = 32; }
        else               { local = b - 8192; in = w_out;         outp = woutT; R = 1024; ldin = 512;  ntx = 16; }
        int bx = (local % ntx) * 32, by = (local / ntx) * 32;
        int tx = tid & 31, ty = tid >> 5;
#pragma unroll
        for (int q = 0; q < 4; ++q)
            t[ty + q * 8][tx] = in[(size_t)(by + ty + q * 8) * ldin + bx + tx];
        __syncthreads();
#pragma unroll
        for (int q = 0; q < 4; ++q)
            outp[(size_t)(bx + ty + q * 8) * R + by + tx] = __float2bfloat16(t[tx][ty + q * 8]);
    } else if (b < 8832) {
        int idx = (b - 8704) * 256 + tid;    // 0..32767
        int sel = idx >> 14;
        int rem = idx & 16383;
        int s = rem >> 10, k = rem & 1023;
        const float* src = sel ? w_C : w_B;
        wdelT[(size_t)(1024 + sel * 16 + s) * DINNER + k] =
            __float2bfloat16(src[(size_t)k * DSTATE + s]);
    } else {
        int local = b - 8832;
        ushort4 zero = {0, 0, 0, 0};
        if (local < 8) {
            int idx = local * 256 + tid;
            *reinterpret_cast<ushort4*>(&zpage[idx * 4]) = zero;
        } else {
            int idx = (local - 8) * 256 + tid;
            *reinterpret_cast<ushort4*>(&wdelT[(size_t)1056 * DINNER + idx * 4]) = zero;
        }
    }
}

// ---------------------------------------------------------------------------
// MFMA chunkS: per block (bc, n-block of 128): S[n][s] = sum_t w[t,n]*Bm[t,s]
// ---------------------------------------------------------------------------
__global__ __launch_bounds__(256)
void chunkS_k(const __hip_bfloat16* __restrict__ wb, const float* __restrict__ Bm,
              float* __restrict__ S)
{
    constexpr int LDW = 72;
    __shared__ __align__(16) __hip_bfloat16 wT[128 * LDW];
    __shared__ __align__(16) __hip_bfloat16 bT[16 * 80];
    const int bc = blockIdx.x, n0 = blockIdx.y * 128, t0 = bc * CHUNK;
    const int tid = threadIdx.x;
#pragma unroll
    for (int q = 0; q < 8; ++q) {
        int idx = tid + q * 256;
        int t = idx >> 5, n4 = (idx & 31) * 4;
        int key = ((n4 >> 2) & 7) << 3;
        int tx = t ^ key;
        ushort4 v = *reinterpret_cast<const ushort4*>(
            &wb[(size_t)(t0 + t) * DINNER + n0 + n4]);
        wT[(n4 + 0) * LDW + tx] = *(const __hip_bfloat16*)&v.x;
        wT[(n4 + 1) * LDW + tx] = *(const __hip_bfloat16*)&v.y;
        wT[(n4 + 2) * LDW + tx] = *(const __hip_bfloat16*)&v.z;
        wT[(n4 + 3) * LDW + tx] = *(const __hip_bfloat16*)&v.w;
    }
#pragma unroll
    for (int q = 0; q < 4; ++q) {
        int idx = tid + q * 256;
        int t = idx >> 4, s = idx & 15;
        bT[s * 80 + t] = __float2bfloat16(Bm[(size_t)(t0 + t) * DSTATE + s]);
    }
    __syncthreads();
    const int wid = tid >> 6, lane = tid & 63;
    const int llo = lane & 15, lhi = lane >> 4;
    f32x4 acc[2] = {};
#pragma unroll
    for (int kk = 0; kk < 2; ++kk) {
        bf16x8 bv = *reinterpret_cast<const bf16x8*>(&bT[llo * 80 + kk * 32 + lhi * 8]);
#pragma unroll
        for (int i = 0; i < 2; ++i) {
            int r = wid * 32 + i * 16 + llo;
            int kbase = (kk * 32 + lhi * 8) ^ (((r >> 2) & 7) << 3);
            bf16x8 af = *reinterpret_cast<const bf16x8*>(&wT[r * LDW + kbase]);
            acc[i] = __builtin_amdgcn_mfma_f32_16x16x32_bf16(af, bv, acc[i], 0, 0, 0);
        }
    }
#pragma unroll
    for (int i = 0; i < 2; ++i)
#pragma unroll
        for (int q = 0; q < 4; ++q) {
            int n = wid * 32 + i * 16 + lhi * 4 + q;
            S[((size_t)bc * DINNER + n0 + n) * DSTATE + llo] = acc[i][q];
        }
}

// exclusive prefix over chunks -> bf16 H
__global__ __launch_bounds__(256)
void hpre_k(const float* __restrict__ S, __hip_bfloat16* __restrict__ Hb)
{
    int idx = blockIdx.x * 256 + threadIdx.x;
    int b  = idx >> 14;
    int ns = idx & 16383;
    float acc = 0.f;
    for (int c = 0; c < NCHUNK; ++c) {
        size_t off = ((size_t)(b * NCHUNK + c)) * (DINNER * DSTATE) + ns;
        Hb[off] = __float2bfloat16(acc);
        acc += S[off];
    }
}

// ---------------------------------------------------------------------------
// MFMA intra-chunk: P = Cm@Bm^T (mask t<=l) -> bf16 LDS; Y = [P|Cm]@[w^T;H^T];
// g = Y * silu(z)
// ---------------------------------------------------------------------------
__global__ __launch_bounds__(256)
void intra_k(const __hip_bfloat16* __restrict__ wb,
             const float* __restrict__ Bm, const float* __restrict__ Cm,
             const __hip_bfloat16* __restrict__ Hb,
             const __hip_bfloat16* __restrict__ zb,
             __hip_bfloat16* __restrict__ gb)
{
    constexpr int LDP  = 104;
    constexpr int LDC  = 40;
    __shared__ __align__(16) __hip_bfloat16 csb[64 * LDC];
    __shared__ __align__(16) __hip_bfloat16 bsb[64 * LDC];
    __shared__ __align__(16) __hip_bfloat16 Pb [64 * LDP];
    __shared__ __align__(16) __hip_bfloat16 Wb [64 * LDP];

    const int bc = blockIdx.x;
    const int n0 = blockIdx.y * 64;
    const int t0 = bc * CHUNK;
    const int tid = threadIdx.x;
    const int wid = tid >> 6, lane = tid & 63;
    const int llo = lane & 15, lhi = lane >> 4;
    const int wr = (wid >> 1) * 32, wc = (wid & 1) * 32;
    const __hip_bfloat16 z16 = __float2bfloat16(0.f);

#pragma unroll
    for (int q = 0; q < 4; ++q) {
        int idx = tid + q * 256;
        int j = idx >> 4, s = idx & 15;
        __hip_bfloat16 cb = __float2bfloat16(Cm[(size_t)(t0 + j) * DSTATE + s]);
        csb[j * LDC + s]      = cb;
        csb[j * LDC + 16 + s] = z16;
        bsb[j * LDC + s]      = __float2bfloat16(Bm[(size_t)(t0 + j) * DSTATE + s]);
        bsb[j * LDC + 16 + s] = z16;
        Pb[j * LDP + 64 + s]  = cb;
        Pb[j * LDP + 80 + s]  = z16;
        Wb[j * LDP + 64 + s]  = Hb[((size_t)bc * DINNER + n0 + j) * DSTATE + s];
        Wb[j * LDP + 80 + s]  = z16;
    }
#pragma unroll
    for (int q = 0; q < 4; ++q) {
        int c = tid + q * 256;
        int t = c >> 4, c4 = (c & 15) * 4;
        ushort4 v = *reinterpret_cast<const ushort4*>(
            &wb[(size_t)(t0 + t) * DINNER + n0 + c4]);
        Wb[(c4 + 0) * LDP + t] = *(const __hip_bfloat16*)&v.x;
        Wb[(c4 + 1) * LDP + t] = *(const __hip_bfloat16*)&v.y;
        Wb[(c4 + 2) * LDP + t] = *(const __hip_bfloat16*)&v.z;
        Wb[(c4 + 3) * LDP + t] = *(const __hip_bfloat16*)&v.w;
    }
    __syncthreads();

    {
        f32x4 pacc[2][2] = {};
        bf16x8 ap[2], bp[2];
#pragma unroll
        for (int i = 0; i < 2; ++i)
            ap[i] = *reinterpret_cast<const bf16x8*>(&csb[(wr + i * 16 + llo) * LDC + lhi * 8]);
#pragma unroll
        for (int j = 0; j < 2; ++j)
            bp[j] = *reinterpret_cast<const bf16x8*>(&bsb[(wc + j * 16 + llo) * LDC + lhi * 8]);
#pragma unroll
        for (int i = 0; i < 2; ++i)
#pragma unroll
            for (int j = 0; j < 2; ++j)
                pacc[i][j] = __builtin_amdgcn_mfma_f32_16x16x32_bf16(ap[i], bp[j], pacc[i][j], 0, 0, 0);
#pragma unroll
        for (int i = 0; i < 2; ++i)
#pragma unroll
            for (int q = 0; q < 4; ++q) {
                int l = wr + i * 16 + lhi * 4 + q;
#pragma unroll
                for (int j = 0; j < 2; ++j) {
                    int t = wc + j * 16 + llo;
                    float pv = (t <= l) ? pacc[i][j][q] : 0.f;
                    Pb[l * LDP + t] = __float2bfloat16(pv);
                }
            }
    }
    __syncthreads();

    f32x4 yacc[2][2] = {};
#pragma unroll
    for (int k0 = 0; k0 < 3; ++k0) {
        bf16x8 af[2], bv[2];
#pragma unroll
        for (int i = 0; i < 2; ++i)
            af[i] = *reinterpret_cast<const bf16x8*>(&Pb[(wr + i * 16 + llo) * LDP + k0 * 32 + lhi * 8]);
#pragma unroll
        for (int j = 0; j < 2; ++j)
            bv[j] = *reinterpret_cast<const bf16x8*>(&Wb[(wc + j * 16 + llo) * LDP + k0 * 32 + lhi * 8]);
#pragma unroll
        for (int i = 0; i < 2; ++i)
#pragma unroll
            for (int j = 0; j < 2; ++j)
                yacc[i][j] = __builtin_amdgcn_mfma_f32_16x16x32_bf16(af[i], bv[j], yacc[i][j], 0, 0, 0);
    }

#pragma unroll
    for (int i = 0; i < 2; ++i)
#pragma unroll
        for (int q = 0; q < 4; ++q) {
            int l = wr + i * 16 + lhi * 4 + q;
            int token = t0 + l;
#pragma unroll
            for (int j = 0; j < 2; ++j) {
                int n = wc + j * 16 + llo;
                float z = __bfloat162float(zb[(size_t)token * DINNER + n0 + n]);
                gb[(size_t)token * DINNER + n0 + n] =
                    __float2bfloat16(yacc[i][j][q] * silu_f(z));
            }
        }
}

extern "C" void kernel_launch(void* const* d_in, const int* in_sizes, int n_in,
                              void* d_out, int out_size, void* d_ws, size_t ws_size,
                              hipStream_t stream) {
    const float* x      = (const float*)d_in[0];
    const float* w_in   = (const float*)d_in[1];
    const float* conv_k = (const float*)d_in[2];
    const float* conv_b = (const float*)d_in[3];
    const float* w_del  = (const float*)d_in[4];
    const float* b_del  = (const float*)d_in[5];
    const float* w_B    = (const float*)d_in[6];
    const float* b_B    = (const float*)d_in[7];
    const float* w_C    = (const float*)d_in[8];
    const float* b_C    = (const float*)d_in[9];
    const float* w_out  = (const float*)d_in[11];
    float* out = (float*)d_out;

    // f32 region
    float* Bm    = (float*)d_ws;
    float* Cm    = Bm + (size_t)NTOK * DSTATE;
    float* S     = Cm + (size_t)NTOK * DSTATE;            // 1M f32
    // bf16 region
    __hip_bfloat16* Hb    = (__hip_bfloat16*)(S + (size_t)2 * NCHUNK * DINNER * DSTATE);
    __hip_bfloat16* xb    = Hb    + (size_t)2 * NCHUNK * DINNER * DSTATE;  // 1M elems
    __hip_bfloat16* xcb   = xb    + (size_t)NTOK * DMODEL;        // 4M elems
    __hip_bfloat16* zb    = xcb   + (size_t)NTOK * DINNER;        // 4M
    __hip_bfloat16* gb    = zb    + (size_t)NTOK * DINNER;        // 4M
    __hip_bfloat16* wbufb = gb    + (size_t)NTOK * DINNER;        // 4M
    __hip_bfloat16* W1b   = wbufb + (size_t)NTOK * DINNER;        // 0.5M
    __hip_bfloat16* w2T   = W1b   + (size_t)DMODEL * DINNER;      // 0.5M
    __hip_bfloat16* convT = w2T   + (size_t)DINNER * DMODEL;      // 4M
    __hip_bfloat16* wdelT = convT + (size_t)4 * DINNER * DINNER;  // 1088 x 1024
    __hip_bfloat16* woutT = wdelT + (size_t)1088 * DINNER;        // 0.5M
    __hip_bfloat16* FT    = woutT + (size_t)DINNER * DMODEL;      // 2M (1024 x 2048)
    __hip_bfloat16* zpage = FT    + (size_t)DINNER * 2048;        // 8K elems
    __hip_bfloat16* P0    = zpage + 8192;                         // 4M elems
    __hip_bfloat16* P1    = P0    + (size_t)NTOK * DINNER;        // 4M elems

    // one-launch prep: cvts + transposes + bcw + zero fills
    prep_k<<<8872, 256, 0, stream>>>(x, w_in, conv_k, w_del, w_B, w_C, w_out,
                                     xb, W1b, w2T, convT, wdelT, woutT, zpage);

    // fused conv weights: FT[o][tap*512 + dm] = (W1 @ K_tap)[dm][o], row stride 2048
    mgemm<4, 64, 64><<<dim3(DMODEL / 64, DINNER / 64, 4), 256, 0, stream>>>(
        convT, 4 * DINNER, W1b, DINNER, nullptr, FT, nullptr, 4 * DMODEL, DINNER,
        nullptr, nullptr, nullptr, 0, zpage, nullptr, nullptr, nullptr, nullptr, nullptr);
    // fused conv(split-K2)+z: x<16 -> P0 (taps 0-1); x<32 -> P1 (taps 2-3);
    //                         x<48 -> zb (w2T, K=512). grid 48x32=1536 (%8 ok)
    mgemm<0, 128, 64><<<dim3(48, NTOK / 128), 256, 0, stream>>>(
        xb, DMODEL, FT, 4 * DMODEL, nullptr, P0, zb, DINNER, 1024,
        nullptr, nullptr, w2T, DMODEL, zpage, nullptr, nullptr, nullptr, nullptr, P1);
    // combine halves: xcb = bf16(silu(P0+P1+conv_b))
    combine_k<<<NTOK * DINNER / 1024, 256, 0, stream>>>(P0, P1, conv_b, xcb);
    // delta + B/C fused: N=1088, tile 64x64, grid (17,64)=1088 blocks (%8 ok)
    mgemm<2, 64, 64><<<dim3(1088 / 64, NTOK / 64), 256, 0, stream>>>(
        xcb, DINNER, wdelT, DINNER, nullptr, wbufb, nullptr, DINNER, DINNER,
        b_del, xcb, nullptr, 0, zpage, b_B, b_C, Bm, Cm, nullptr);
    // scan
    chunkS_k<<<dim3(2 * NCHUNK, DINNER / 128), 256, 0, stream>>>(wbufb, Bm, S);
    hpre_k<<<dim3(2 * DINNER * DSTATE / 256), 256, 0, stream>>>(S, Hb);
    intra_k<<<dim3(2 * NCHUNK, DINNER / 64), 256, 0, stream>>>(wbufb, Bm, Cm, Hb, zb, gb);
    // out = g @ w_out  (tile 64x64, grid (8,64) = 512 blocks, 16 KB LDS)
    mgemm<3, 64, 64><<<dim3(DMODEL / 64, NTOK / 64), 256, 0, stream>>>(
        gb, DINNER, woutT, DINNER, out, nullptr, nullptr, DMODEL, DINNER,
        nullptr, nullptr, nullptr, 0, zpage, nullptr, nullptr, nullptr, nullptr, nullptr);
}